// Round 6
// baseline (481.099 us; speedup 1.0000x reference)
//
#include <hip/hip_runtime.h>
#include <math.h>

#define SCALE_ATTN 0.15811388300841897f

typedef __attribute__((ext_vector_type(8))) short short8v;
typedef __attribute__((ext_vector_type(4))) float float4v;
typedef unsigned short u16;

__device__ __forceinline__ u16 f2bf(float x) {
  unsigned u = __float_as_uint(x);
  unsigned r = (u + 0x7FFFu + ((u >> 16) & 1u)) >> 16;
  return (u16)r;
}
__device__ __forceinline__ unsigned pack2(float a, float b) {
  return (unsigned)f2bf(a) | ((unsigned)f2bf(b) << 16);
}
__device__ __forceinline__ float bfu2f(u16 u) {
  return __uint_as_float(((unsigned)u) << 16);
}

// ---------------- prep: weight transpose+convert | ctx cvt | gn stats (block ranges) --------
struct TDesc { const float* src; u16* dst; int K, N, off, tx; };
struct TPack { TDesc d[12]; };

__global__ __launch_bounds__(256) void prep_kernel(
    TPack p, int nT,
    const float* __restrict__ ctxsrc, u16* __restrict__ ctxdst,
    const float* __restrict__ x, const float* __restrict__ gs,
    const float* __restrict__ gb, float* __restrict__ chscale, float* __restrict__ chshift) {
  __shared__ float ls[32][33];
  int bt = blockIdx.x, t = threadIdx.x;
  if (bt < nT) {
    int ti = 0;
    #pragma unroll
    for (int i = 1; i < 12; i++) if (bt >= p.d[i].off) ti = i;
    TDesc dd = p.d[ti];
    int local = bt - dd.off;
    int n0 = (local % dd.tx) * 32, k0 = (local / dd.tx) * 32;
    #pragma unroll
    for (int i = 0; i < 4; i++) {
      int idx = t + i*256, r = idx >> 5, c = idx & 31;
      ls[r][c] = dd.src[(size_t)(k0 + r)*dd.N + n0 + c];
    }
    __syncthreads();
    #pragma unroll
    for (int i = 0; i < 2; i++) {
      int p2 = t + i*256, n = p2 >> 4, kp = (p2 & 15)*2;
      *(unsigned*)&dd.dst[(size_t)(n0 + n)*dd.K + k0 + kp] = pack2(ls[kp][n], ls[kp+1][n]);
    }
  } else if (bt < nT + 58) {
    int idx = ((bt - nT)*256 + t)*4;
    if (idx < 59136) {
      float4 v = *(const float4*)&ctxsrc[idx];
      uint2 o; o.x = pack2(v.x, v.y); o.y = pack2(v.z, v.w);
      *(uint2*)&ctxdst[idx] = o;
    }
  } else {
    int g = bt - nT - 58;
    size_t base = (size_t)g * 40960;
    float sum = 0.f, sq = 0.f;
    for (int e = t; e < 40960; e += 256) {
      float v = x[base + e];
      sum += v; sq += v * v;
    }
    float* s1 = &ls[0][0];        // 256 floats
    float* s2 = &ls[8][0] + 8;    // within 32x33
    s1[t] = sum; s2[t] = sq; __syncthreads();
    for (int st = 128; st > 0; st >>= 1) {
      if (t < st) { s1[t] += s1[t+st]; s2[t] += s2[t+st]; }
      __syncthreads();
    }
    float mu = s1[0] * (1.f/40960.f);
    float var = s2[0] * (1.f/40960.f) - mu*mu;
    float rs = rsqrtf(var + 1e-6f);
    if (t < 10) {
      int c = g*10 + t;
      float sc = rs * gs[c];
      chscale[c] = sc;
      chshift[c] = gb[c] - mu * sc;
    }
  }
}

// ---------------- GN apply + transpose: x[c][s] fp32 -> gnT[s][c] bf16 ----------------
__global__ __launch_bounds__(256) void gn_apply_t_kernel(
    const float* __restrict__ x, const float* __restrict__ chscale,
    const float* __restrict__ chshift, u16* __restrict__ gnT) {
  __shared__ float ts[64][65];
  __shared__ float scl[64], sft[64];
  int s0 = blockIdx.x * 64, c0 = blockIdx.y * 64;
  int t = threadIdx.x;
  if (t < 64) { scl[t] = chscale[c0 + t]; sft[t] = chshift[c0 + t]; }
  int crow = t >> 2, sch = (t & 3) * 16;
  #pragma unroll
  for (int j = 0; j < 4; j++) {
    float4 v = *(const float4*)&x[(size_t)(c0 + crow)*4096 + s0 + sch + 4*j];
    ts[crow][sch + 4*j + 0] = v.x; ts[crow][sch + 4*j + 1] = v.y;
    ts[crow][sch + 4*j + 2] = v.z; ts[crow][sch + 4*j + 3] = v.w;
  }
  __syncthreads();
  int srow = t >> 2, cch = (t & 3) * 16;
  #pragma unroll
  for (int p = 0; p < 8; p++) {
    int cl = cch + 2*p;
    float f0 = ts[cl][srow] * scl[cl] + sft[cl];
    float f1 = ts[cl+1][srow] * scl[cl+1] + sft[cl+1];
    *(unsigned*)&gnT[(size_t)(s0 + srow)*320 + c0 + cl] = pack2(f0, f1);
  }
}

// ---------------- LayerNorm bf16->bf16: one wave per row of 320 ----------------
__global__ __launch_bounds__(64) void layernorm_kernel(
    const u16* __restrict__ X, const float* __restrict__ s,
    const float* __restrict__ b, u16* __restrict__ Y) {
  int row = blockIdx.x, t = threadIdx.x;
  const u16* xr = X + (size_t)row*320;
  float v[5], sum = 0.f, sq = 0.f;
  #pragma unroll
  for (int i = 0; i < 5; i++) { v[i] = bfu2f(xr[t + 64*i]); sum += v[i]; sq += v[i]*v[i]; }
  #pragma unroll
  for (int o = 32; o > 0; o >>= 1) { sum += __shfl_down(sum, o); sq += __shfl_down(sq, o); }
  sum = __shfl(sum, 0); sq = __shfl(sq, 0);
  float mu = sum * (1.f/320.f);
  float var = sq * (1.f/320.f) - mu*mu;
  float rs = rsqrtf(var + 1e-5f);
  u16* yr = Y + (size_t)row*320;
  #pragma unroll
  for (int i = 0; i < 5; i++) {
    int c = t + 64*i;
    yr[c] = f2bf((v[i]-mu)*rs*s[c] + b[c]);
  }
}

// ---------------- MFMA GEMM: C[M,N] = A[M,K](bf16) * BT[N,K](bf16)^T ----------------
// MODE 0: bf16 out C[m*N+n], optional fp32 bias[n], optional bf16 res
// MODE 1: bf16 out segmented (seg = bn/320, Cout + seg*segStride + m*320 + col%320)
// MODE 2: proj_out: fp32 out[n*4096+m] = acc + bias[n] + xres[n*4096+m]
// MODE 3: QKV: segs 0,1 like MODE 1 (q,k); seg 2 -> vT[(col%320)][m] transposed (ptr in xres)
template<int MODE>
__global__ __launch_bounds__(256) void mgemm(
    const u16* __restrict__ A, const u16* __restrict__ BT,
    const float* __restrict__ bias, const u16* __restrict__ res,
    const float* __restrict__ xres, void* __restrict__ Cout,
    int M, int N, int K, int segStride) {
  __shared__ __align__(16) u16 smem[2*64*72];
  u16* As = smem;
  u16* Bs = smem + 64*72;
  const int t = threadIdx.x;
  const int lane = t & 63, w = t >> 6, l16 = lane & 15, g = lane >> 4;
  const int bm = blockIdx.x * 64, bn = blockIdx.y * 64;
  const int m0 = (w & 1) * 32, n0 = (w >> 1) * 32;
  float4v acc[2][2] = {};
  const int ar = t >> 2, ac = (t & 3) * 16;
  const bool aok = (bm + ar) < M;

  for (int k0 = 0; k0 < K; k0 += 64) {
    __syncthreads();
    short8v a0 = {}, a1 = {};
    if (aok) {
      const u16* ga = &A[(size_t)(bm + ar)*K + k0 + ac];
      a0 = *(const short8v*)ga; a1 = *(const short8v*)(ga + 8);
    }
    *(short8v*)&As[ar*72 + ac] = a0;
    *(short8v*)&As[ar*72 + ac + 8] = a1;
    const u16* gbp = &BT[(size_t)(bn + ar)*K + k0 + ac];
    *(short8v*)&Bs[ar*72 + ac] = *(const short8v*)gbp;
    *(short8v*)&Bs[ar*72 + ac + 8] = *(const short8v*)(gbp + 8);
    __syncthreads();
    #pragma unroll
    for (int ks = 0; ks < 2; ks++) {
      short8v af[2], bfv[2];
      #pragma unroll
      for (int mt = 0; mt < 2; mt++)
        af[mt] = *(const short8v*)&As[(m0 + 16*mt + l16)*72 + ks*32 + g*8];
      #pragma unroll
      for (int nt = 0; nt < 2; nt++)
        bfv[nt] = *(const short8v*)&Bs[(n0 + 16*nt + l16)*72 + ks*32 + g*8];
      #pragma unroll
      for (int mt = 0; mt < 2; mt++)
        #pragma unroll
        for (int nt = 0; nt < 2; nt++)
          acc[mt][nt] = __builtin_amdgcn_mfma_f32_16x16x32_bf16(af[mt], bfv[nt], acc[mt][nt], 0, 0, 0);
    }
  }
  __syncthreads();
  float* Cs = (float*)smem;  // [64][68]
  #pragma unroll
  for (int mt = 0; mt < 2; mt++)
    #pragma unroll
    for (int nt = 0; nt < 2; nt++)
      #pragma unroll
      for (int r = 0; r < 4; r++)
        Cs[(m0 + 16*mt + 4*g + r)*68 + n0 + 16*nt + l16] = acc[mt][nt][r];
  __syncthreads();

  if (MODE == 0) {
    u16* C = (u16*)Cout;
    #pragma unroll
    for (int i = 0; i < 8; i++) {
      int p = t + i*256;
      int mm = p >> 5, nn = (p & 31)*2;
      int gm = bm + mm;
      if (gm >= M) continue;
      float f0 = Cs[mm*68 + nn], f1 = Cs[mm*68 + nn + 1];
      if (bias) { f0 += bias[bn + nn]; f1 += bias[bn + nn + 1]; }
      if (res) {
        unsigned u = *(const unsigned*)&res[(size_t)gm*N + bn + nn];
        f0 += bfu2f((u16)(u & 0xffffu));
        f1 += bfu2f((u16)(u >> 16));
      }
      *(unsigned*)&C[(size_t)gm*N + bn + nn] = pack2(f0, f1);
    }
  } else if (MODE == 1) {
    u16* C = (u16*)Cout + (size_t)(bn / 320) * segStride;
    int nb = bn % 320;
    #pragma unroll
    for (int i = 0; i < 8; i++) {
      int p = t + i*256;
      int mm = p >> 5, nn = (p & 31)*2;
      int gm = bm + mm;
      if (gm >= M) continue;
      *(unsigned*)&C[(size_t)gm*320 + nb + nn] = pack2(Cs[mm*68 + nn], Cs[mm*68 + nn + 1]);
    }
  } else if (MODE == 3) {
    if (bn < 640) {
      u16* C = (u16*)Cout + (size_t)(bn / 320) * segStride;
      int nb = bn % 320;
      #pragma unroll
      for (int i = 0; i < 8; i++) {
        int p = t + i*256;
        int mm = p >> 5, nn = (p & 31)*2;
        *(unsigned*)&C[(size_t)(bm + mm)*320 + nb + nn] = pack2(Cs[mm*68 + nn], Cs[mm*68 + nn + 1]);
      }
    } else {
      u16* vTp = (u16*)(void*)xres;
      int nloc = t >> 2, mch = (t & 3) * 16;
      int vd = bn - 640 + nloc;
      u16* dst = vTp + (size_t)vd*4096 + bm + mch;
      unsigned buf[8];
      #pragma unroll
      for (int jj = 0; jj < 8; jj++)
        buf[jj] = pack2(Cs[(mch + 2*jj)*68 + nloc], Cs[(mch + 2*jj + 1)*68 + nloc]);
      uint4 o0; o0.x = buf[0]; o0.y = buf[1]; o0.z = buf[2]; o0.w = buf[3];
      uint4 o1; o1.x = buf[4]; o1.y = buf[5]; o1.z = buf[6]; o1.w = buf[7];
      *(uint4*)dst = o0;
      *(uint4*)(dst + 8) = o1;
    }
  } else {
    float* C = (float*)Cout;
    int nloc = t >> 2, mch = (t & 3) * 16;
    float bb = bias[bn + nloc];
    #pragma unroll
    for (int j = 0; j < 4; j++) {
      int m4 = mch + j*4;
      float4 xv = *(const float4*)&xres[(size_t)(bn + nloc)*4096 + bm + m4];
      float4 ov;
      ov.x = Cs[(m4+0)*68 + nloc] + bb + xv.x;
      ov.y = Cs[(m4+1)*68 + nloc] + bb + xv.y;
      ov.z = Cs[(m4+2)*68 + nloc] + bb + xv.z;
      ov.w = Cs[(m4+3)*68 + nloc] + bb + xv.w;
      *(float4*)&C[(size_t)(bn + nloc)*4096 + bm + m4] = ov;
    }
  }
}

// ---------------- GEGLU MFMA ----------------
__global__ __launch_bounds__(256) void geglu_mfma(
    const u16* __restrict__ A, const u16* __restrict__ BT,
    const float* __restrict__ bias, u16* __restrict__ C) {
  __shared__ __align__(16) u16 smem[3*64*72];
  u16* As = smem;
  u16* Ba = smem + 64*72;
  u16* Bg = smem + 2*64*72;
  const int t = threadIdx.x;
  const int lane = t & 63, w = t >> 6, l16 = lane & 15, g = lane >> 4;
  const int bm = blockIdx.x * 64, bn = blockIdx.y * 64;
  const int m0 = (w & 1) * 32, n0 = (w >> 1) * 32;
  float4v aacc[2][2] = {}, gacc[2][2] = {};
  const int ar = t >> 2, ac = (t & 3) * 16;

  for (int k0 = 0; k0 < 320; k0 += 64) {
    __syncthreads();
    {
      const u16* ga = &A[(size_t)(bm + ar)*320 + k0 + ac];
      *(short8v*)&As[ar*72 + ac] = *(const short8v*)ga;
      *(short8v*)&As[ar*72 + ac + 8] = *(const short8v*)(ga + 8);
      const u16* gba = &BT[(size_t)(bn + ar)*320 + k0 + ac];
      *(short8v*)&Ba[ar*72 + ac] = *(const short8v*)gba;
      *(short8v*)&Ba[ar*72 + ac + 8] = *(const short8v*)(gba + 8);
      const u16* gbg = &BT[(size_t)(1280 + bn + ar)*320 + k0 + ac];
      *(short8v*)&Bg[ar*72 + ac] = *(const short8v*)gbg;
      *(short8v*)&Bg[ar*72 + ac + 8] = *(const short8v*)(gbg + 8);
    }
    __syncthreads();
    #pragma unroll
    for (int ks = 0; ks < 2; ks++) {
      short8v af[2], bav[2], bgv[2];
      #pragma unroll
      for (int mt = 0; mt < 2; mt++)
        af[mt] = *(const short8v*)&As[(m0 + 16*mt + l16)*72 + ks*32 + g*8];
      #pragma unroll
      for (int nt = 0; nt < 2; nt++) {
        bav[nt] = *(const short8v*)&Ba[(n0 + 16*nt + l16)*72 + ks*32 + g*8];
        bgv[nt] = *(const short8v*)&Bg[(n0 + 16*nt + l16)*72 + ks*32 + g*8];
      }
      #pragma unroll
      for (int mt = 0; mt < 2; mt++)
        #pragma unroll
        for (int nt = 0; nt < 2; nt++) {
          aacc[mt][nt] = __builtin_amdgcn_mfma_f32_16x16x32_bf16(af[mt], bav[nt], aacc[mt][nt], 0, 0, 0);
          gacc[mt][nt] = __builtin_amdgcn_mfma_f32_16x16x32_bf16(af[mt], bgv[nt], gacc[mt][nt], 0, 0, 0);
        }
    }
  }
  __syncthreads();
  float* Cs = (float*)smem;
  #pragma unroll
  for (int nt = 0; nt < 2; nt++) {
    int col = n0 + 16*nt + l16;
    float ba = bias[bn + col];
    float bg2 = bias[1280 + bn + col];
    #pragma unroll
    for (int mt = 0; mt < 2; mt++)
      #pragma unroll
      for (int r = 0; r < 4; r++) {
        float a = aacc[mt][nt][r] + ba;
        float gv = gacc[mt][nt][r] + bg2;
        float gl = 0.5f * gv * (1.f + erff(gv * 0.70710678118654752f));
        Cs[(m0 + 16*mt + 4*g + r)*68 + col] = a * gl;
      }
  }
  __syncthreads();
  #pragma unroll
  for (int i = 0; i < 8; i++) {
    int p = t + i*256;
    int mm = p >> 5, nn = (p & 31)*2;
    *(unsigned*)&C[(size_t)(bm + mm)*1280 + bn + nn] = pack2(Cs[mm*68 + nn], Cs[mm*68 + nn + 1]);
  }
}

// ---------------- Self-attention partial: barrier-free, global-direct frags ----------------
// K [4096][320] bf16 (per-head cols h*40..), vT [320][4096] bf16 (row h*40+d).
// Grid (64 qtiles, 8 heads, 4 splits); 4 waves/block, each wave = 16 queries, independent.
__global__ __launch_bounds__(256) void self_attn_part(
    const u16* __restrict__ Q, const u16* __restrict__ K,
    const u16* __restrict__ vT, float* __restrict__ Opart,
    float* __restrict__ Mp, float* __restrict__ Lp) {
  const int h = blockIdx.y;
  const int q0 = blockIdx.x * 64;
  const int sp = blockIdx.z;
  const int tid = threadIdx.x;
  const int w = tid >> 6, lane = tid & 63;
  const int l16 = lane & 15, g = lane >> 4;

  __shared__ __align__(16) u16 PsT[4][16][72];   // wave-private P^T

  short8v Qb[2];
  {
    const u16* qrow = Q + (size_t)(q0 + w*16 + l16)*320 + h*40;
    Qb[0] = *(const short8v*)(qrow + g*8);
    short8v z = {};
    Qb[1] = (g == 0) ? *(const short8v*)(qrow + 32) : z;
  }

  const u16* Kb  = K  + (size_t)(sp*1024 + l16)*320 + h*40 + g*8;  // + key*320
  const u16* Vb  = vT + (size_t)(h*40 + l16)*4096 + sp*1024 + g*8; // + d*4096 + key

  float m_i = -1e30f, l_i = 0.f;
  float4v Of[3] = {};

  for (int kt = 0; kt < 1024; kt += 64) {
    // S^T = K·Q^T, A-frags direct from global
    float4v Sf[4];
    #pragma unroll
    for (int mt = 0; mt < 4; mt++) {
      const u16* kp = Kb + (size_t)(kt + mt*16)*320;
      short8v ka0 = *(const short8v*)kp;
      short8v ka1 = *(const short8v*)(kp + 32);
      float4v s = {};
      s = __builtin_amdgcn_mfma_f32_16x16x32_bf16(ka0, Qb[0], s, 0, 0, 0);
      s = __builtin_amdgcn_mfma_f32_16x16x32_bf16(ka1, Qb[1], s, 0, 0, 0);
      Sf[mt] = s;
    }

    // online softmax (lane-scalar per query l16)
    float mx = -1e30f;
    #pragma unroll
    for (int mt = 0; mt < 4; mt++)
      #pragma unroll
      for (int r = 0; r < 4; r++) mx = fmaxf(mx, Sf[mt][r]);
    mx = fmaxf(mx, __shfl_xor(mx, 16));
    mx = fmaxf(mx, __shfl_xor(mx, 32));
    float mnew = fmaxf(m_i, mx);
    float alpha = __expf((m_i - mnew) * SCALE_ATTN);
    float rsum = 0.f;
    #pragma unroll
    for (int mt = 0; mt < 4; mt++)
      #pragma unroll
      for (int r = 0; r < 4; r++) {
        float p = __expf((Sf[mt][r] - mnew) * SCALE_ATTN);
        Sf[mt][r] = p; rsum += p;
      }
    rsum += __shfl_xor(rsum, 16);
    rsum += __shfl_xor(rsum, 32);
    l_i = l_i * alpha + rsum;
    m_i = mnew;
    #pragma unroll
    for (int mt = 0; mt < 3; mt++)
      #pragma unroll
      for (int r = 0; r < 4; r++) Of[mt][r] *= alpha;

    // P^T -> LDS (wave-private; same-wave DS ordering, no block barrier)
    #pragma unroll
    for (int mt = 0; mt < 4; mt++) {
      uint2 pk;
      pk.x = pack2(Sf[mt][0], Sf[mt][1]);
      pk.y = pack2(Sf[mt][2], Sf[mt][3]);
      *(uint2*)&PsT[w][l16][mt*16 + 4*g] = pk;
    }
    asm volatile("s_waitcnt lgkmcnt(0)" ::: "memory");

    // O^T += V^T·P^T, A-frags direct from global vT
    #pragma unroll
    for (int ks = 0; ks < 2; ks++) {
      short8v pb = *(const short8v*)&PsT[w][l16][ks*32 + g*8];
      #pragma unroll
      for (int mt = 0; mt < 3; mt++) {
        const u16* vp = Vb + (size_t)(mt*16)*4096 + kt + ks*32;
        short8v va = *(const short8v*)vp;
        Of[mt] = __builtin_amdgcn_mfma_f32_16x16x32_bf16(va, pb, Of[mt], 0, 0, 0);
      }
    }
  }

  // store unnormalized partial O^T + m,l
  const int q = q0 + w*16 + l16;
  float* orow = Opart + (size_t)sp*4096*320 + (size_t)q*320 + h*40;
  #pragma unroll
  for (int mt = 0; mt < 3; mt++) {
    #pragma unroll
    for (int rp = 0; rp < 2; rp++) {
      int d = mt*16 + 4*g + rp*2;
      if (d < 40) {
        float2 val = { Of[mt][rp*2], Of[mt][rp*2+1] };
        *(float2*)&orow[d] = val;
      }
    }
  }
  if (g == 0) {
    Mp[sp*32768 + q*8 + h] = m_i;
    Lp[sp*32768 + q*8 + h] = l_i;
  }
}

// ---------------- merge 4 partials -> ao bf16 ----------------
__global__ __launch_bounds__(256) void attn_merge(
    const float* __restrict__ Opart, const float* __restrict__ Mp,
    const float* __restrict__ Lp, u16* __restrict__ O) {
  int gid = blockIdx.x*256 + threadIdx.x;   // < 4096*8*20
  int dp = gid % 20;
  int qh = gid / 20;
  int q = qh >> 3, h = qh & 7;
  float m0 = Mp[qh], m1 = Mp[32768 + qh], m2 = Mp[2*32768 + qh], m3 = Mp[3*32768 + qh];
  float ms = fmaxf(fmaxf(m0, m1), fmaxf(m2, m3));
  float w0 = __expf((m0 - ms) * SCALE_ATTN);
  float w1 = __expf((m1 - ms) * SCALE_ATTN);
  float w2 = __expf((m2 - ms) * SCALE_ATTN);
  float w3 = __expf((m3 - ms) * SCALE_ATTN);
  float ls = Lp[qh]*w0 + Lp[32768 + qh]*w1 + Lp[2*32768 + qh]*w2 + Lp[3*32768 + qh]*w3;
  size_t base = (size_t)q*320 + h*40 + dp*2;
  const size_t HBf = 4096u*320u;
  float2 o0 = *(const float2*)&Opart[base];
  float2 o1 = *(const float2*)&Opart[HBf + base];
  float2 o2 = *(const float2*)&Opart[2*HBf + base];
  float2 o3 = *(const float2*)&Opart[3*HBf + base];
  float inv = 1.f / ls;
  float r0 = (o0.x*w0 + o1.x*w1 + o2.x*w2 + o3.x*w3) * inv;
  float r1 = (o0.y*w0 + o1.y*w1 + o2.y*w2 + o3.y*w3) * inv;
  *(unsigned*)&O[base] = pack2(r0, r1);
}

// ---------------- Cross-attention: single-shot MFMA, 77 keys (pad 80/96) ----------------
__global__ __launch_bounds__(256) void cross_attn_mfma(
    const u16* __restrict__ Q, const u16* __restrict__ Kc,
    const u16* __restrict__ Vc, u16* __restrict__ O) {
  const int h = blockIdx.y;
  const int q0 = blockIdx.x * 64;
  const int tid = threadIdx.x;
  const int w = tid >> 6, lane = tid & 63;
  const int l16 = lane & 15, g = lane >> 4;

  __shared__ __align__(16) u16 Kls[80][72];
  __shared__ __align__(16) u16 Vt[48][104];
  __shared__ __align__(16) u16 PsT[4][16][104];

  for (int e = tid; e < 80*12; e += 256) {
    int r = e / 12, c = e % 12;
    *(unsigned*)&Kls[r][40 + 2*c] = 0u;
  }
  for (int e = tid; e < 48*52; e += 256) {
    int r = e / 52, c = e % 52;
    *(unsigned*)&Vt[r][2*c] = 0u;
  }
  {
    int r = lane >> 2, c4 = (lane & 3)*4;
    uint2 z; z.x = 0u; z.y = 0u;
    *(uint2*)&PsT[w][r][80 + c4] = z;
  }

  short8v Qb[2];
  {
    const u16* qrow = Q + (size_t)(q0 + w*16 + l16)*320 + h*40;
    Qb[0] = *(const short8v*)(qrow + g*8);
    short8v z = {};
    Qb[1] = (g == 0) ? *(const short8v*)(qrow + 32) : z;
  }

  for (int e = tid; e < 1600; e += 256) {
    int key = e / 20, dp = e % 20;
    unsigned val = 0u;
    if (key < 77) val = *(const unsigned*)&Kc[(size_t)key*320 + h*40 + dp*2];
    *(unsigned*)&Kls[key][dp*2] = val;
  }
  __syncthreads();
  for (int e = tid; e < 1600; e += 256) {
    int kp = e / 40, d = e % 40;
    unsigned u0 = (kp*2     < 77) ? (unsigned)Vc[(size_t)(kp*2    )*320 + h*40 + d] : 0u;
    unsigned u1 = (kp*2 + 1 < 77) ? (unsigned)Vc[(size_t)(kp*2 + 1)*320 + h*40 + d] : 0u;
    *(unsigned*)&Vt[d][kp*2] = u0 | (u1 << 16);
  }
  __syncthreads();

  float4v Sf[5];
  #pragma unroll
  for (int mt = 0; mt < 5; mt++) {
    short8v ka0 = *(const short8v*)&Kls[mt*16 + l16][g*8];
    short8v ka1 = *(const short8v*)&Kls[mt*16 + l16][32 + g*8];
    float4v s = {};
    s = __builtin_amdgcn_mfma_f32_16x16x32_bf16(ka0, Qb[0], s, 0, 0, 0);
    s = __builtin_amdgcn_mfma_f32_16x16x32_bf16(ka1, Qb[1], s, 0, 0, 0);
    Sf[mt] = s;
  }

  float mx = -1e30f;
  #pragma unroll
  for (int mt = 0; mt < 5; mt++)
    #pragma unroll
    for (int r = 0; r < 4; r++) {
      int key = mt*16 + 4*g + r;
      if (key >= 77) Sf[mt][r] = -1e30f;
      mx = fmaxf(mx, Sf[mt][r]);
    }
  mx = fmaxf(mx, __shfl_xor(mx, 16));
  mx = fmaxf(mx, __shfl_xor(mx, 32));
  float rsum = 0.f;
  #pragma unroll
  for (int mt = 0; mt < 5; mt++)
    #pragma unroll
    for (int r = 0; r < 4; r++) {
      float p = __expf((Sf[mt][r] - mx) * SCALE_ATTN);
      Sf[mt][r] = p; rsum += p;
    }
  rsum += __shfl_xor(rsum, 16);
  rsum += __shfl_xor(rsum, 32);

  #pragma unroll
  for (int mt = 0; mt < 5; mt++) {
    uint2 pk;
    pk.x = pack2(Sf[mt][0], Sf[mt][1]);
    pk.y = pack2(Sf[mt][2], Sf[mt][3]);
    *(uint2*)&PsT[w][l16][mt*16 + 4*g] = pk;
  }
  __syncthreads();

  float4v Of[3] = {};
  #pragma unroll
  for (int ks = 0; ks < 3; ks++) {
    short8v pb = *(const short8v*)&PsT[w][l16][ks*32 + g*8];
    #pragma unroll
    for (int mt = 0; mt < 3; mt++) {
      short8v va = *(const short8v*)&Vt[mt*16 + l16][ks*32 + g*8];
      Of[mt] = __builtin_amdgcn_mfma_f32_16x16x32_bf16(va, pb, Of[mt], 0, 0, 0);
    }
  }

  float inv = 1.f / rsum;
  u16* orow = O + (size_t)(q0 + w*16 + l16)*320 + h*40;
  #pragma unroll
  for (int mt = 0; mt < 3; mt++) {
    #pragma unroll
    for (int rp = 0; rp < 2; rp++) {
      int d = mt*16 + 4*g + rp*2;
      if (d < 40)
        *(unsigned*)&orow[d] = pack2(Of[mt][rp*2] * inv, Of[mt][rp*2+1] * inv);
    }
  }
}

extern "C" void kernel_launch(void* const* d_in, const int* in_sizes, int n_in,
                              void* d_out, int out_size, void* d_ws, size_t ws_size,
                              hipStream_t stream) {
  const float* x        = (const float*)d_in[0];
  const float* ctx      = (const float*)d_in[1];
  const float* gn_s     = (const float*)d_in[2];
  const float* gn_b     = (const float*)d_in[3];
  const float* w_pin    = (const float*)d_in[4];
  const float* b_pin    = (const float*)d_in[5];
  const float* ln1_s    = (const float*)d_in[6];
  const float* ln1_b    = (const float*)d_in[7];
  const float* wq1      = (const float*)d_in[8];
  const float* wk1      = (const float*)d_in[9];
  const float* wv1      = (const float*)d_in[10];
  const float* wo1      = (const float*)d_in[11];
  const float* bo1      = (const float*)d_in[12];
  const float* ln2_s    = (const float*)d_in[13];
  const float* ln2_b    = (const float*)d_in[14];
  const float* wq2      = (const float*)d_in[15];
  const float* wk2      = (const float*)d_in[16];
  const float* wv2      = (const float*)d_in[17];
  const float* wo2      = (const float*)d_in[18];
  const float* bo2      = (const float*)d_in[19];
  const float* ln3_s    = (const float*)d_in[20];
  const float* ln3_b    = (const float*)d_in[21];
  const float* w_ff1    = (const float*)d_in[22];
  const float* b_ff1    = (const float*)d_in[23];
  const float* w_ff2    = (const float*)d_in[24];
  const float* b_ff2    = (const float*)d_in[25];
  const float* w_pout   = (const float*)d_in[26];
  const float* b_pout   = (const float*)d_in[27];
  float* out = (float*)d_out;

  u16* ws = (u16*)d_ws;
  const size_t HB = 4096u*320u;
  u16* h   = ws;
  u16* hn  = ws + HB;
  u16* q   = ws + 2*HB;    // q,k contiguous (QKV fused epilogue)
  u16* k   = ws + 3*HB;
  u16* vT  = ws + 4*HB;    // V^T [320][4096] (d>=40 head-overflow reads spill into ao: finite)
  u16* ao  = ws + 5*HB;
  u16* gnT = k;
  u16* gg  = q;            // GEGLU out overlays q,k,vT,ao
  u16* wb  = ws + 6*HB;
  size_t o = 0;
  u16* ctxb   = wb + o; o += 59136;
  u16* wq1T   = wb + o; o += 102400;   // stacked: wq1T,wk1T,wv1T = [960][320]
  u16* wk1T   = wb + o; o += 102400;
  u16* wv1T   = wb + o; o += 102400;
  u16* wo1T   = wb + o; o += 102400;
  u16* wq2T   = wb + o; o += 102400;
  u16* wk2T   = wb + o; o += 245760;   // stacked: wk2T,wv2T = [640][768]
  u16* wv2T   = wb + o; o += 245760;
  u16* wo2T   = wb + o; o += 102400;
  u16* wff1T  = wb + o; o += 819200;
  u16* wff2T  = wb + o; o += 409600;
  u16* wpoutT = wb + o; o += 102400;
  u16* wpinT  = wb + o; o += 102400;
  u16* kc     = wb + o; o += 24640;    // kc,vc contiguous, segStride 24640
  u16* vc     = wb + o; o += 24640;
  float* chscale = (float*)(wb + o);
  float* chshift = chscale + 320;
  float* Opart = chshift + 320;        // 4 x 4096 x 320 fp32 = 21 MB
  float* Mpart = Opart + 4*HB;
  float* Lpart = Mpart + 4*32768;

  TPack tp;
  const float* srcs[12] = {wq1, wk1, wv1, wo1, wq2, wo2, w_pin, w_pout, wk2, wv2, w_ff1, w_ff2};
  u16* dsts[12]         = {wq1T, wk1T, wv1T, wo1T, wq2T, wo2T, wpinT, wpoutT, wk2T, wv2T, wff1T, wff2T};
  int Ks[12] = {320,320,320,320,320,320,320,320,768,768,320,1280};
  int Ns[12] = {320,320,320,320,320,320,320,320,320,320,2560,320};
  int off = 0;
  for (int i = 0; i < 12; i++) {
    tp.d[i].src = srcs[i]; tp.d[i].dst = dsts[i];
    tp.d[i].K = Ks[i]; tp.d[i].N = Ns[i];
    tp.d[i].off = off; tp.d[i].tx = Ns[i]/32;
    off += (Ks[i]/32)*(Ns[i]/32);
  }

  dim3 blk(256), g64x5(64, 5);
  const u16* nres = nullptr;
  const float* nb = nullptr;

  // prep: weight tcvt (off blocks) + ctx cvt (58) + gn stats (32)
  hipLaunchKernelGGL(prep_kernel, dim3(off + 58 + 32), blk, 0, stream,
                     tp, off, ctx, ctxb, x, gn_s, gn_b, chscale, chshift);
  hipLaunchKernelGGL(gn_apply_t_kernel, g64x5, blk, 0, stream, x, chscale, chshift, gnT);
  hipLaunchKernelGGL((mgemm<0>), g64x5, blk, 0, stream, gnT, wpinT, b_pin, nres, nb, (void*)h, 4096, 320, 320, 0);
  hipLaunchKernelGGL(layernorm_kernel, dim3(4096), dim3(64), 0, stream, h, ln1_s, ln1_b, hn);
  // fused QKV: N=960; segs 0,1 -> q,k; seg 2 -> vT (transposed)
  hipLaunchKernelGGL((mgemm<3>), dim3(64, 15), blk, 0, stream, hn, wq1T, nb, nres, (const float*)vT, (void*)q, 4096, 960, 320, (int)HB);
  hipLaunchKernelGGL(self_attn_part, dim3(64, 8, 4), blk, 0, stream, q, k, vT, Opart, Mpart, Lpart);
  hipLaunchKernelGGL(attn_merge, dim3(2560), blk, 0, stream, Opart, Mpart, Lpart, ao);
  hipLaunchKernelGGL((mgemm<0>), g64x5, blk, 0, stream, ao, wo1T, bo1, h, nb, (void*)h, 4096, 320, 320, 0);
  hipLaunchKernelGGL(layernorm_kernel, dim3(4096), dim3(64), 0, stream, h, ln2_s, ln2_b, hn);
  hipLaunchKernelGGL((mgemm<0>), g64x5, blk, 0, stream, hn, wq2T, nb, nres, nb, (void*)q, 4096, 320, 320, 0);
  hipLaunchKernelGGL((mgemm<1>), dim3(2, 10), blk, 0, stream, ctxb, wk2T, nb, nres, nb, (void*)kc, 77, 640, 768, 24640);
  hipLaunchKernelGGL(cross_attn_mfma, dim3(64, 8), blk, 0, stream, q, kc, vc, ao);
  hipLaunchKernelGGL((mgemm<0>), g64x5, blk, 0, stream, ao, wo2T, bo2, h, nb, (void*)h, 4096, 320, 320, 0);
  hipLaunchKernelGGL(layernorm_kernel, dim3(4096), dim3(64), 0, stream, h, ln3_s, ln3_b, hn);
  hipLaunchKernelGGL(geglu_mfma, dim3(64, 20), blk, 0, stream, hn, wff1T, b_ff1, gg);
  hipLaunchKernelGGL((mgemm<0>), g64x5, blk, 0, stream, gg, wff2T, b_ff2, h, nb, (void*)h, 4096, 320, 1280, 0);
  hipLaunchKernelGGL((mgemm<2>), g64x5, blk, 0, stream, h, wpoutT, b_pout, nres, x, (void*)out, 4096, 320, 320, 0);
}

// Round 7
// 365.578 us; speedup vs baseline: 1.3160x; 1.3160x over previous
//
#include <hip/hip_runtime.h>
#include <math.h>

#define SCALE_ATTN 0.15811388300841897f
#define SCALE_L2E  0.22811011265722836f   // SCALE_ATTN * log2(e)

typedef __attribute__((ext_vector_type(8))) short short8v;
typedef __attribute__((ext_vector_type(4))) float float4v;
typedef unsigned short u16;

__device__ __forceinline__ u16 f2bf(float x) {
  unsigned u = __float_as_uint(x);
  unsigned r = (u + 0x7FFFu + ((u >> 16) & 1u)) >> 16;
  return (u16)r;
}
__device__ __forceinline__ unsigned pack2(float a, float b) {
  return (unsigned)f2bf(a) | ((unsigned)f2bf(b) << 16);
}
__device__ __forceinline__ float bfu2f(u16 u) {
  return __uint_as_float(((unsigned)u) << 16);
}

// ---------------- prep: weight transpose+convert | ctx cvt | gn stats (block ranges) --------
struct TDesc { const float* src; u16* dst; int K, N, off, tx; };
struct TPack { TDesc d[12]; };

__global__ __launch_bounds__(256) void prep_kernel(
    TPack p, int nT,
    const float* __restrict__ ctxsrc, u16* __restrict__ ctxdst,
    const float* __restrict__ x, const float* __restrict__ gs,
    const float* __restrict__ gb, float* __restrict__ chscale, float* __restrict__ chshift) {
  __shared__ float ls[32][33];
  int bt = blockIdx.x, t = threadIdx.x;
  if (bt < nT) {
    int ti = 0;
    #pragma unroll
    for (int i = 1; i < 12; i++) if (bt >= p.d[i].off) ti = i;
    TDesc dd = p.d[ti];
    int local = bt - dd.off;
    int n0 = (local % dd.tx) * 32, k0 = (local / dd.tx) * 32;
    #pragma unroll
    for (int i = 0; i < 4; i++) {
      int idx = t + i*256, r = idx >> 5, c = idx & 31;
      ls[r][c] = dd.src[(size_t)(k0 + r)*dd.N + n0 + c];
    }
    __syncthreads();
    #pragma unroll
    for (int i = 0; i < 2; i++) {
      int p2 = t + i*256, n = p2 >> 4, kp = (p2 & 15)*2;
      *(unsigned*)&dd.dst[(size_t)(n0 + n)*dd.K + k0 + kp] = pack2(ls[kp][n], ls[kp+1][n]);
    }
  } else if (bt < nT + 58) {
    int idx = ((bt - nT)*256 + t)*4;
    if (idx < 59136) {
      float4 v = *(const float4*)&ctxsrc[idx];
      uint2 o; o.x = pack2(v.x, v.y); o.y = pack2(v.z, v.w);
      *(uint2*)&ctxdst[idx] = o;
    }
  } else {
    int g = bt - nT - 58;
    size_t base = (size_t)g * 40960;
    float sum = 0.f, sq = 0.f;
    for (int e = t; e < 40960; e += 256) {
      float v = x[base + e];
      sum += v; sq += v * v;
    }
    float* s1 = &ls[0][0];
    float* s2 = &ls[8][0] + 8;
    s1[t] = sum; s2[t] = sq; __syncthreads();
    for (int st = 128; st > 0; st >>= 1) {
      if (t < st) { s1[t] += s1[t+st]; s2[t] += s2[t+st]; }
      __syncthreads();
    }
    float mu = s1[0] * (1.f/40960.f);
    float var = s2[0] * (1.f/40960.f) - mu*mu;
    float rs = rsqrtf(var + 1e-6f);
    if (t < 10) {
      int c = g*10 + t;
      float sc = rs * gs[c];
      chscale[c] = sc;
      chshift[c] = gb[c] - mu * sc;
    }
  }
}

// ---------------- GN apply + transpose: x[c][s] fp32 -> gnT[s][c] bf16 ----------------
__global__ __launch_bounds__(256) void gn_apply_t_kernel(
    const float* __restrict__ x, const float* __restrict__ chscale,
    const float* __restrict__ chshift, u16* __restrict__ gnT) {
  __shared__ float ts[64][65];
  __shared__ float scl[64], sft[64];
  int s0 = blockIdx.x * 64, c0 = blockIdx.y * 64;
  int t = threadIdx.x;
  if (t < 64) { scl[t] = chscale[c0 + t]; sft[t] = chshift[c0 + t]; }
  int crow = t >> 2, sch = (t & 3) * 16;
  #pragma unroll
  for (int j = 0; j < 4; j++) {
    float4 v = *(const float4*)&x[(size_t)(c0 + crow)*4096 + s0 + sch + 4*j];
    ts[crow][sch + 4*j + 0] = v.x; ts[crow][sch + 4*j + 1] = v.y;
    ts[crow][sch + 4*j + 2] = v.z; ts[crow][sch + 4*j + 3] = v.w;
  }
  __syncthreads();
  int srow = t >> 2, cch = (t & 3) * 16;
  #pragma unroll
  for (int p = 0; p < 8; p++) {
    int cl = cch + 2*p;
    float f0 = ts[cl][srow] * scl[cl] + sft[cl];
    float f1 = ts[cl+1][srow] * scl[cl+1] + sft[cl+1];
    *(unsigned*)&gnT[(size_t)(s0 + srow)*320 + c0 + cl] = pack2(f0, f1);
  }
}

// ---------------- LayerNorm bf16->bf16: one wave per row of 320 ----------------
__global__ __launch_bounds__(64) void layernorm_kernel(
    const u16* __restrict__ X, const float* __restrict__ s,
    const float* __restrict__ b, u16* __restrict__ Y) {
  int row = blockIdx.x, t = threadIdx.x;
  const u16* xr = X + (size_t)row*320;
  float v[5], sum = 0.f, sq = 0.f;
  #pragma unroll
  for (int i = 0; i < 5; i++) { v[i] = bfu2f(xr[t + 64*i]); sum += v[i]; sq += v[i]*v[i]; }
  #pragma unroll
  for (int o = 32; o > 0; o >>= 1) { sum += __shfl_down(sum, o); sq += __shfl_down(sq, o); }
  sum = __shfl(sum, 0); sq = __shfl(sq, 0);
  float mu = sum * (1.f/320.f);
  float var = sq * (1.f/320.f) - mu*mu;
  float rs = rsqrtf(var + 1e-5f);
  u16* yr = Y + (size_t)row*320;
  #pragma unroll
  for (int i = 0; i < 5; i++) {
    int c = t + 64*i;
    yr[c] = f2bf((v[i]-mu)*rs*s[c] + b[c]);
  }
}

// ---------------- MFMA GEMM: C[M,N] = A[M,K](bf16) * BT[N,K](bf16)^T ----------------
// MODE 0: bf16 out C[m*N+n], optional fp32 bias[n], optional bf16 res
// MODE 1: bf16 out segmented (seg = bn/320, Cout + seg*segStride + m*320 + col%320)
// MODE 2: proj_out: fp32 out[n*4096+m] = acc + bias[n] + xres[n*4096+m]
// MODE 3: QKV: segs 0,1 like MODE 1 (q,k); seg 2 -> vT[(col%320)][m] transposed (ptr in xres)
template<int MODE>
__global__ __launch_bounds__(256) void mgemm(
    const u16* __restrict__ A, const u16* __restrict__ BT,
    const float* __restrict__ bias, const u16* __restrict__ res,
    const float* __restrict__ xres, void* __restrict__ Cout,
    int M, int N, int K, int segStride) {
  __shared__ __align__(16) u16 smem[2*64*72];
  u16* As = smem;
  u16* Bs = smem + 64*72;
  const int t = threadIdx.x;
  const int lane = t & 63, w = t >> 6, l16 = lane & 15, g = lane >> 4;
  const int bm = blockIdx.x * 64, bn = blockIdx.y * 64;
  const int m0 = (w & 1) * 32, n0 = (w >> 1) * 32;
  float4v acc[2][2] = {};
  const int ar = t >> 2, ac = (t & 3) * 16;
  const bool aok = (bm + ar) < M;

  for (int k0 = 0; k0 < K; k0 += 64) {
    __syncthreads();
    short8v a0 = {}, a1 = {};
    if (aok) {
      const u16* ga = &A[(size_t)(bm + ar)*K + k0 + ac];
      a0 = *(const short8v*)ga; a1 = *(const short8v*)(ga + 8);
    }
    *(short8v*)&As[ar*72 + ac] = a0;
    *(short8v*)&As[ar*72 + ac + 8] = a1;
    const u16* gbp = &BT[(size_t)(bn + ar)*K + k0 + ac];
    *(short8v*)&Bs[ar*72 + ac] = *(const short8v*)gbp;
    *(short8v*)&Bs[ar*72 + ac + 8] = *(const short8v*)(gbp + 8);
    __syncthreads();
    #pragma unroll
    for (int ks = 0; ks < 2; ks++) {
      short8v af[2], bfv[2];
      #pragma unroll
      for (int mt = 0; mt < 2; mt++)
        af[mt] = *(const short8v*)&As[(m0 + 16*mt + l16)*72 + ks*32 + g*8];
      #pragma unroll
      for (int nt = 0; nt < 2; nt++)
        bfv[nt] = *(const short8v*)&Bs[(n0 + 16*nt + l16)*72 + ks*32 + g*8];
      #pragma unroll
      for (int mt = 0; mt < 2; mt++)
        #pragma unroll
        for (int nt = 0; nt < 2; nt++)
          acc[mt][nt] = __builtin_amdgcn_mfma_f32_16x16x32_bf16(af[mt], bfv[nt], acc[mt][nt], 0, 0, 0);
    }
  }
  __syncthreads();
  float* Cs = (float*)smem;  // [64][68]
  #pragma unroll
  for (int mt = 0; mt < 2; mt++)
    #pragma unroll
    for (int nt = 0; nt < 2; nt++)
      #pragma unroll
      for (int r = 0; r < 4; r++)
        Cs[(m0 + 16*mt + 4*g + r)*68 + n0 + 16*nt + l16] = acc[mt][nt][r];
  __syncthreads();

  if (MODE == 0) {
    u16* C = (u16*)Cout;
    #pragma unroll
    for (int i = 0; i < 8; i++) {
      int p = t + i*256;
      int mm = p >> 5, nn = (p & 31)*2;
      int gm = bm + mm;
      if (gm >= M) continue;
      float f0 = Cs[mm*68 + nn], f1 = Cs[mm*68 + nn + 1];
      if (bias) { f0 += bias[bn + nn]; f1 += bias[bn + nn + 1]; }
      if (res) {
        unsigned u = *(const unsigned*)&res[(size_t)gm*N + bn + nn];
        f0 += bfu2f((u16)(u & 0xffffu));
        f1 += bfu2f((u16)(u >> 16));
      }
      *(unsigned*)&C[(size_t)gm*N + bn + nn] = pack2(f0, f1);
    }
  } else if (MODE == 1) {
    u16* C = (u16*)Cout + (size_t)(bn / 320) * segStride;
    int nb = bn % 320;
    #pragma unroll
    for (int i = 0; i < 8; i++) {
      int p = t + i*256;
      int mm = p >> 5, nn = (p & 31)*2;
      int gm = bm + mm;
      if (gm >= M) continue;
      *(unsigned*)&C[(size_t)gm*320 + nb + nn] = pack2(Cs[mm*68 + nn], Cs[mm*68 + nn + 1]);
    }
  } else if (MODE == 3) {
    if (bn < 640) {
      u16* C = (u16*)Cout + (size_t)(bn / 320) * segStride;
      int nb = bn % 320;
      #pragma unroll
      for (int i = 0; i < 8; i++) {
        int p = t + i*256;
        int mm = p >> 5, nn = (p & 31)*2;
        *(unsigned*)&C[(size_t)(bm + mm)*320 + nb + nn] = pack2(Cs[mm*68 + nn], Cs[mm*68 + nn + 1]);
      }
    } else {
      u16* vTp = (u16*)(void*)xres;
      int nloc = t >> 2, mch = (t & 3) * 16;
      int vd = bn - 640 + nloc;
      u16* dst = vTp + (size_t)vd*4096 + bm + mch;
      unsigned buf[8];
      #pragma unroll
      for (int jj = 0; jj < 8; jj++)
        buf[jj] = pack2(Cs[(mch + 2*jj)*68 + nloc], Cs[(mch + 2*jj + 1)*68 + nloc]);
      uint4 o0; o0.x = buf[0]; o0.y = buf[1]; o0.z = buf[2]; o0.w = buf[3];
      uint4 o1; o1.x = buf[4]; o1.y = buf[5]; o1.z = buf[6]; o1.w = buf[7];
      *(uint4*)dst = o0;
      *(uint4*)(dst + 8) = o1;
    }
  } else {
    float* C = (float*)Cout;
    int nloc = t >> 2, mch = (t & 3) * 16;
    float bb = bias[bn + nloc];
    #pragma unroll
    for (int j = 0; j < 4; j++) {
      int m4 = mch + j*4;
      float4 xv = *(const float4*)&xres[(size_t)(bn + nloc)*4096 + bm + m4];
      float4 ov;
      ov.x = Cs[(m4+0)*68 + nloc] + bb + xv.x;
      ov.y = Cs[(m4+1)*68 + nloc] + bb + xv.y;
      ov.z = Cs[(m4+2)*68 + nloc] + bb + xv.z;
      ov.w = Cs[(m4+3)*68 + nloc] + bb + xv.w;
      *(float4*)&C[(size_t)(bn + nloc)*4096 + bm + m4] = ov;
    }
  }
}

// ---------------- GEGLU MFMA ----------------
__global__ __launch_bounds__(256) void geglu_mfma(
    const u16* __restrict__ A, const u16* __restrict__ BT,
    const float* __restrict__ bias, u16* __restrict__ C) {
  __shared__ __align__(16) u16 smem[3*64*72];
  u16* As = smem;
  u16* Ba = smem + 64*72;
  u16* Bg = smem + 2*64*72;
  const int t = threadIdx.x;
  const int lane = t & 63, w = t >> 6, l16 = lane & 15, g = lane >> 4;
  const int bm = blockIdx.x * 64, bn = blockIdx.y * 64;
  const int m0 = (w & 1) * 32, n0 = (w >> 1) * 32;
  float4v aacc[2][2] = {}, gacc[2][2] = {};
  const int ar = t >> 2, ac = (t & 3) * 16;

  for (int k0 = 0; k0 < 320; k0 += 64) {
    __syncthreads();
    {
      const u16* ga = &A[(size_t)(bm + ar)*320 + k0 + ac];
      *(short8v*)&As[ar*72 + ac] = *(const short8v*)ga;
      *(short8v*)&As[ar*72 + ac + 8] = *(const short8v*)(ga + 8);
      const u16* gba = &BT[(size_t)(bn + ar)*320 + k0 + ac];
      *(short8v*)&Ba[ar*72 + ac] = *(const short8v*)gba;
      *(short8v*)&Ba[ar*72 + ac + 8] = *(const short8v*)(gba + 8);
      const u16* gbg = &BT[(size_t)(1280 + bn + ar)*320 + k0 + ac];
      *(short8v*)&Bg[ar*72 + ac] = *(const short8v*)gbg;
      *(short8v*)&Bg[ar*72 + ac + 8] = *(const short8v*)(gbg + 8);
    }
    __syncthreads();
    #pragma unroll
    for (int ks = 0; ks < 2; ks++) {
      short8v af[2], bav[2], bgv[2];
      #pragma unroll
      for (int mt = 0; mt < 2; mt++)
        af[mt] = *(const short8v*)&As[(m0 + 16*mt + l16)*72 + ks*32 + g*8];
      #pragma unroll
      for (int nt = 0; nt < 2; nt++) {
        bav[nt] = *(const short8v*)&Ba[(n0 + 16*nt + l16)*72 + ks*32 + g*8];
        bgv[nt] = *(const short8v*)&Bg[(n0 + 16*nt + l16)*72 + ks*32 + g*8];
      }
      #pragma unroll
      for (int mt = 0; mt < 2; mt++)
        #pragma unroll
        for (int nt = 0; nt < 2; nt++) {
          aacc[mt][nt] = __builtin_amdgcn_mfma_f32_16x16x32_bf16(af[mt], bav[nt], aacc[mt][nt], 0, 0, 0);
          gacc[mt][nt] = __builtin_amdgcn_mfma_f32_16x16x32_bf16(af[mt], bgv[nt], gacc[mt][nt], 0, 0, 0);
        }
    }
  }
  __syncthreads();
  float* Cs = (float*)smem;
  #pragma unroll
  for (int nt = 0; nt < 2; nt++) {
    int col = n0 + 16*nt + l16;
    float ba = bias[bn + col];
    float bg2 = bias[1280 + bn + col];
    #pragma unroll
    for (int mt = 0; mt < 2; mt++)
      #pragma unroll
      for (int r = 0; r < 4; r++) {
        float a = aacc[mt][nt][r] + ba;
        float gv = gacc[mt][nt][r] + bg2;
        float gl = 0.5f * gv * (1.f + erff(gv * 0.70710678118654752f));
        Cs[(m0 + 16*mt + 4*g + r)*68 + col] = a * gl;
      }
  }
  __syncthreads();
  #pragma unroll
  for (int i = 0; i < 8; i++) {
    int p = t + i*256;
    int mm = p >> 5, nn = (p & 31)*2;
    *(unsigned*)&C[(size_t)(bm + mm)*1280 + bn + nn] = pack2(Cs[mm*68 + nn], Cs[mm*68 + nn + 1]);
  }
}

// ---------------- Self-attention partial: K-split flash MFMA, vectorized LDS staging ----------
// K [4096][320] bf16; vT [320][4096] bf16 (from QKV MODE-3 epilogue).
// Grid (64 qtiles, 8 heads, 4 splits); 4 waves/block; 16 queries/wave.
__global__ __launch_bounds__(256) void self_attn_part(
    const u16* __restrict__ Q, const u16* __restrict__ K,
    const u16* __restrict__ vT, float* __restrict__ Opart,
    float* __restrict__ Mp, float* __restrict__ Lp) {
  const int h = blockIdx.y;
  const int q0 = blockIdx.x * 64;
  const int sp = blockIdx.z;
  const int tid = threadIdx.x;
  const int w = tid >> 6, lane = tid & 63;
  const int l16 = lane & 15, g = lane >> 4;

  __shared__ __align__(16) u16 Kls[64][72];   // [key][d], cols 40..63 zero
  __shared__ __align__(16) u16 Vt[48][72];    // [d][key], rows 40..47 zero
  __shared__ __align__(16) u16 PsT[4][16][72];

  // zero never-restaged pads once
  for (int e = tid; e < 64*12; e += 256) {
    int r = e / 12, c = e % 12;
    *(unsigned*)&Kls[r][40 + 2*c] = 0u;
  }
  for (int e = tid; e < 8*32; e += 256) {
    int r = 40 + (e >> 5), c = e & 31;
    *(unsigned*)&Vt[r][2*c] = 0u;
  }

  short8v Qb[2];
  {
    const u16* qrow = Q + (size_t)(q0 + w*16 + l16)*320 + h*40;
    Qb[0] = *(const short8v*)(qrow + g*8);
    short8v z = {};
    Qb[1] = (g == 0) ? *(const short8v*)(qrow + 32) : z;
  }

  const u16* Kbase = K + (size_t)(sp*1024)*320 + h*40;      // + key*320 + ch*8
  const u16* Vbase = vT + (size_t)(h*40)*4096 + sp*1024;    // + d*4096 + kt + ch*8

  float m_i = -1e30f, l_i = 0.f;
  float4v Of[3] = {};

  for (int kt = 0; kt < 1024; kt += 64) {
    __syncthreads();   // prior tile's LDS reads complete
    // K tile: 320 b128 slots (key 0..63, ch 0..4)
    for (int s = tid; s < 320; s += 256) {
      int key = s / 5, ch = s - key*5;
      *(short8v*)&Kls[key][ch*8] =
        *(const short8v*)&Kbase[(size_t)(kt + key)*320 + ch*8];
    }
    // V^T tile: 320 b128 slots (d 0..39, ch 0..7), row-contiguous global reads
    for (int s = tid; s < 320; s += 256) {
      int d = s >> 3, ch = s & 7;
      *(short8v*)&Vt[d][ch*8] =
        *(const short8v*)&Vbase[(size_t)d*4096 + kt + ch*8];
    }
    __syncthreads();   // staged tiles visible

    // S^T = K·Q^T
    float4v Sf[4];
    #pragma unroll
    for (int mt = 0; mt < 4; mt++) {
      short8v ka0 = *(const short8v*)&Kls[mt*16 + l16][g*8];
      short8v ka1 = *(const short8v*)&Kls[mt*16 + l16][32 + g*8];
      float4v s = {};
      s = __builtin_amdgcn_mfma_f32_16x16x32_bf16(ka0, Qb[0], s, 0, 0, 0);
      s = __builtin_amdgcn_mfma_f32_16x16x32_bf16(ka1, Qb[1], s, 0, 0, 0);
      Sf[mt] = s;
    }

    // online softmax (lane-scalar per query l16); exp2-folded scale
    float mx = -1e30f;
    #pragma unroll
    for (int mt = 0; mt < 4; mt++)
      #pragma unroll
      for (int r = 0; r < 4; r++) mx = fmaxf(mx, Sf[mt][r]);
    mx = fmaxf(mx, __shfl_xor(mx, 16));
    mx = fmaxf(mx, __shfl_xor(mx, 32));
    float mnew = fmaxf(m_i, mx);
    float alpha = exp2f((m_i - mnew) * SCALE_L2E);
    float rsum = 0.f;
    #pragma unroll
    for (int mt = 0; mt < 4; mt++)
      #pragma unroll
      for (int r = 0; r < 4; r++) {
        float p = exp2f((Sf[mt][r] - mnew) * SCALE_L2E);
        Sf[mt][r] = p; rsum += p;
      }
    rsum += __shfl_xor(rsum, 16);
    rsum += __shfl_xor(rsum, 32);
    l_i = l_i * alpha + rsum;
    m_i = mnew;
    #pragma unroll
    for (int mt = 0; mt < 3; mt++)
      #pragma unroll
      for (int r = 0; r < 4; r++) Of[mt][r] *= alpha;

    // P^T -> LDS (wave-private)
    #pragma unroll
    for (int mt = 0; mt < 4; mt++) {
      uint2 pk;
      pk.x = pack2(Sf[mt][0], Sf[mt][1]);
      pk.y = pack2(Sf[mt][2], Sf[mt][3]);
      *(uint2*)&PsT[w][l16][mt*16 + 4*g] = pk;
    }
    asm volatile("s_waitcnt lgkmcnt(0)" ::: "memory");

    // O^T += V^T·P^T
    #pragma unroll
    for (int ks = 0; ks < 2; ks++) {
      short8v pb = *(const short8v*)&PsT[w][l16][ks*32 + g*8];
      #pragma unroll
      for (int mt = 0; mt < 3; mt++) {
        short8v va = *(const short8v*)&Vt[mt*16 + l16][ks*32 + g*8];
        Of[mt] = __builtin_amdgcn_mfma_f32_16x16x32_bf16(va, pb, Of[mt], 0, 0, 0);
      }
    }
  }

  // store unnormalized partial O^T + m,l
  const int q = q0 + w*16 + l16;
  float* orow = Opart + (size_t)sp*4096*320 + (size_t)q*320 + h*40;
  #pragma unroll
  for (int mt = 0; mt < 3; mt++) {
    #pragma unroll
    for (int rp = 0; rp < 2; rp++) {
      int d = mt*16 + 4*g + rp*2;
      if (d < 40) {
        float2 val = { Of[mt][rp*2], Of[mt][rp*2+1] };
        *(float2*)&orow[d] = val;
      }
    }
  }
  if (g == 0) {
    Mp[sp*32768 + q*8 + h] = m_i;
    Lp[sp*32768 + q*8 + h] = l_i;
  }
}

// ---------------- merge 4 partials -> ao bf16 ----------------
__global__ __launch_bounds__(256) void attn_merge(
    const float* __restrict__ Opart, const float* __restrict__ Mp,
    const float* __restrict__ Lp, u16* __restrict__ O) {
  int gid = blockIdx.x*256 + threadIdx.x;   // < 4096*8*20
  int dp = gid % 20;
  int qh = gid / 20;
  int q = qh >> 3, h = qh & 7;
  float m0 = Mp[qh], m1 = Mp[32768 + qh], m2 = Mp[2*32768 + qh], m3 = Mp[3*32768 + qh];
  float ms = fmaxf(fmaxf(m0, m1), fmaxf(m2, m3));
  float w0 = exp2f((m0 - ms) * SCALE_L2E);
  float w1 = exp2f((m1 - ms) * SCALE_L2E);
  float w2 = exp2f((m2 - ms) * SCALE_L2E);
  float w3 = exp2f((m3 - ms) * SCALE_L2E);
  float ls = Lp[qh]*w0 + Lp[32768 + qh]*w1 + Lp[2*32768 + qh]*w2 + Lp[3*32768 + qh]*w3;
  size_t base = (size_t)q*320 + h*40 + dp*2;
  const size_t HBf = 4096u*320u;
  float2 o0 = *(const float2*)&Opart[base];
  float2 o1 = *(const float2*)&Opart[HBf + base];
  float2 o2 = *(const float2*)&Opart[2*HBf + base];
  float2 o3 = *(const float2*)&Opart[3*HBf + base];
  float inv = 1.f / ls;
  float r0 = (o0.x*w0 + o1.x*w1 + o2.x*w2 + o3.x*w3) * inv;
  float r1 = (o0.y*w0 + o1.y*w1 + o2.y*w2 + o3.y*w3) * inv;
  *(unsigned*)&O[base] = pack2(r0, r1);
}

// ---------------- Cross-attention: single-shot MFMA, 77 keys (pad 80/96) ----------------
__global__ __launch_bounds__(256) void cross_attn_mfma(
    const u16* __restrict__ Q, const u16* __restrict__ Kc,
    const u16* __restrict__ Vc, u16* __restrict__ O) {
  const int h = blockIdx.y;
  const int q0 = blockIdx.x * 64;
  const int tid = threadIdx.x;
  const int w = tid >> 6, lane = tid & 63;
  const int l16 = lane & 15, g = lane >> 4;

  __shared__ __align__(16) u16 Kls[80][72];
  __shared__ __align__(16) u16 Vt[48][104];
  __shared__ __align__(16) u16 PsT[4][16][104];

  for (int e = tid; e < 80*12; e += 256) {
    int r = e / 12, c = e % 12;
    *(unsigned*)&Kls[r][40 + 2*c] = 0u;
  }
  for (int e = tid; e < 48*52; e += 256) {
    int r = e / 52, c = e % 52;
    *(unsigned*)&Vt[r][2*c] = 0u;
  }
  {
    int r = lane >> 2, c4 = (lane & 3)*4;
    uint2 z; z.x = 0u; z.y = 0u;
    *(uint2*)&PsT[w][r][80 + c4] = z;
  }

  short8v Qb[2];
  {
    const u16* qrow = Q + (size_t)(q0 + w*16 + l16)*320 + h*40;
    Qb[0] = *(const short8v*)(qrow + g*8);
    short8v z = {};
    Qb[1] = (g == 0) ? *(const short8v*)(qrow + 32) : z;
  }

  for (int e = tid; e < 1600; e += 256) {
    int key = e / 20, dp = e % 20;
    unsigned val = 0u;
    if (key < 77) val = *(const unsigned*)&Kc[(size_t)key*320 + h*40 + dp*2];
    *(unsigned*)&Kls[key][dp*2] = val;
  }
  __syncthreads();
  for (int e = tid; e < 1600; e += 256) {
    int kp = e / 40, d = e % 40;
    unsigned u0 = (kp*2     < 77) ? (unsigned)Vc[(size_t)(kp*2    )*320 + h*40 + d] : 0u;
    unsigned u1 = (kp*2 + 1 < 77) ? (unsigned)Vc[(size_t)(kp*2 + 1)*320 + h*40 + d] : 0u;
    *(unsigned*)&Vt[d][kp*2] = u0 | (u1 << 16);
  }
  __syncthreads();

  float4v Sf[5];
  #pragma unroll
  for (int mt = 0; mt < 5; mt++) {
    short8v ka0 = *(const short8v*)&Kls[mt*16 + l16][g*8];
    short8v ka1 = *(const short8v*)&Kls[mt*16 + l16][32 + g*8];
    float4v s = {};
    s = __builtin_amdgcn_mfma_f32_16x16x32_bf16(ka0, Qb[0], s, 0, 0, 0);
    s = __builtin_amdgcn_mfma_f32_16x16x32_bf16(ka1, Qb[1], s, 0, 0, 0);
    Sf[mt] = s;
  }

  float mx = -1e30f;
  #pragma unroll
  for (int mt = 0; mt < 5; mt++)
    #pragma unroll
    for (int r = 0; r < 4; r++) {
      int key = mt*16 + 4*g + r;
      if (key >= 77) Sf[mt][r] = -1e30f;
      mx = fmaxf(mx, Sf[mt][r]);
    }
  mx = fmaxf(mx, __shfl_xor(mx, 16));
  mx = fmaxf(mx, __shfl_xor(mx, 32));
  float rsum = 0.f;
  #pragma unroll
  for (int mt = 0; mt < 5; mt++)
    #pragma unroll
    for (int r = 0; r < 4; r++) {
      float p = exp2f((Sf[mt][r] - mx) * SCALE_L2E);
      Sf[mt][r] = p; rsum += p;
    }
  rsum += __shfl_xor(rsum, 16);
  rsum += __shfl_xor(rsum, 32);

  #pragma unroll
  for (int mt = 0; mt < 5; mt++) {
    uint2 pk;
    pk.x = pack2(Sf[mt][0], Sf[mt][1]);
    pk.y = pack2(Sf[mt][2], Sf[mt][3]);
    *(uint2*)&PsT[w][l16][mt*16 + 4*g] = pk;
  }
  __syncthreads();

  float4v Of[3] = {};
  #pragma unroll
  for (int ks = 0; ks < 3; ks++) {
    short8v pb = *(const short8v*)&PsT[w][l16][ks*32 + g*8];
    #pragma unroll
    for (int mt = 0; mt < 3; mt++) {
      short8v va = *(const short8v*)&Vt[mt*16 + l16][ks*32 + g*8];
      Of[mt] = __builtin_amdgcn_mfma_f32_16x16x32_bf16(va, pb, Of[mt], 0, 0, 0);
    }
  }

  float inv = 1.f / rsum;
  u16* orow = O + (size_t)(q0 + w*16 + l16)*320 + h*40;
  #pragma unroll
  for (int mt = 0; mt < 3; mt++) {
    #pragma unroll
    for (int rp = 0; rp < 2; rp++) {
      int d = mt*16 + 4*g + rp*2;
      if (d < 40)
        *(unsigned*)&orow[d] = pack2(Of[mt][rp*2] * inv, Of[mt][rp*2+1] * inv);
    }
  }
}

extern "C" void kernel_launch(void* const* d_in, const int* in_sizes, int n_in,
                              void* d_out, int out_size, void* d_ws, size_t ws_size,
                              hipStream_t stream) {
  const float* x        = (const float*)d_in[0];
  const float* ctx      = (const float*)d_in[1];
  const float* gn_s     = (const float*)d_in[2];
  const float* gn_b     = (const float*)d_in[3];
  const float* w_pin    = (const float*)d_in[4];
  const float* b_pin    = (const float*)d_in[5];
  const float* ln1_s    = (const float*)d_in[6];
  const float* ln1_b    = (const float*)d_in[7];
  const float* wq1      = (const float*)d_in[8];
  const float* wk1      = (const float*)d_in[9];
  const float* wv1      = (const float*)d_in[10];
  const float* wo1      = (const float*)d_in[11];
  const float* bo1      = (const float*)d_in[12];
  const float* ln2_s    = (const float*)d_in[13];
  const float* ln2_b    = (const float*)d_in[14];
  const float* wq2      = (const float*)d_in[15];
  const float* wk2      = (const float*)d_in[16];
  const float* wv2      = (const float*)d_in[17];
  const float* wo2      = (const float*)d_in[18];
  const float* bo2      = (const float*)d_in[19];
  const float* ln3_s    = (const float*)d_in[20];
  const float* ln3_b    = (const float*)d_in[21];
  const float* w_ff1    = (const float*)d_in[22];
  const float* b_ff1    = (const float*)d_in[23];
  const float* w_ff2    = (const float*)d_in[24];
  const float* b_ff2    = (const float*)d_in[25];
  const float* w_pout   = (const float*)d_in[26];
  const float* b_pout   = (const float*)d_in[27];
  float* out = (float*)d_out;

  u16* ws = (u16*)d_ws;
  const size_t HB = 4096u*320u;
  u16* h   = ws;
  u16* hn  = ws + HB;
  u16* q   = ws + 2*HB;    // q,k contiguous (QKV fused epilogue)
  u16* k   = ws + 3*HB;
  u16* vT  = ws + 4*HB;    // V^T [320][4096]
  u16* ao  = ws + 5*HB;
  u16* gnT = k;
  u16* gg  = q;            // GEGLU out overlays q,k,vT,ao
  u16* wb  = ws + 6*HB;
  size_t o = 0;
  u16* ctxb   = wb + o; o += 59136;
  u16* wq1T   = wb + o; o += 102400;   // stacked: wq1T,wk1T,wv1T = [960][320]
  u16* wk1T   = wb + o; o += 102400;
  u16* wv1T   = wb + o; o += 102400;
  u16* wo1T   = wb + o; o += 102400;
  u16* wq2T   = wb + o; o += 102400;
  u16* wk2T   = wb + o; o += 245760;   // stacked: wk2T,wv2T = [640][768]
  u16* wv2T   = wb + o; o += 245760;
  u16* wo2T   = wb + o; o += 102400;
  u16* wff1T  = wb + o; o += 819200;
  u16* wff2T  = wb + o; o += 409600;
  u16* wpoutT = wb + o; o += 102400;
  u16* wpinT  = wb + o; o += 102400;
  u16* kc     = wb + o; o += 24640;    // kc,vc contiguous, segStride 24640
  u16* vc     = wb + o; o += 24640;
  float* chscale = (float*)(wb + o);
  float* chshift = chscale + 320;
  float* Opart = chshift + 320;        // 4 x 4096 x 320 fp32 = 21 MB
  float* Mpart = Opart + 4*HB;
  float* Lpart = Mpart + 4*32768;

  TPack tp;
  const float* srcs[12] = {wq1, wk1, wv1, wo1, wq2, wo2, w_pin, w_pout, wk2, wv2, w_ff1, w_ff2};
  u16* dsts[12]         = {wq1T, wk1T, wv1T, wo1T, wq2T, wo2T, wpinT, wpoutT, wk2T, wv2T, wff1T, wff2T};
  int Ks[12] = {320,320,320,320,320,320,320,320,768,768,320,1280};
  int Ns[12] = {320,320,320,320,320,320,320,320,320,320,2560,320};
  int off = 0;
  for (int i = 0; i < 12; i++) {
    tp.d[i].src = srcs[i]; tp.d[i].dst = dsts[i];
    tp.d[i].K = Ks[i]; tp.d[i].N = Ns[i];
    tp.d[i].off = off; tp.d[i].tx = Ns[i]/32;
    off += (Ks[i]/32)*(Ns[i]/32);
  }

  dim3 blk(256), g64x5(64, 5);
  const u16* nres = nullptr;
  const float* nb = nullptr;

  hipLaunchKernelGGL(prep_kernel, dim3(off + 58 + 32), blk, 0, stream,
                     tp, off, ctx, ctxb, x, gn_s, gn_b, chscale, chshift);
  hipLaunchKernelGGL(gn_apply_t_kernel, g64x5, blk, 0, stream, x, chscale, chshift, gnT);
  hipLaunchKernelGGL((mgemm<0>), g64x5, blk, 0, stream, gnT, wpinT, b_pin, nres, nb, (void*)h, 4096, 320, 320, 0);
  hipLaunchKernelGGL(layernorm_kernel, dim3(4096), dim3(64), 0, stream, h, ln1_s, ln1_b, hn);
  // fused QKV: N=960; segs 0,1 -> q,k; seg 2 -> vT (transposed)
  hipLaunchKernelGGL((mgemm<3>), dim3(64, 15), blk, 0, stream, hn, wq1T, nb, nres, (const float*)vT, (void*)q, 4096, 960, 320, (int)HB);
  hipLaunchKernelGGL(self_attn_part, dim3(64, 8, 4), blk, 0, stream, q, k, vT, Opart, Mpart, Lpart);
  hipLaunchKernelGGL(attn_merge, dim3(2560), blk, 0, stream, Opart, Mpart, Lpart, ao);
  hipLaunchKernelGGL((mgemm<0>), g64x5, blk, 0, stream, ao, wo1T, bo1, h, nb, (void*)h, 4096, 320, 320, 0);
  hipLaunchKernelGGL(layernorm_kernel, dim3(4096), dim3(64), 0, stream, h, ln2_s, ln2_b, hn);
  hipLaunchKernelGGL((mgemm<0>), g64x5, blk, 0, stream, hn, wq2T, nb, nres, nb, (void*)q, 4096, 320, 320, 0);
  hipLaunchKernelGGL((mgemm<1>), dim3(2, 10), blk, 0, stream, ctxb, wk2T, nb, nres, nb, (void*)kc, 77, 640, 768, 24640);
  hipLaunchKernelGGL(cross_attn_mfma, dim3(64, 8), blk, 0, stream, q, kc, vc, ao);
  hipLaunchKernelGGL((mgemm<0>), g64x5, blk, 0, stream, ao, wo2T, bo2, h, nb, (void*)h, 4096, 320, 320, 0);
  hipLaunchKernelGGL(layernorm_kernel, dim3(4096), dim3(64), 0, stream, h, ln3_s, ln3_b, hn);
  hipLaunchKernelGGL(geglu_mfma, dim3(64, 20), blk, 0, stream, hn, wff1T, b_ff1, gg);
  hipLaunchKernelGGL((mgemm<0>), g64x5, blk, 0, stream, gg, wff2T, b_ff2, h, nb, (void*)h, 4096, 320, 1280, 0);
  hipLaunchKernelGGL((mgemm<2>), g64x5, blk, 0, stream, h, wpoutT, b_pout, nres, x, (void*)out, 4096, 320, 320, 0);
}

// Round 8
// 348.557 us; speedup vs baseline: 1.3803x; 1.0488x over previous
//
#include <hip/hip_runtime.h>
#include <hip/hip_bf16.h>
#include <math.h>

#define SCALE_ATTN 0.15811388300841897f
#define SCALE_L2E  0.22811011265722836f   // SCALE_ATTN * log2(e)

typedef __attribute__((ext_vector_type(8))) short short8v;
typedef __attribute__((ext_vector_type(4))) float float4v;
typedef unsigned short u16;

__device__ __forceinline__ unsigned pack2(float a, float b) {
  float2 f; f.x = a; f.y = b;
  __hip_bfloat162 h = __float22bfloat162_rn(f);
  return *(unsigned*)&h;
}
__device__ __forceinline__ float bfu2f(u16 u) {
  return __uint_as_float(((unsigned)u) << 16);
}
__device__ __forceinline__ u16 f2bf(float x) {
  __hip_bfloat16 h = __float2bfloat16(x);
  return *(u16*)&h;
}

// ---------------- prep: weight transpose+convert (opt. scale) | ctx cvt | gn stats ----------
struct TDesc { const float* src; u16* dst; int K, N, off, tx; float sc; };
struct TPack { TDesc d[12]; };

__global__ __launch_bounds__(256) void prep_kernel(
    TPack p, int nT,
    const float* __restrict__ ctxsrc, u16* __restrict__ ctxdst,
    const float* __restrict__ x, const float* __restrict__ gs,
    const float* __restrict__ gb, float* __restrict__ chscale, float* __restrict__ chshift) {
  __shared__ float ls[32][33];
  int bt = blockIdx.x, t = threadIdx.x;
  if (bt < nT) {
    int ti = 0;
    #pragma unroll
    for (int i = 1; i < 12; i++) if (bt >= p.d[i].off) ti = i;
    TDesc dd = p.d[ti];
    int local = bt - dd.off;
    int n0 = (local % dd.tx) * 32, k0 = (local / dd.tx) * 32;
    #pragma unroll
    for (int i = 0; i < 4; i++) {
      int idx = t + i*256, r = idx >> 5, c = idx & 31;
      ls[r][c] = dd.src[(size_t)(k0 + r)*dd.N + n0 + c];
    }
    __syncthreads();
    #pragma unroll
    for (int i = 0; i < 2; i++) {
      int p2 = t + i*256, n = p2 >> 4, kp = (p2 & 15)*2;
      *(unsigned*)&dd.dst[(size_t)(n0 + n)*dd.K + k0 + kp] =
        pack2(ls[kp][n]*dd.sc, ls[kp+1][n]*dd.sc);
    }
  } else if (bt < nT + 58) {
    int idx = ((bt - nT)*256 + t)*4;
    if (idx < 59136) {
      float4 v = *(const float4*)&ctxsrc[idx];
      uint2 o; o.x = pack2(v.x, v.y); o.y = pack2(v.z, v.w);
      *(uint2*)&ctxdst[idx] = o;
    }
  } else {
    int g = bt - nT - 58;
    size_t base = (size_t)g * 40960;
    float sum = 0.f, sq = 0.f;
    for (int e = t; e < 40960; e += 256) {
      float v = x[base + e];
      sum += v; sq += v * v;
    }
    float* s1 = &ls[0][0];
    float* s2 = &ls[8][0] + 8;
    s1[t] = sum; s2[t] = sq; __syncthreads();
    for (int st = 128; st > 0; st >>= 1) {
      if (t < st) { s1[t] += s1[t+st]; s2[t] += s2[t+st]; }
      __syncthreads();
    }
    float mu = s1[0] * (1.f/40960.f);
    float var = s2[0] * (1.f/40960.f) - mu*mu;
    float rs = rsqrtf(var + 1e-6f);
    if (t < 10) {
      int c = g*10 + t;
      float sc = rs * gs[c];
      chscale[c] = sc;
      chshift[c] = gb[c] - mu * sc;
    }
  }
}

// ---------------- GN apply + transpose: x[c][s] fp32 -> gnT[s][c] bf16 ----------------
__global__ __launch_bounds__(256) void gn_apply_t_kernel(
    const float* __restrict__ x, const float* __restrict__ chscale,
    const float* __restrict__ chshift, u16* __restrict__ gnT) {
  __shared__ float ts[64][65];
  __shared__ float scl[64], sft[64];
  int s0 = blockIdx.x * 64, c0 = blockIdx.y * 64;
  int t = threadIdx.x;
  if (t < 64) { scl[t] = chscale[c0 + t]; sft[t] = chshift[c0 + t]; }
  int crow = t >> 2, sch = (t & 3) * 16;
  #pragma unroll
  for (int j = 0; j < 4; j++) {
    float4 v = *(const float4*)&x[(size_t)(c0 + crow)*4096 + s0 + sch + 4*j];
    ts[crow][sch + 4*j + 0] = v.x; ts[crow][sch + 4*j + 1] = v.y;
    ts[crow][sch + 4*j + 2] = v.z; ts[crow][sch + 4*j + 3] = v.w;
  }
  __syncthreads();
  int srow = t >> 2, cch = (t & 3) * 16;
  #pragma unroll
  for (int p = 0; p < 8; p++) {
    int cl = cch + 2*p;
    float f0 = ts[cl][srow] * scl[cl] + sft[cl];
    float f1 = ts[cl+1][srow] * scl[cl+1] + sft[cl+1];
    *(unsigned*)&gnT[(size_t)(s0 + srow)*320 + c0 + cl] = pack2(f0, f1);
  }
}

// ---------------- LayerNorm bf16->bf16: one wave per row of 320 ----------------
__global__ __launch_bounds__(64) void layernorm_kernel(
    const u16* __restrict__ X, const float* __restrict__ s,
    const float* __restrict__ b, u16* __restrict__ Y) {
  int row = blockIdx.x, t = threadIdx.x;
  const u16* xr = X + (size_t)row*320;
  float v[5], sum = 0.f, sq = 0.f;
  #pragma unroll
  for (int i = 0; i < 5; i++) { v[i] = bfu2f(xr[t + 64*i]); sum += v[i]; sq += v[i]*v[i]; }
  #pragma unroll
  for (int o = 32; o > 0; o >>= 1) { sum += __shfl_down(sum, o); sq += __shfl_down(sq, o); }
  sum = __shfl(sum, 0); sq = __shfl(sq, 0);
  float mu = sum * (1.f/320.f);
  float var = sq * (1.f/320.f) - mu*mu;
  float rs = rsqrtf(var + 1e-5f);
  u16* yr = Y + (size_t)row*320;
  #pragma unroll
  for (int i = 0; i < 5; i++) {
    int c = t + 64*i;
    yr[c] = f2bf((v[i]-mu)*rs*s[c] + b[c]);
  }
}

// ---------------- MFMA GEMM: C[M,N] = A[M,K](bf16) * BT[N,K](bf16)^T ----------------
template<int MODE>
__global__ __launch_bounds__(256) void mgemm(
    const u16* __restrict__ A, const u16* __restrict__ BT,
    const float* __restrict__ bias, const u16* __restrict__ res,
    const float* __restrict__ xres, void* __restrict__ Cout,
    int M, int N, int K, int segStride) {
  __shared__ __align__(16) u16 smem[2*64*72];
  u16* As = smem;
  u16* Bs = smem + 64*72;
  const int t = threadIdx.x;
  const int lane = t & 63, w = t >> 6, l16 = lane & 15, g = lane >> 4;
  const int bm = blockIdx.x * 64, bn = blockIdx.y * 64;
  const int m0 = (w & 1) * 32, n0 = (w >> 1) * 32;
  float4v acc[2][2] = {};
  const int ar = t >> 2, ac = (t & 3) * 16;
  const bool aok = (bm + ar) < M;

  for (int k0 = 0; k0 < K; k0 += 64) {
    __syncthreads();
    short8v a0 = {}, a1 = {};
    if (aok) {
      const u16* ga = &A[(size_t)(bm + ar)*K + k0 + ac];
      a0 = *(const short8v*)ga; a1 = *(const short8v*)(ga + 8);
    }
    *(short8v*)&As[ar*72 + ac] = a0;
    *(short8v*)&As[ar*72 + ac + 8] = a1;
    const u16* gbp = &BT[(size_t)(bn + ar)*K + k0 + ac];
    *(short8v*)&Bs[ar*72 + ac] = *(const short8v*)gbp;
    *(short8v*)&Bs[ar*72 + ac + 8] = *(const short8v*)(gbp + 8);
    __syncthreads();
    #pragma unroll
    for (int ks = 0; ks < 2; ks++) {
      short8v af[2], bfv[2];
      #pragma unroll
      for (int mt = 0; mt < 2; mt++)
        af[mt] = *(const short8v*)&As[(m0 + 16*mt + l16)*72 + ks*32 + g*8];
      #pragma unroll
      for (int nt = 0; nt < 2; nt++)
        bfv[nt] = *(const short8v*)&Bs[(n0 + 16*nt + l16)*72 + ks*32 + g*8];
      #pragma unroll
      for (int mt = 0; mt < 2; mt++)
        #pragma unroll
        for (int nt = 0; nt < 2; nt++)
          acc[mt][nt] = __builtin_amdgcn_mfma_f32_16x16x32_bf16(af[mt], bfv[nt], acc[mt][nt], 0, 0, 0);
    }
  }
  __syncthreads();
  float* Cs = (float*)smem;  // [64][68]
  #pragma unroll
  for (int mt = 0; mt < 2; mt++)
    #pragma unroll
    for (int nt = 0; nt < 2; nt++)
      #pragma unroll
      for (int r = 0; r < 4; r++)
        Cs[(m0 + 16*mt + 4*g + r)*68 + n0 + 16*nt + l16] = acc[mt][nt][r];
  __syncthreads();

  if (MODE == 0) {
    u16* C = (u16*)Cout;
    #pragma unroll
    for (int i = 0; i < 8; i++) {
      int p = t + i*256;
      int mm = p >> 5, nn = (p & 31)*2;
      int gm = bm + mm;
      if (gm >= M) continue;
      float f0 = Cs[mm*68 + nn], f1 = Cs[mm*68 + nn + 1];
      if (bias) { f0 += bias[bn + nn]; f1 += bias[bn + nn + 1]; }
      if (res) {
        unsigned u = *(const unsigned*)&res[(size_t)gm*N + bn + nn];
        f0 += bfu2f((u16)(u & 0xffffu));
        f1 += bfu2f((u16)(u >> 16));
      }
      *(unsigned*)&C[(size_t)gm*N + bn + nn] = pack2(f0, f1);
    }
  } else if (MODE == 1) {
    u16* C = (u16*)Cout + (size_t)(bn / 320) * segStride;
    int nb = bn % 320;
    #pragma unroll
    for (int i = 0; i < 8; i++) {
      int p = t + i*256;
      int mm = p >> 5, nn = (p & 31)*2;
      int gm = bm + mm;
      if (gm >= M) continue;
      *(unsigned*)&C[(size_t)gm*320 + nb + nn] = pack2(Cs[mm*68 + nn], Cs[mm*68 + nn + 1]);
    }
  } else if (MODE == 3) {
    if (bn < 640) {
      u16* C = (u16*)Cout + (size_t)(bn / 320) * segStride;
      int nb = bn % 320;
      #pragma unroll
      for (int i = 0; i < 8; i++) {
        int p = t + i*256;
        int mm = p >> 5, nn = (p & 31)*2;
        *(unsigned*)&C[(size_t)(bm + mm)*320 + nb + nn] = pack2(Cs[mm*68 + nn], Cs[mm*68 + nn + 1]);
      }
    } else {
      u16* vTp = (u16*)(void*)xres;
      int nloc = t >> 2, mch = (t & 3) * 16;
      int vd = bn - 640 + nloc;
      u16* dst = vTp + (size_t)vd*4096 + bm + mch;
      unsigned buf[8];
      #pragma unroll
      for (int jj = 0; jj < 8; jj++)
        buf[jj] = pack2(Cs[(mch + 2*jj)*68 + nloc], Cs[(mch + 2*jj + 1)*68 + nloc]);
      uint4 o0; o0.x = buf[0]; o0.y = buf[1]; o0.z = buf[2]; o0.w = buf[3];
      uint4 o1; o1.x = buf[4]; o1.y = buf[5]; o1.z = buf[6]; o1.w = buf[7];
      *(uint4*)dst = o0;
      *(uint4*)(dst + 8) = o1;
    }
  } else {
    float* C = (float*)Cout;
    int nloc = t >> 2, mch = (t & 3) * 16;
    float bb = bias[bn + nloc];
    #pragma unroll
    for (int j = 0; j < 4; j++) {
      int m4 = mch + j*4;
      float4 xv = *(const float4*)&xres[(size_t)(bn + nloc)*4096 + bm + m4];
      float4 ov;
      ov.x = Cs[(m4+0)*68 + nloc] + bb + xv.x;
      ov.y = Cs[(m4+1)*68 + nloc] + bb + xv.y;
      ov.z = Cs[(m4+2)*68 + nloc] + bb + xv.z;
      ov.w = Cs[(m4+3)*68 + nloc] + bb + xv.w;
      *(float4*)&C[(size_t)(bn + nloc)*4096 + bm + m4] = ov;
    }
  }
}

// ---------------- GEGLU MFMA ----------------
__global__ __launch_bounds__(256) void geglu_mfma(
    const u16* __restrict__ A, const u16* __restrict__ BT,
    const float* __restrict__ bias, u16* __restrict__ C) {
  __shared__ __align__(16) u16 smem[3*64*72];
  u16* As = smem;
  u16* Ba = smem + 64*72;
  u16* Bg = smem + 2*64*72;
  const int t = threadIdx.x;
  const int lane = t & 63, w = t >> 6, l16 = lane & 15, g = lane >> 4;
  const int bm = blockIdx.x * 64, bn = blockIdx.y * 64;
  const int m0 = (w & 1) * 32, n0 = (w >> 1) * 32;
  float4v aacc[2][2] = {}, gacc[2][2] = {};
  const int ar = t >> 2, ac = (t & 3) * 16;

  for (int k0 = 0; k0 < 320; k0 += 64) {
    __syncthreads();
    {
      const u16* ga = &A[(size_t)(bm + ar)*320 + k0 + ac];
      *(short8v*)&As[ar*72 + ac] = *(const short8v*)ga;
      *(short8v*)&As[ar*72 + ac + 8] = *(const short8v*)(ga + 8);
      const u16* gba = &BT[(size_t)(bn + ar)*320 + k0 + ac];
      *(short8v*)&Ba[ar*72 + ac] = *(const short8v*)gba;
      *(short8v*)&Ba[ar*72 + ac + 8] = *(const short8v*)(gba + 8);
      const u16* gbg = &BT[(size_t)(1280 + bn + ar)*320 + k0 + ac];
      *(short8v*)&Bg[ar*72 + ac] = *(const short8v*)gbg;
      *(short8v*)&Bg[ar*72 + ac + 8] = *(const short8v*)(gbg + 8);
    }
    __syncthreads();
    #pragma unroll
    for (int ks = 0; ks < 2; ks++) {
      short8v af[2], bav[2], bgv[2];
      #pragma unroll
      for (int mt = 0; mt < 2; mt++)
        af[mt] = *(const short8v*)&As[(m0 + 16*mt + l16)*72 + ks*32 + g*8];
      #pragma unroll
      for (int nt = 0; nt < 2; nt++) {
        bav[nt] = *(const short8v*)&Ba[(n0 + 16*nt + l16)*72 + ks*32 + g*8];
        bgv[nt] = *(const short8v*)&Bg[(n0 + 16*nt + l16)*72 + ks*32 + g*8];
      }
      #pragma unroll
      for (int mt = 0; mt < 2; mt++)
        #pragma unroll
        for (int nt = 0; nt < 2; nt++) {
          aacc[mt][nt] = __builtin_amdgcn_mfma_f32_16x16x32_bf16(af[mt], bav[nt], aacc[mt][nt], 0, 0, 0);
          gacc[mt][nt] = __builtin_amdgcn_mfma_f32_16x16x32_bf16(af[mt], bgv[nt], gacc[mt][nt], 0, 0, 0);
        }
    }
  }
  __syncthreads();
  float* Cs = (float*)smem;
  #pragma unroll
  for (int nt = 0; nt < 2; nt++) {
    int col = n0 + 16*nt + l16;
    float ba = bias[bn + col];
    float bg2 = bias[1280 + bn + col];
    #pragma unroll
    for (int mt = 0; mt < 2; mt++)
      #pragma unroll
      for (int r = 0; r < 4; r++) {
        float a = aacc[mt][nt][r] + ba;
        float gv = gacc[mt][nt][r] + bg2;
        float gl = 0.5f * gv * (1.f + erff(gv * 0.70710678118654752f));
        Cs[(m0 + 16*mt + 4*g + r)*68 + col] = a * gl;
      }
  }
  __syncthreads();
  #pragma unroll
  for (int i = 0; i < 8; i++) {
    int p = t + i*256;
    int mm = p >> 5, nn = (p & 31)*2;
    *(unsigned*)&C[(size_t)(bm + mm)*1280 + bn + nn] = pack2(Cs[mm*68 + nn], Cs[mm*68 + nn + 1]);
  }
}

// ---------------- Self-attention partial: 8-wave blocks, hoisted staging ----------------
// q pre-scaled by SCALE*log2e. Grid (32 qtiles of 128, 8 heads, 4 splits) = 1024 blocks.
__global__ __launch_bounds__(512) void self_attn_part(
    const u16* __restrict__ Q, const u16* __restrict__ K,
    const u16* __restrict__ vT, float* __restrict__ Opart,
    float* __restrict__ Mp, float* __restrict__ Lp) {
  const int h = blockIdx.y;
  const int q0 = blockIdx.x * 128;
  const int sp = blockIdx.z;
  const int tid = threadIdx.x;
  const int w = tid >> 6, lane = tid & 63;
  const int l16 = lane & 15, g = lane >> 4;

  __shared__ __align__(16) u16 Kls[64][72];   // [key][d], cols 40..63 zero
  __shared__ __align__(16) u16 Vt[48][72];    // [d][key], rows 40..47 zero
  __shared__ __align__(16) u16 PsT[8][16][72];

  // zero never-restaged pads once
  for (int e = tid; e < 64*12; e += 512) {
    int r = e / 12, c = e % 12;
    *(unsigned*)&Kls[r][40 + 2*c] = 0u;
  }
  if (tid < 256) {
    int r = 40 + (tid >> 5), c = tid & 31;
    *(unsigned*)&Vt[r][2*c] = 0u;
  }

  short8v Qb[2];
  {
    const u16* qrow = Q + (size_t)(q0 + w*16 + l16)*320 + h*40;
    Qb[0] = *(const short8v*)(qrow + g*8);
    short8v z = {};
    Qb[1] = (g == 0) ? *(const short8v*)(qrow + 32) : z;
  }

  const u16* Kbase = K + (size_t)(sp*1024)*320 + h*40;
  const u16* Vbase = vT + (size_t)(h*40)*4096 + sp*1024;

  // hoisted staging slots: K slot = tid (<320); V slot = tid-192 (tid>=192)
  const int ksl = (tid < 320) ? tid : 0;
  const int keyK = ksl / 5, chK = ksl - keyK*5;
  const u16* gK = Kbase + (size_t)keyK*320 + chK*8;
  u16* lK = &Kls[keyK][chK*8];
  const int vsl = (tid >= 192) ? (tid - 192) : 0;
  const int dV = vsl >> 3, chV = vsl & 7;
  const u16* gV = Vbase + (size_t)dV*4096 + chV*8;
  u16* lV = &Vt[dV][chV*8];

  float m_i = -1e30f, l_i = 0.f;
  float4v Of[3] = {};

  for (int it = 0; it < 16; ++it) {
    __syncthreads();   // prior tile's LDS reads complete
    if (tid < 320) *(short8v*)lK = *(const short8v*)gK;
    if (tid >= 192) *(short8v*)lV = *(const short8v*)gV;
    gK += 64*320; gV += 64;
    __syncthreads();   // staged tiles visible

    // S^T = K·Q^T (scores already in exp2 units)
    float4v Sf[4];
    #pragma unroll
    for (int mt = 0; mt < 4; mt++) {
      short8v ka0 = *(const short8v*)&Kls[mt*16 + l16][g*8];
      short8v ka1 = *(const short8v*)&Kls[mt*16 + l16][32 + g*8];
      float4v s = {};
      s = __builtin_amdgcn_mfma_f32_16x16x32_bf16(ka0, Qb[0], s, 0, 0, 0);
      s = __builtin_amdgcn_mfma_f32_16x16x32_bf16(ka1, Qb[1], s, 0, 0, 0);
      Sf[mt] = s;
    }

    // online softmax (lane-scalar per query l16)
    float mx = -1e30f;
    #pragma unroll
    for (int mt = 0; mt < 4; mt++)
      #pragma unroll
      for (int r = 0; r < 4; r++) mx = fmaxf(mx, Sf[mt][r]);
    mx = fmaxf(mx, __shfl_xor(mx, 16));
    mx = fmaxf(mx, __shfl_xor(mx, 32));
    float mnew = fmaxf(m_i, mx);
    float alpha = exp2f(m_i - mnew);
    float rsum = 0.f;
    #pragma unroll
    for (int mt = 0; mt < 4; mt++)
      #pragma unroll
      for (int r = 0; r < 4; r++) {
        float p = exp2f(Sf[mt][r] - mnew);
        Sf[mt][r] = p; rsum += p;
      }
    rsum += __shfl_xor(rsum, 16);
    rsum += __shfl_xor(rsum, 32);
    l_i = l_i * alpha + rsum;
    m_i = mnew;
    #pragma unroll
    for (int mt = 0; mt < 3; mt++)
      #pragma unroll
      for (int r = 0; r < 4; r++) Of[mt][r] *= alpha;

    // P^T -> LDS (wave-private)
    #pragma unroll
    for (int mt = 0; mt < 4; mt++) {
      uint2 pk;
      pk.x = pack2(Sf[mt][0], Sf[mt][1]);
      pk.y = pack2(Sf[mt][2], Sf[mt][3]);
      *(uint2*)&PsT[w][l16][mt*16 + 4*g] = pk;
    }
    asm volatile("s_waitcnt lgkmcnt(0)" ::: "memory");

    // O^T += V^T·P^T
    #pragma unroll
    for (int ks = 0; ks < 2; ks++) {
      short8v pb = *(const short8v*)&PsT[w][l16][ks*32 + g*8];
      #pragma unroll
      for (int mt = 0; mt < 3; mt++) {
        short8v va = *(const short8v*)&Vt[mt*16 + l16][ks*32 + g*8];
        Of[mt] = __builtin_amdgcn_mfma_f32_16x16x32_bf16(va, pb, Of[mt], 0, 0, 0);
      }
    }
  }

  // store unnormalized partial O^T + m,l
  const int q = q0 + w*16 + l16;
  float* orow = Opart + (size_t)sp*4096*320 + (size_t)q*320 + h*40;
  #pragma unroll
  for (int mt = 0; mt < 3; mt++) {
    #pragma unroll
    for (int rp = 0; rp < 2; rp++) {
      int d = mt*16 + 4*g + rp*2;
      if (d < 40) {
        float2 val = { Of[mt][rp*2], Of[mt][rp*2+1] };
        *(float2*)&orow[d] = val;
      }
    }
  }
  if (g == 0) {
    Mp[sp*32768 + q*8 + h] = m_i;
    Lp[sp*32768 + q*8 + h] = l_i;
  }
}

// ---------------- merge 4 partials -> ao bf16 ----------------
__global__ __launch_bounds__(256) void attn_merge(
    const float* __restrict__ Opart, const float* __restrict__ Mp,
    const float* __restrict__ Lp, u16* __restrict__ O) {
  int gid = blockIdx.x*256 + threadIdx.x;   // < 4096*8*20
  int dp = gid % 20;
  int qh = gid / 20;
  int q = qh >> 3, h = qh & 7;
  float m0 = Mp[qh], m1 = Mp[32768 + qh], m2 = Mp[2*32768 + qh], m3 = Mp[3*32768 + qh];
  float ms = fmaxf(fmaxf(m0, m1), fmaxf(m2, m3));
  float w0 = exp2f(m0 - ms);
  float w1 = exp2f(m1 - ms);
  float w2 = exp2f(m2 - ms);
  float w3 = exp2f(m3 - ms);
  float ls = Lp[qh]*w0 + Lp[32768 + qh]*w1 + Lp[2*32768 + qh]*w2 + Lp[3*32768 + qh]*w3;
  size_t base = (size_t)q*320 + h*40 + dp*2;
  const size_t HBf = 4096u*320u;
  float2 o0 = *(const float2*)&Opart[base];
  float2 o1 = *(const float2*)&Opart[HBf + base];
  float2 o2 = *(const float2*)&Opart[2*HBf + base];
  float2 o3 = *(const float2*)&Opart[3*HBf + base];
  float inv = 1.f / ls;
  float r0 = (o0.x*w0 + o1.x*w1 + o2.x*w2 + o3.x*w3) * inv;
  float r1 = (o0.y*w0 + o1.y*w1 + o2.y*w2 + o3.y*w3) * inv;
  *(unsigned*)&O[base] = pack2(r0, r1);
}

// ---------------- Cross-attention: single-shot MFMA, 77 keys (q pre-scaled) ----------------
__global__ __launch_bounds__(256) void cross_attn_mfma(
    const u16* __restrict__ Q, const u16* __restrict__ Kc,
    const u16* __restrict__ Vc, u16* __restrict__ O) {
  const int h = blockIdx.y;
  const int q0 = blockIdx.x * 64;
  const int tid = threadIdx.x;
  const int w = tid >> 6, lane = tid & 63;
  const int l16 = lane & 15, g = lane >> 4;

  __shared__ __align__(16) u16 Kls[80][72];
  __shared__ __align__(16) u16 Vt[48][104];
  __shared__ __align__(16) u16 PsT[4][16][104];

  for (int e = tid; e < 80*12; e += 256) {
    int r = e / 12, c = e % 12;
    *(unsigned*)&Kls[r][40 + 2*c] = 0u;
  }
  for (int e = tid; e < 48*52; e += 256) {
    int r = e / 52, c = e % 52;
    *(unsigned*)&Vt[r][2*c] = 0u;
  }
  {
    int r = lane >> 2, c4 = (lane & 3)*4;
    uint2 z; z.x = 0u; z.y = 0u;
    *(uint2*)&PsT[w][r][80 + c4] = z;
  }

  short8v Qb[2];
  {
    const u16* qrow = Q + (size_t)(q0 + w*16 + l16)*320 + h*40;
    Qb[0] = *(const short8v*)(qrow + g*8);
    short8v z = {};
    Qb[1] = (g == 0) ? *(const short8v*)(qrow + 32) : z;
  }

  for (int e = tid; e < 1600; e += 256) {
    int key = e / 20, dp = e % 20;
    unsigned val = 0u;
    if (key < 77) val = *(const unsigned*)&Kc[(size_t)key*320 + h*40 + dp*2];
    *(unsigned*)&Kls[key][dp*2] = val;
  }
  __syncthreads();
  for (int e = tid; e < 1600; e += 256) {
    int kp = e / 40, d = e % 40;
    unsigned u0 = (kp*2     < 77) ? (unsigned)Vc[(size_t)(kp*2    )*320 + h*40 + d] : 0u;
    unsigned u1 = (kp*2 + 1 < 77) ? (unsigned)Vc[(size_t)(kp*2 + 1)*320 + h*40 + d] : 0u;
    *(unsigned*)&Vt[d][kp*2] = u0 | (u1 << 16);
  }
  __syncthreads();

  float4v Sf[5];
  #pragma unroll
  for (int mt = 0; mt < 5; mt++) {
    short8v ka0 = *(const short8v*)&Kls[mt*16 + l16][g*8];
    short8v ka1 = *(const short8v*)&Kls[mt*16 + l16][32 + g*8];
    float4v s = {};
    s = __builtin_amdgcn_mfma_f32_16x16x32_bf16(ka0, Qb[0], s, 0, 0, 0);
    s = __builtin_amdgcn_mfma_f32_16x16x32_bf16(ka1, Qb[1], s, 0, 0, 0);
    Sf[mt] = s;
  }

  float mx = -1e30f;
  #pragma unroll
  for (int mt = 0; mt < 5; mt++)
    #pragma unroll
    for (int r = 0; r < 4; r++) {
      int key = mt*16 + 4*g + r;
      if (key >= 77) Sf[mt][r] = -1e30f;
      mx = fmaxf(mx, Sf[mt][r]);
    }
  mx = fmaxf(mx, __shfl_xor(mx, 16));
  mx = fmaxf(mx, __shfl_xor(mx, 32));
  float rsum = 0.f;
  #pragma unroll
  for (int mt = 0; mt < 5; mt++)
    #pragma unroll
    for (int r = 0; r < 4; r++) {
      float p = exp2f(Sf[mt][r] - mx);
      Sf[mt][r] = p; rsum += p;
    }
  rsum += __shfl_xor(rsum, 16);
  rsum += __shfl_xor(rsum, 32);

  #pragma unroll
  for (int mt = 0; mt < 5; mt++) {
    uint2 pk;
    pk.x = pack2(Sf[mt][0], Sf[mt][1]);
    pk.y = pack2(Sf[mt][2], Sf[mt][3]);
    *(uint2*)&PsT[w][l16][mt*16 + 4*g] = pk;
  }
  __syncthreads();

  float4v Of[3] = {};
  #pragma unroll
  for (int ks = 0; ks < 3; ks++) {
    short8v pb = *(const short8v*)&PsT[w][l16][ks*32 + g*8];
    #pragma unroll
    for (int mt = 0; mt < 3; mt++) {
      short8v va = *(const short8v*)&Vt[mt*16 + l16][ks*32 + g*8];
      Of[mt] = __builtin_amdgcn_mfma_f32_16x16x32_bf16(va, pb, Of[mt], 0, 0, 0);
    }
  }

  float inv = 1.f / rsum;
  u16* orow = O + (size_t)(q0 + w*16 + l16)*320 + h*40;
  #pragma unroll
  for (int mt = 0; mt < 3; mt++) {
    #pragma unroll
    for (int rp = 0; rp < 2; rp++) {
      int d = mt*16 + 4*g + rp*2;
      if (d < 40)
        *(unsigned*)&orow[d] = pack2(Of[mt][rp*2] * inv, Of[mt][rp*2+1] * inv);
    }
  }
}

extern "C" void kernel_launch(void* const* d_in, const int* in_sizes, int n_in,
                              void* d_out, int out_size, void* d_ws, size_t ws_size,
                              hipStream_t stream) {
  const float* x        = (const float*)d_in[0];
  const float* ctx      = (const float*)d_in[1];
  const float* gn_s     = (const float*)d_in[2];
  const float* gn_b     = (const float*)d_in[3];
  const float* w_pin    = (const float*)d_in[4];
  const float* b_pin    = (const float*)d_in[5];
  const float* ln1_s    = (const float*)d_in[6];
  const float* ln1_b    = (const float*)d_in[7];
  const float* wq1      = (const float*)d_in[8];
  const float* wk1      = (const float*)d_in[9];
  const float* wv1      = (const float*)d_in[10];
  const float* wo1      = (const float*)d_in[11];
  const float* bo1      = (const float*)d_in[12];
  const float* ln2_s    = (const float*)d_in[13];
  const float* ln2_b    = (const float*)d_in[14];
  const float* wq2      = (const float*)d_in[15];
  const float* wk2      = (const float*)d_in[16];
  const float* wv2      = (const float*)d_in[17];
  const float* wo2      = (const float*)d_in[18];
  const float* bo2      = (const float*)d_in[19];
  const float* ln3_s    = (const float*)d_in[20];
  const float* ln3_b    = (const float*)d_in[21];
  const float* w_ff1    = (const float*)d_in[22];
  const float* b_ff1    = (const float*)d_in[23];
  const float* w_ff2    = (const float*)d_in[24];
  const float* b_ff2    = (const float*)d_in[25];
  const float* w_pout   = (const float*)d_in[26];
  const float* b_pout   = (const float*)d_in[27];
  float* out = (float*)d_out;

  u16* ws = (u16*)d_ws;
  const size_t HB = 4096u*320u;
  u16* h   = ws;
  u16* hn  = ws + HB;
  u16* q   = ws + 2*HB;    // q,k contiguous (QKV fused epilogue)
  u16* k   = ws + 3*HB;
  u16* vT  = ws + 4*HB;    // V^T [320][4096]
  u16* ao  = ws + 5*HB;
  u16* gnT = k;
  u16* gg  = q;            // GEGLU out overlays q,k,vT,ao
  u16* wb  = ws + 6*HB;
  size_t o = 0;
  u16* ctxb   = wb + o; o += 59136;
  u16* wq1T   = wb + o; o += 102400;   // stacked: wq1T,wk1T,wv1T = [960][320]
  u16* wk1T   = wb + o; o += 102400;
  u16* wv1T   = wb + o; o += 102400;
  u16* wo1T   = wb + o; o += 102400;
  u16* wq2T   = wb + o; o += 102400;
  u16* wk2T   = wb + o; o += 245760;   // stacked: wk2T,wv2T = [640][768]
  u16* wv2T   = wb + o; o += 245760;
  u16* wo2T   = wb + o; o += 102400;
  u16* wff1T  = wb + o; o += 819200;
  u16* wff2T  = wb + o; o += 409600;
  u16* wpoutT = wb + o; o += 102400;
  u16* wpinT  = wb + o; o += 102400;
  u16* kc     = wb + o; o += 24640;    // kc,vc contiguous, segStride 24640
  u16* vc     = wb + o; o += 24640;
  float* chscale = (float*)(wb + o);
  float* chshift = chscale + 320;
  float* Opart = chshift + 320;        // 4 x 4096 x 320 fp32 = 21 MB
  float* Mpart = Opart + 4*HB;
  float* Lpart = Mpart + 4*32768;

  TPack tp;
  const float* srcs[12] = {wq1, wk1, wv1, wo1, wq2, wo2, w_pin, w_pout, wk2, wv2, w_ff1, w_ff2};
  u16* dsts[12]         = {wq1T, wk1T, wv1T, wo1T, wq2T, wo2T, wpinT, wpoutT, wk2T, wv2T, wff1T, wff2T};
  int Ks[12] = {320,320,320,320,320,320,320,320,768,768,320,1280};
  int Ns[12] = {320,320,320,320,320,320,320,320,320,320,2560,320};
  int off = 0;
  for (int i = 0; i < 12; i++) {
    tp.d[i].src = srcs[i]; tp.d[i].dst = dsts[i];
    tp.d[i].K = Ks[i]; tp.d[i].N = Ns[i];
    tp.d[i].off = off; tp.d[i].tx = Ns[i]/32;
    tp.d[i].sc = (i == 0 || i == 4) ? SCALE_L2E : 1.0f;   // wq1, wq2 pre-scaled
    off += (Ks[i]/32)*(Ns[i]/32);
  }

  dim3 blk(256), g64x5(64, 5);
  const u16* nres = nullptr;
  const float* nb = nullptr;

  hipLaunchKernelGGL(prep_kernel, dim3(off + 58 + 32), blk, 0, stream,
                     tp, off, ctx, ctxb, x, gn_s, gn_b, chscale, chshift);
  hipLaunchKernelGGL(gn_apply_t_kernel, g64x5, blk, 0, stream, x, chscale, chshift, gnT);
  hipLaunchKernelGGL((mgemm<0>), g64x5, blk, 0, stream, gnT, wpinT, b_pin, nres, nb, (void*)h, 4096, 320, 320, 0);
  hipLaunchKernelGGL(layernorm_kernel, dim3(4096), dim3(64), 0, stream, h, ln1_s, ln1_b, hn);
  // fused QKV: N=960; segs 0,1 -> q,k; seg 2 -> vT (transposed)
  hipLaunchKernelGGL((mgemm<3>), dim3(64, 15), blk, 0, stream, hn, wq1T, nb, nres, (const float*)vT, (void*)q, 4096, 960, 320, (int)HB);
  hipLaunchKernelGGL(self_attn_part, dim3(32, 8, 4), dim3(512), 0, stream, q, k, vT, Opart, Mpart, Lpart);
  hipLaunchKernelGGL(attn_merge, dim3(2560), blk, 0, stream, Opart, Mpart, Lpart, ao);
  hipLaunchKernelGGL((mgemm<0>), g64x5, blk, 0, stream, ao, wo1T, bo1, h, nb, (void*)h, 4096, 320, 320, 0);
  hipLaunchKernelGGL(layernorm_kernel, dim3(4096), dim3(64), 0, stream, h, ln2_s, ln2_b, hn);
  hipLaunchKernelGGL((mgemm<0>), g64x5, blk, 0, stream, hn, wq2T, nb, nres, nb, (void*)q, 4096, 320, 320, 0);
  hipLaunchKernelGGL((mgemm<1>), dim3(2, 10), blk, 0, stream, ctxb, wk2T, nb, nres, nb, (void*)kc, 77, 640, 768, 24640);
  hipLaunchKernelGGL(cross_attn_mfma, dim3(64, 8), blk, 0, stream, q, kc, vc, ao);
  hipLaunchKernelGGL((mgemm<0>), g64x5, blk, 0, stream, ao, wo2T, bo2, h, nb, (void*)h, 4096, 320, 320, 0);
  hipLaunchKernelGGL(layernorm_kernel, dim3(4096), dim3(64), 0, stream, h, ln3_s, ln3_b, hn);
  hipLaunchKernelGGL(geglu_mfma, dim3(64, 20), blk, 0, stream, hn, wff1T, b_ff1, gg);
  hipLaunchKernelGGL((mgemm<0>), g64x5, blk, 0, stream, gg, wff2T, b_ff2, h, nb, (void*)h, 4096, 320, 1280, 0);
  hipLaunchKernelGGL((mgemm<2>), g64x5, blk, 0, stream, h, wpoutT, b_pout, nres, x, (void*)out, 4096, 320, 320, 0);
}

// Round 10
// 342.405 us; speedup vs baseline: 1.4051x; 1.0180x over previous
//
#include <hip/hip_runtime.h>
#include <hip/hip_bf16.h>
#include <math.h>

#define SCALE_L2E  0.22811011265722836f   // (1/sqrt(40)) * log2(e)

typedef __attribute__((ext_vector_type(8))) short short8v;
typedef __attribute__((ext_vector_type(4))) float float4v;
typedef unsigned short u16;

__device__ __forceinline__ unsigned pack2(float a, float b) {
  float2 f; f.x = a; f.y = b;
  __hip_bfloat162 h = __float22bfloat162_rn(f);
  return *(unsigned*)&h;
}
__device__ __forceinline__ float bfu2f(u16 u) {
  return __uint_as_float(((unsigned)u) << 16);
}
__device__ __forceinline__ u16 f2bf(float x) {
  __hip_bfloat16 h = __float2bfloat16(x);
  return *(u16*)&h;
}

// ---------------- prep: weight transpose+convert (opt. scale) | ctx cvt | gn stats ----------
struct TDesc { const float* src; u16* dst; int K, N, off, tx; float sc; };
struct TPack { TDesc d[12]; };

__global__ __launch_bounds__(256) void prep_kernel(
    TPack p, int nT,
    const float* __restrict__ ctxsrc, u16* __restrict__ ctxdst,
    const float* __restrict__ x, const float* __restrict__ gs,
    const float* __restrict__ gb, float* __restrict__ chscale, float* __restrict__ chshift) {
  __shared__ float ls[32][33];
  int bt = blockIdx.x, t = threadIdx.x;
  if (bt < nT) {
    int ti = 0;
    #pragma unroll
    for (int i = 1; i < 12; i++) if (bt >= p.d[i].off) ti = i;
    TDesc dd = p.d[ti];
    int local = bt - dd.off;
    int n0 = (local % dd.tx) * 32, k0 = (local / dd.tx) * 32;
    #pragma unroll
    for (int i = 0; i < 4; i++) {
      int idx = t + i*256, r = idx >> 5, c = idx & 31;
      ls[r][c] = dd.src[(size_t)(k0 + r)*dd.N + n0 + c];
    }
    __syncthreads();
    #pragma unroll
    for (int i = 0; i < 2; i++) {
      int p2 = t + i*256, n = p2 >> 4, kp = (p2 & 15)*2;
      *(unsigned*)&dd.dst[(size_t)(n0 + n)*dd.K + k0 + kp] =
        pack2(ls[kp][n]*dd.sc, ls[kp+1][n]*dd.sc);
    }
  } else if (bt < nT + 58) {
    int idx = ((bt - nT)*256 + t)*4;
    if (idx < 59136) {
      float4 v = *(const float4*)&ctxsrc[idx];
      uint2 o; o.x = pack2(v.x, v.y); o.y = pack2(v.z, v.w);
      *(uint2*)&ctxdst[idx] = o;
    }
  } else {
    int g = bt - nT - 58;
    size_t base = (size_t)g * 40960;
    float sum = 0.f, sq = 0.f;
    for (int e = t; e < 40960; e += 256) {
      float v = x[base + e];
      sum += v; sq += v * v;
    }
    float* s1 = &ls[0][0];
    float* s2 = &ls[8][0] + 8;
    s1[t] = sum; s2[t] = sq; __syncthreads();
    for (int st = 128; st > 0; st >>= 1) {
      if (t < st) { s1[t] += s1[t+st]; s2[t] += s2[t+st]; }
      __syncthreads();
    }
    float mu = s1[0] * (1.f/40960.f);
    float var = s2[0] * (1.f/40960.f) - mu*mu;
    float rs = rsqrtf(var + 1e-6f);
    if (t < 10) {
      int c = g*10 + t;
      float sc = rs * gs[c];
      chscale[c] = sc;
      chshift[c] = gb[c] - mu * sc;
    }
  }
}

// ---------------- GN apply + transpose: x[c][s] fp32 -> gnT[s][c] bf16 ----------------
__global__ __launch_bounds__(256) void gn_apply_t_kernel(
    const float* __restrict__ x, const float* __restrict__ chscale,
    const float* __restrict__ chshift, u16* __restrict__ gnT) {
  __shared__ float ts[64][65];
  __shared__ float scl[64], sft[64];
  int s0 = blockIdx.x * 64, c0 = blockIdx.y * 64;
  int t = threadIdx.x;
  if (t < 64) { scl[t] = chscale[c0 + t]; sft[t] = chshift[c0 + t]; }
  int crow = t >> 2, sch = (t & 3) * 16;
  #pragma unroll
  for (int j = 0; j < 4; j++) {
    float4 v = *(const float4*)&x[(size_t)(c0 + crow)*4096 + s0 + sch + 4*j];
    ts[crow][sch + 4*j + 0] = v.x; ts[crow][sch + 4*j + 1] = v.y;
    ts[crow][sch + 4*j + 2] = v.z; ts[crow][sch + 4*j + 3] = v.w;
  }
  __syncthreads();
  int srow = t >> 2, cch = (t & 3) * 16;
  #pragma unroll
  for (int p = 0; p < 8; p++) {
    int cl = cch + 2*p;
    float f0 = ts[cl][srow] * scl[cl] + sft[cl];
    float f1 = ts[cl+1][srow] * scl[cl+1] + sft[cl+1];
    *(unsigned*)&gnT[(size_t)(s0 + srow)*320 + c0 + cl] = pack2(f0, f1);
  }
}

// ---------------- LayerNorm bf16->bf16: one wave per row of 320 ----------------
__global__ __launch_bounds__(64) void layernorm_kernel(
    const u16* __restrict__ X, const float* __restrict__ s,
    const float* __restrict__ b, u16* __restrict__ Y) {
  int row = blockIdx.x, t = threadIdx.x;
  const u16* xr = X + (size_t)row*320;
  float v[5], sum = 0.f, sq = 0.f;
  #pragma unroll
  for (int i = 0; i < 5; i++) { v[i] = bfu2f(xr[t + 64*i]); sum += v[i]; sq += v[i]*v[i]; }
  #pragma unroll
  for (int o = 32; o > 0; o >>= 1) { sum += __shfl_down(sum, o); sq += __shfl_down(sq, o); }
  sum = __shfl(sum, 0); sq = __shfl(sq, 0);
  float mu = sum * (1.f/320.f);
  float var = sq * (1.f/320.f) - mu*mu;
  float rs = rsqrtf(var + 1e-5f);
  u16* yr = Y + (size_t)row*320;
  #pragma unroll
  for (int i = 0; i < 5; i++) {
    int c = t + 64*i;
    yr[c] = f2bf((v[i]-mu)*rs*s[c] + b[c]);
  }
}

// ---------------- One-shot GEMM: C[M,320] = A[M,K] * BT[320,K]^T, K in 320-chunks ---------
// BM=64, BN=32, one barrier pair per 320-K chunk. Grid (M/64, 10).
// MODE 0: bf16 out, optional bias/res. MODE 2: proj_out fp32 transposed + xres.
template<int MODE>
__global__ __launch_bounds__(256) void oneshot(
    const u16* __restrict__ A, const u16* __restrict__ BT,
    const float* __restrict__ bias, const u16* __restrict__ res,
    const float* __restrict__ xres, void* __restrict__ Cout,
    int K, int chunks) {
  __shared__ __align__(16) u16 As[64*328];
  __shared__ __align__(16) u16 Bs[32*328];
  const int t = threadIdx.x;
  const int lane = t & 63, w = t >> 6, l16 = lane & 15, g = lane >> 4;
  const int bm = blockIdx.x * 64, bn = blockIdx.y * 32;
  const int m0 = (w & 1) * 32, n0 = (w >> 1) * 16;
  float4v acc[2] = {};

  const u16* Ab = A + (size_t)(bm + (t>>2))*K + (t&3)*16;
  u16* Al = As + (t>>2)*328 + (t&3)*16;
  const u16* Bb = BT + (size_t)(bn + (t>>3))*K + (t&7)*16;
  u16* Bl = Bs + (t>>3)*328 + (t&7)*16;
  const bool b3 = (t & 7) < 4;

  for (int ch = 0; ch < chunks; ch++) {
    const int c0 = ch*320;
    __syncthreads();
    // NOTE: short8v = 8 u16 (16 B). Each 16-element slot needs TWO loads (+0, +8).
    #pragma unroll
    for (int j = 0; j < 5; j++) {
      *(short8v*)(Al + 64*j)     = *(const short8v*)(Ab + c0 + 64*j);
      *(short8v*)(Al + 64*j + 8) = *(const short8v*)(Ab + c0 + 64*j + 8);
    }
    *(short8v*)Bl         = *(const short8v*)(Bb + c0);
    *(short8v*)(Bl + 8)   = *(const short8v*)(Bb + c0 + 8);
    *(short8v*)(Bl + 128) = *(const short8v*)(Bb + c0 + 128);
    *(short8v*)(Bl + 136) = *(const short8v*)(Bb + c0 + 136);
    if (b3) {
      *(short8v*)(Bl + 256) = *(const short8v*)(Bb + c0 + 256);
      *(short8v*)(Bl + 264) = *(const short8v*)(Bb + c0 + 264);
    }
    __syncthreads();
    #pragma unroll
    for (int ks = 0; ks < 10; ks++) {
      short8v bfv = *(const short8v*)&Bs[(n0 + l16)*328 + ks*32 + g*8];
      #pragma unroll
      for (int mt = 0; mt < 2; mt++) {
        short8v af = *(const short8v*)&As[(m0 + 16*mt + l16)*328 + ks*32 + g*8];
        acc[mt] = __builtin_amdgcn_mfma_f32_16x16x32_bf16(af, bfv, acc[mt], 0, 0, 0);
      }
    }
  }
  __syncthreads();
  float* Cs = (float*)As;   // [64][36]
  #pragma unroll
  for (int mt = 0; mt < 2; mt++)
    #pragma unroll
    for (int r = 0; r < 4; r++)
      Cs[(m0 + 16*mt + 4*g + r)*36 + n0 + l16] = acc[mt][r];
  __syncthreads();

  if (MODE == 0) {
    u16* C = (u16*)Cout;
    #pragma unroll
    for (int i = 0; i < 4; i++) {
      int p = t + i*256;
      int mm = p >> 4, pp = (p & 15)*2;
      float f0 = Cs[mm*36 + pp], f1 = Cs[mm*36 + pp + 1];
      if (bias) { f0 += bias[bn + pp]; f1 += bias[bn + pp + 1]; }
      if (res) {
        unsigned u = *(const unsigned*)&res[(size_t)(bm + mm)*320 + bn + pp];
        f0 += bfu2f((u16)(u & 0xffffu));
        f1 += bfu2f((u16)(u >> 16));
      }
      *(unsigned*)&C[(size_t)(bm + mm)*320 + bn + pp] = pack2(f0, f1);
    }
  } else {
    float* C = (float*)Cout;
    int nloc = t >> 3, mch = (t & 7) * 8;
    float bb = bias[bn + nloc];
    #pragma unroll
    for (int j = 0; j < 2; j++) {
      int m4 = mch + j*4;
      float4 xv = *(const float4*)&xres[(size_t)(bn + nloc)*4096 + bm + m4];
      float4 ov;
      ov.x = Cs[(m4+0)*36 + nloc] + bb + xv.x;
      ov.y = Cs[(m4+1)*36 + nloc] + bb + xv.y;
      ov.z = Cs[(m4+2)*36 + nloc] + bb + xv.z;
      ov.w = Cs[(m4+3)*36 + nloc] + bb + xv.w;
      *(float4*)&C[(size_t)(bn + nloc)*4096 + bm + m4] = ov;
    }
  }
}

// ---------------- MFMA GEMM (looped BK=64): used for QKV (MODE 3) and kc/vc (MODE 1) ------
template<int MODE>
__global__ __launch_bounds__(256) void mgemm(
    const u16* __restrict__ A, const u16* __restrict__ BT,
    const float* __restrict__ bias, const u16* __restrict__ res,
    const float* __restrict__ xres, void* __restrict__ Cout,
    int M, int N, int K, int segStride) {
  __shared__ __align__(16) u16 smem[2*64*72];
  u16* As = smem;
  u16* Bs = smem + 64*72;
  const int t = threadIdx.x;
  const int lane = t & 63, w = t >> 6, l16 = lane & 15, g = lane >> 4;
  const int bm = blockIdx.x * 64, bn = blockIdx.y * 64;
  const int m0 = (w & 1) * 32, n0 = (w >> 1) * 32;
  float4v acc[2][2] = {};
  const int ar = t >> 2, ac = (t & 3) * 16;
  const bool aok = (bm + ar) < M;

  for (int k0 = 0; k0 < K; k0 += 64) {
    __syncthreads();
    short8v a0 = {}, a1 = {};
    if (aok) {
      const u16* ga = &A[(size_t)(bm + ar)*K + k0 + ac];
      a0 = *(const short8v*)ga; a1 = *(const short8v*)(ga + 8);
    }
    *(short8v*)&As[ar*72 + ac] = a0;
    *(short8v*)&As[ar*72 + ac + 8] = a1;
    const u16* gbp = &BT[(size_t)(bn + ar)*K + k0 + ac];
    *(short8v*)&Bs[ar*72 + ac] = *(const short8v*)gbp;
    *(short8v*)&Bs[ar*72 + ac + 8] = *(const short8v*)(gbp + 8);
    __syncthreads();
    #pragma unroll
    for (int ks = 0; ks < 2; ks++) {
      short8v af[2], bfv[2];
      #pragma unroll
      for (int mt = 0; mt < 2; mt++)
        af[mt] = *(const short8v*)&As[(m0 + 16*mt + l16)*72 + ks*32 + g*8];
      #pragma unroll
      for (int nt = 0; nt < 2; nt++)
        bfv[nt] = *(const short8v*)&Bs[(n0 + 16*nt + l16)*72 + ks*32 + g*8];
      #pragma unroll
      for (int mt = 0; mt < 2; mt++)
        #pragma unroll
        for (int nt = 0; nt < 2; nt++)
          acc[mt][nt] = __builtin_amdgcn_mfma_f32_16x16x32_bf16(af[mt], bfv[nt], acc[mt][nt], 0, 0, 0);
    }
  }
  __syncthreads();
  float* Cs = (float*)smem;  // [64][68]
  #pragma unroll
  for (int mt = 0; mt < 2; mt++)
    #pragma unroll
    for (int nt = 0; nt < 2; nt++)
      #pragma unroll
      for (int r = 0; r < 4; r++)
        Cs[(m0 + 16*mt + 4*g + r)*68 + n0 + 16*nt + l16] = acc[mt][nt][r];
  __syncthreads();

  if (MODE == 1) {
    u16* C = (u16*)Cout + (size_t)(bn / 320) * segStride;
    int nb = bn % 320;
    #pragma unroll
    for (int i = 0; i < 8; i++) {
      int p = t + i*256;
      int mm = p >> 5, nn = (p & 31)*2;
      int gm = bm + mm;
      if (gm >= M) continue;
      *(unsigned*)&C[(size_t)gm*320 + nb + nn] = pack2(Cs[mm*68 + nn], Cs[mm*68 + nn + 1]);
    }
  } else if (MODE == 3) {
    if (bn < 640) {
      u16* C = (u16*)Cout + (size_t)(bn / 320) * segStride;
      int nb = bn % 320;
      #pragma unroll
      for (int i = 0; i < 8; i++) {
        int p = t + i*256;
        int mm = p >> 5, nn = (p & 31)*2;
        *(unsigned*)&C[(size_t)(bm + mm)*320 + nb + nn] = pack2(Cs[mm*68 + nn], Cs[mm*68 + nn + 1]);
      }
    } else {
      u16* vTp = (u16*)(void*)xres;
      int nloc = t >> 2, mch = (t & 3) * 16;
      int vd = bn - 640 + nloc;
      u16* dst = vTp + (size_t)vd*4096 + bm + mch;
      unsigned buf[8];
      #pragma unroll
      for (int jj = 0; jj < 8; jj++)
        buf[jj] = pack2(Cs[(mch + 2*jj)*68 + nloc], Cs[(mch + 2*jj + 1)*68 + nloc]);
      uint4 o0; o0.x = buf[0]; o0.y = buf[1]; o0.z = buf[2]; o0.w = buf[3];
      uint4 o1; o1.x = buf[4]; o1.y = buf[5]; o1.z = buf[6]; o1.w = buf[7];
      *(uint4*)dst = o0;
      *(uint4*)(dst + 8) = o1;
    }
  }
}

// ---------------- GEGLU MFMA ----------------
__global__ __launch_bounds__(256) void geglu_mfma(
    const u16* __restrict__ A, const u16* __restrict__ BT,
    const float* __restrict__ bias, u16* __restrict__ C) {
  __shared__ __align__(16) u16 smem[3*64*72];
  u16* As = smem;
  u16* Ba = smem + 64*72;
  u16* Bg = smem + 2*64*72;
  const int t = threadIdx.x;
  const int lane = t & 63, w = t >> 6, l16 = lane & 15, g = lane >> 4;
  const int bm = blockIdx.x * 64, bn = blockIdx.y * 64;
  const int m0 = (w & 1) * 32, n0 = (w >> 1) * 32;
  float4v aacc[2][2] = {}, gacc[2][2] = {};
  const int ar = t >> 2, ac = (t & 3) * 16;

  for (int k0 = 0; k0 < 320; k0 += 64) {
    __syncthreads();
    {
      const u16* ga = &A[(size_t)(bm + ar)*320 + k0 + ac];
      *(short8v*)&As[ar*72 + ac] = *(const short8v*)ga;
      *(short8v*)&As[ar*72 + ac + 8] = *(const short8v*)(ga + 8);
      const u16* gba = &BT[(size_t)(bn + ar)*320 + k0 + ac];
      *(short8v*)&Ba[ar*72 + ac] = *(const short8v*)gba;
      *(short8v*)&Ba[ar*72 + ac + 8] = *(const short8v*)(gba + 8);
      const u16* gbg = &BT[(size_t)(1280 + bn + ar)*320 + k0 + ac];
      *(short8v*)&Bg[ar*72 + ac] = *(const short8v*)gbg;
      *(short8v*)&Bg[ar*72 + ac + 8] = *(const short8v*)(gbg + 8);
    }
    __syncthreads();
    #pragma unroll
    for (int ks = 0; ks < 2; ks++) {
      short8v af[2], bav[2], bgv[2];
      #pragma unroll
      for (int mt = 0; mt < 2; mt++)
        af[mt] = *(const short8v*)&As[(m0 + 16*mt + l16)*72 + ks*32 + g*8];
      #pragma unroll
      for (int nt = 0; nt < 2; nt++) {
        bav[nt] = *(const short8v*)&Ba[(n0 + 16*nt + l16)*72 + ks*32 + g*8];
        bgv[nt] = *(const short8v*)&Bg[(n0 + 16*nt + l16)*72 + ks*32 + g*8];
      }
      #pragma unroll
      for (int mt = 0; mt < 2; mt++)
        #pragma unroll
        for (int nt = 0; nt < 2; nt++) {
          aacc[mt][nt] = __builtin_amdgcn_mfma_f32_16x16x32_bf16(af[mt], bav[nt], aacc[mt][nt], 0, 0, 0);
          gacc[mt][nt] = __builtin_amdgcn_mfma_f32_16x16x32_bf16(af[mt], bgv[nt], gacc[mt][nt], 0, 0, 0);
        }
    }
  }
  __syncthreads();
  float* Cs = (float*)smem;
  #pragma unroll
  for (int nt = 0; nt < 2; nt++) {
    int col = n0 + 16*nt + l16;
    float ba = bias[bn + col];
    float bg2 = bias[1280 + bn + col];
    #pragma unroll
    for (int mt = 0; mt < 2; mt++)
      #pragma unroll
      for (int r = 0; r < 4; r++) {
        float a = aacc[mt][nt][r] + ba;
        float gv = gacc[mt][nt][r] + bg2;
        float gl = 0.5f * gv * (1.f + erff(gv * 0.70710678118654752f));
        Cs[(m0 + 16*mt + 4*g + r)*68 + col] = a * gl;
      }
  }
  __syncthreads();
  #pragma unroll
  for (int i = 0; i < 8; i++) {
    int p = t + i*256;
    int mm = p >> 5, nn = (p & 31)*2;
    *(unsigned*)&C[(size_t)(bm + mm)*1280 + bn + nn] = pack2(Cs[mm*68 + nn], Cs[mm*68 + nn + 1]);
  }
}

// ---------------- Self-attention partial: max-free softmax, bf16 partials ----------------
// q pre-scaled by SCALE*log2e. Grid (32 qtiles of 128, 8 heads, 4 splits).
__global__ __launch_bounds__(512) void self_attn_part(
    const u16* __restrict__ Q, const u16* __restrict__ K,
    const u16* __restrict__ vT, u16* __restrict__ Opart,
    float* __restrict__ Lp) {
  const int h = blockIdx.y;
  const int q0 = blockIdx.x * 128;
  const int sp = blockIdx.z;
  const int tid = threadIdx.x;
  const int w = tid >> 6, lane = tid & 63;
  const int l16 = lane & 15, g = lane >> 4;

  __shared__ __align__(16) u16 Kls[64][72];
  __shared__ __align__(16) u16 Vt[48][72];
  __shared__ __align__(16) u16 PsT[8][16][72];

  for (int e = tid; e < 64*12; e += 512) {
    int r = e / 12, c = e % 12;
    *(unsigned*)&Kls[r][40 + 2*c] = 0u;
  }
  if (tid < 256) {
    int r = 40 + (tid >> 5), c = tid & 31;
    *(unsigned*)&Vt[r][2*c] = 0u;
  }

  short8v Qb[2];
  {
    const u16* qrow = Q + (size_t)(q0 + w*16 + l16)*320 + h*40;
    Qb[0] = *(const short8v*)(qrow + g*8);
    short8v z = {};
    Qb[1] = (g == 0) ? *(const short8v*)(qrow + 32) : z;
  }

  const u16* Kbase = K + (size_t)(sp*1024)*320 + h*40;
  const u16* Vbase = vT + (size_t)(h*40)*4096 + sp*1024;

  const int ksl = (tid < 320) ? tid : 0;
  const int keyK = ksl / 5, chK = ksl - keyK*5;
  const u16* gK = Kbase + (size_t)keyK*320 + chK*8;
  u16* lK = &Kls[keyK][chK*8];
  const int vsl = (tid >= 192) ? (tid - 192) : 0;
  const int dV = vsl >> 3, chV = vsl & 7;
  const u16* gV = Vbase + (size_t)dV*4096 + chV*8;
  u16* lV = &Vt[dV][chV*8];

  float l_i = 0.f;
  float4v Of[3] = {};

  for (int it = 0; it < 16; ++it) {
    __syncthreads();
    if (tid < 320) *(short8v*)lK = *(const short8v*)gK;
    if (tid >= 192) *(short8v*)lV = *(const short8v*)gV;
    gK += 64*320; gV += 64;
    __syncthreads();

    // S^T = K·Q^T (scores in exp2 units; bounded — no running max needed)
    float4v Sf[4];
    #pragma unroll
    for (int mt = 0; mt < 4; mt++) {
      short8v ka0 = *(const short8v*)&Kls[mt*16 + l16][g*8];
      short8v ka1 = *(const short8v*)&Kls[mt*16 + l16][32 + g*8];
      float4v s = {};
      s = __builtin_amdgcn_mfma_f32_16x16x32_bf16(ka0, Qb[0], s, 0, 0, 0);
      s = __builtin_amdgcn_mfma_f32_16x16x32_bf16(ka1, Qb[1], s, 0, 0, 0);
      Sf[mt] = s;
    }

    float rsum = 0.f;
    #pragma unroll
    for (int mt = 0; mt < 4; mt++)
      #pragma unroll
      for (int r = 0; r < 4; r++) {
        float p = exp2f(Sf[mt][r]);
        Sf[mt][r] = p; rsum += p;
      }
    rsum += __shfl_xor(rsum, 16);
    rsum += __shfl_xor(rsum, 32);
    l_i += rsum;

    #pragma unroll
    for (int mt = 0; mt < 4; mt++) {
      uint2 pk;
      pk.x = pack2(Sf[mt][0], Sf[mt][1]);
      pk.y = pack2(Sf[mt][2], Sf[mt][3]);
      *(uint2*)&PsT[w][l16][mt*16 + 4*g] = pk;
    }
    asm volatile("s_waitcnt lgkmcnt(0)" ::: "memory");

    #pragma unroll
    for (int ks = 0; ks < 2; ks++) {
      short8v pb = *(const short8v*)&PsT[w][l16][ks*32 + g*8];
      #pragma unroll
      for (int mt = 0; mt < 3; mt++) {
        short8v va = *(const short8v*)&Vt[mt*16 + l16][ks*32 + g*8];
        Of[mt] = __builtin_amdgcn_mfma_f32_16x16x32_bf16(va, pb, Of[mt], 0, 0, 0);
      }
    }
  }

  // store unnormalized partial O^T (bf16) + l
  const int q = q0 + w*16 + l16;
  u16* orow = Opart + (size_t)sp*4096*320 + (size_t)q*320 + h*40;
  #pragma unroll
  for (int mt = 0; mt < 3; mt++) {
    #pragma unroll
    for (int rp = 0; rp < 2; rp++) {
      int d = mt*16 + 4*g + rp*2;
      if (d < 40)
        *(unsigned*)&orow[d] = pack2(Of[mt][rp*2], Of[mt][rp*2+1]);
    }
  }
  if (g == 0)
    Lp[sp*32768 + q*8 + h] = l_i;
}

// ---------------- merge 4 partials (weights all 1) -> ao bf16 ----------------
__global__ __launch_bounds__(256) void attn_merge(
    const u16* __restrict__ Opart, const float* __restrict__ Lp,
    u16* __restrict__ O) {
  int gid = blockIdx.x*256 + threadIdx.x;   // < 4096*8*20
  int dp = gid % 20;
  int qh = gid / 20;
  int q = qh >> 3, h = qh & 7;
  float ls = Lp[qh] + Lp[32768 + qh] + Lp[2*32768 + qh] + Lp[3*32768 + qh];
  size_t base = (size_t)q*320 + h*40 + dp*2;
  const size_t HBu = 4096u*320u;
  float r0 = 0.f, r1 = 0.f;
  #pragma unroll
  for (int sp = 0; sp < 4; sp++) {
    unsigned u = *(const unsigned*)&Opart[sp*HBu + base];
    r0 += bfu2f((u16)(u & 0xffffu));
    r1 += bfu2f((u16)(u >> 16));
  }
  float inv = 1.f / ls;
  *(unsigned*)&O[base] = pack2(r0*inv, r1*inv);
}

// ---------------- Cross-attention: single-shot MFMA, 77 keys, max-free ----------------
__global__ __launch_bounds__(256) void cross_attn_mfma(
    const u16* __restrict__ Q, const u16* __restrict__ Kc,
    const u16* __restrict__ Vc, u16* __restrict__ O) {
  const int h = blockIdx.y;
  const int q0 = blockIdx.x * 64;
  const int tid = threadIdx.x;
  const int w = tid >> 6, lane = tid & 63;
  const int l16 = lane & 15, g = lane >> 4;

  __shared__ __align__(16) u16 Kls[80][72];
  __shared__ __align__(16) u16 Vt[48][104];
  __shared__ __align__(16) u16 PsT[4][16][104];

  for (int e = tid; e < 80*12; e += 256) {
    int r = e / 12, c = e % 12;
    *(unsigned*)&Kls[r][40 + 2*c] = 0u;
  }
  for (int e = tid; e < 48*52; e += 256) {
    int r = e / 52, c = e % 52;
    *(unsigned*)&Vt[r][2*c] = 0u;
  }
  {
    int r = lane >> 2, c4 = (lane & 3)*4;
    uint2 z; z.x = 0u; z.y = 0u;
    *(uint2*)&PsT[w][r][80 + c4] = z;
  }

  short8v Qb[2];
  {
    const u16* qrow = Q + (size_t)(q0 + w*16 + l16)*320 + h*40;
    Qb[0] = *(const short8v*)(qrow + g*8);
    short8v z = {};
    Qb[1] = (g == 0) ? *(const short8v*)(qrow + 32) : z;
  }

  for (int e = tid; e < 1600; e += 256) {
    int key = e / 20, dp = e % 20;
    unsigned val = 0u;
    if (key < 77) val = *(const unsigned*)&Kc[(size_t)key*320 + h*40 + dp*2];
    *(unsigned*)&Kls[key][dp*2] = val;
  }
  __syncthreads();
  for (int e = tid; e < 1600; e += 256) {
    int kp = e / 40, d = e % 40;
    unsigned u0 = (kp*2     < 77) ? (unsigned)Vc[(size_t)(kp*2    )*320 + h*40 + d] : 0u;
    unsigned u1 = (kp*2 + 1 < 77) ? (unsigned)Vc[(size_t)(kp*2 + 1)*320 + h*40 + d] : 0u;
    *(unsigned*)&Vt[d][kp*2] = u0 | (u1 << 16);
  }
  __syncthreads();

  float4v Sf[5];
  #pragma unroll
  for (int mt = 0; mt < 5; mt++) {
    short8v ka0 = *(const short8v*)&Kls[mt*16 + l16][g*8];
    short8v ka1 = *(const short8v*)&Kls[mt*16 + l16][32 + g*8];
    float4v s = {};
    s = __builtin_amdgcn_mfma_f32_16x16x32_bf16(ka0, Qb[0], s, 0, 0, 0);
    s = __builtin_amdgcn_mfma_f32_16x16x32_bf16(ka1, Qb[1], s, 0, 0, 0);
    Sf[mt] = s;
  }

  float rsum = 0.f;
  #pragma unroll
  for (int mt = 0; mt < 5; mt++)
    #pragma unroll
    for (int r = 0; r < 4; r++) {
      int key = mt*16 + 4*g + r;
      float p = (key < 77) ? exp2f(Sf[mt][r]) : 0.f;
      Sf[mt][r] = p; rsum += p;
    }
  rsum += __shfl_xor(rsum, 16);
  rsum += __shfl_xor(rsum, 32);

  #pragma unroll
  for (int mt = 0; mt < 5; mt++) {
    uint2 pk;
    pk.x = pack2(Sf[mt][0], Sf[mt][1]);
    pk.y = pack2(Sf[mt][2], Sf[mt][3]);
    *(uint2*)&PsT[w][l16][mt*16 + 4*g] = pk;
  }
  __syncthreads();

  float4v Of[3] = {};
  #pragma unroll
  for (int ks = 0; ks < 3; ks++) {
    short8v pb = *(const short8v*)&PsT[w][l16][ks*32 + g*8];
    #pragma unroll
    for (int mt = 0; mt < 3; mt++) {
      short8v va = *(const short8v*)&Vt[mt*16 + l16][ks*32 + g*8];
      Of[mt] = __builtin_amdgcn_mfma_f32_16x16x32_bf16(va, pb, Of[mt], 0, 0, 0);
    }
  }

  float inv = 1.f / rsum;
  u16* orow = O + (size_t)(q0 + w*16 + l16)*320 + h*40;
  #pragma unroll
  for (int mt = 0; mt < 3; mt++) {
    #pragma unroll
    for (int rp = 0; rp < 2; rp++) {
      int d = mt*16 + 4*g + rp*2;
      if (d < 40)
        *(unsigned*)&orow[d] = pack2(Of[mt][rp*2] * inv, Of[mt][rp*2+1] * inv);
    }
  }
}

extern "C" void kernel_launch(void* const* d_in, const int* in_sizes, int n_in,
                              void* d_out, int out_size, void* d_ws, size_t ws_size,
                              hipStream_t stream) {
  const float* x        = (const float*)d_in[0];
  const float* ctx      = (const float*)d_in[1];
  const float* gn_s     = (const float*)d_in[2];
  const float* gn_b     = (const float*)d_in[3];
  const float* w_pin    = (const float*)d_in[4];
  const float* b_pin    = (const float*)d_in[5];
  const float* ln1_s    = (const float*)d_in[6];
  const float* ln1_b    = (const float*)d_in[7];
  const float* wq1      = (const float*)d_in[8];
  const float* wk1      = (const float*)d_in[9];
  const float* wv1      = (const float*)d_in[10];
  const float* wo1      = (const float*)d_in[11];
  const float* bo1      = (const float*)d_in[12];
  const float* ln2_s    = (const float*)d_in[13];
  const float* ln2_b    = (const float*)d_in[14];
  const float* wq2      = (const float*)d_in[15];
  const float* wk2      = (const float*)d_in[16];
  const float* wv2      = (const float*)d_in[17];
  const float* wo2      = (const float*)d_in[18];
  const float* bo2      = (const float*)d_in[19];
  const float* ln3_s    = (const float*)d_in[20];
  const float* ln3_b    = (const float*)d_in[21];
  const float* w_ff1    = (const float*)d_in[22];
  const float* b_ff1    = (const float*)d_in[23];
  const float* w_ff2    = (const float*)d_in[24];
  const float* b_ff2    = (const float*)d_in[25];
  const float* w_pout   = (const float*)d_in[26];
  const float* b_pout   = (const float*)d_in[27];
  float* out = (float*)d_out;

  u16* ws = (u16*)d_ws;
  const size_t HB = 4096u*320u;
  u16* h   = ws;
  u16* hn  = ws + HB;
  u16* q   = ws + 2*HB;    // q,k contiguous (QKV fused epilogue)
  u16* k   = ws + 3*HB;
  u16* vT  = ws + 4*HB;    // V^T [320][4096]
  u16* ao  = ws + 5*HB;
  u16* gnT = k;
  u16* gg  = q;            // GEGLU out overlays q,k,vT,ao
  u16* wb  = ws + 6*HB;
  size_t o = 0;
  u16* ctxb   = wb + o; o += 59136;
  u16* wq1T   = wb + o; o += 102400;   // stacked: wq1T,wk1T,wv1T = [960][320]
  u16* wk1T   = wb + o; o += 102400;
  u16* wv1T   = wb + o; o += 102400;
  u16* wo1T   = wb + o; o += 102400;
  u16* wq2T   = wb + o; o += 102400;
  u16* wk2T   = wb + o; o += 245760;   // stacked: wk2T,wv2T = [640][768]
  u16* wv2T   = wb + o; o += 245760;
  u16* wo2T   = wb + o; o += 102400;
  u16* wff1T  = wb + o; o += 819200;
  u16* wff2T  = wb + o; o += 409600;
  u16* wpoutT = wb + o; o += 102400;
  u16* wpinT  = wb + o; o += 102400;
  u16* kc     = wb + o; o += 24640;    // kc,vc contiguous, segStride 24640
  u16* vc     = wb + o; o += 24640;
  float* chscale = (float*)(wb + o);
  float* chshift = chscale + 320;
  u16* OpartB = (u16*)(chshift + 320);           // 4 x HB bf16 = 10.5 MB
  float* Lpart = (float*)(OpartB + 4*HB);        // 4 x 32768 fp32

  TPack tp;
  const float* srcs[12] = {wq1, wk1, wv1, wo1, wq2, wo2, w_pin, w_pout, wk2, wv2, w_ff1, w_ff2};
  u16* dsts[12]         = {wq1T, wk1T, wv1T, wo1T, wq2T, wo2T, wpinT, wpoutT, wk2T, wv2T, wff1T, wff2T};
  int Ks[12] = {320,320,320,320,320,320,320,320,768,768,320,1280};
  int Ns[12] = {320,320,320,320,320,320,320,320,320,320,2560,320};
  int off = 0;
  for (int i = 0; i < 12; i++) {
    tp.d[i].src = srcs[i]; tp.d[i].dst = dsts[i];
    tp.d[i].K = Ks[i]; tp.d[i].N = Ns[i];
    tp.d[i].off = off; tp.d[i].tx = Ns[i]/32;
    tp.d[i].sc = (i == 0 || i == 4) ? SCALE_L2E : 1.0f;   // wq1, wq2 pre-scaled
    off += (Ks[i]/32)*(Ns[i]/32);
  }

  dim3 blk(256), g64x10(64, 10), g64x5(64, 5);
  const u16* nres = nullptr;
  const float* nb = nullptr;

  hipLaunchKernelGGL(prep_kernel, dim3(off + 58 + 32), blk, 0, stream,
                     tp, off, ctx, ctxb, x, gn_s, gn_b, chscale, chshift);
  hipLaunchKernelGGL(gn_apply_t_kernel, g64x5, blk, 0, stream, x, chscale, chshift, gnT);
  hipLaunchKernelGGL((oneshot<0>), g64x10, blk, 0, stream, gnT, wpinT, b_pin, nres, nb, (void*)h, 320, 1);
  hipLaunchKernelGGL(layernorm_kernel, dim3(4096), dim3(64), 0, stream, h, ln1_s, ln1_b, hn);
  // fused QKV: N=960; segs 0,1 -> q,k; seg 2 -> vT (transposed)
  hipLaunchKernelGGL((mgemm<3>), dim3(64, 15), blk, 0, stream, hn, wq1T, nb, nres, (const float*)vT, (void*)q, 4096, 960, 320, (int)HB);
  hipLaunchKernelGGL(self_attn_part, dim3(32, 8, 4), dim3(512), 0, stream, q, k, vT, OpartB, Lpart);
  hipLaunchKernelGGL(attn_merge, dim3(2560), blk, 0, stream, OpartB, Lpart, ao);
  hipLaunchKernelGGL((oneshot<0>), g64x10, blk, 0, stream, ao, wo1T, bo1, h, nb, (void*)h, 320, 1);
  hipLaunchKernelGGL(layernorm_kernel, dim3(4096), dim3(64), 0, stream, h, ln2_s, ln2_b, hn);
  hipLaunchKernelGGL((oneshot<0>), g64x10, blk, 0, stream, hn, wq2T, nb, nres, nb, (void*)q, 320, 1);
  hipLaunchKernelGGL((mgemm<1>), dim3(2, 10), blk, 0, stream, ctxb, wk2T, nb, nres, nb, (void*)kc, 77, 640, 768, 24640);
  hipLaunchKernelGGL(cross_attn_mfma, dim3(64, 8), blk, 0, stream, q, kc, vc, ao);
  hipLaunchKernelGGL((oneshot<0>), g64x10, blk, 0, stream, ao, wo2T, bo2, h, nb, (void*)h, 320, 1);
  hipLaunchKernelGGL(layernorm_kernel, dim3(4096), dim3(64), 0, stream, h, ln3_s, ln3_b, hn);
  hipLaunchKernelGGL(geglu_mfma, dim3(64, 20), blk, 0, stream, hn, wff1T, b_ff1, gg);
  hipLaunchKernelGGL((oneshot<0>), g64x10, blk, 0, stream, gg, wff2T, b_ff2, h, nb, (void*)h, 1280, 4);
  hipLaunchKernelGGL((oneshot<2>), g64x10, blk, 0, stream, h, wpoutT, b_pout, nres, x, (void*)out, 320, 1);
}

// Round 11
// 335.003 us; speedup vs baseline: 1.4361x; 1.0221x over previous
//
#include <hip/hip_runtime.h>
#include <hip/hip_bf16.h>
#include <math.h>

#define SCALE_L2E  0.22811011265722836f   // (1/sqrt(40)) * log2(e)

typedef __attribute__((ext_vector_type(8))) short short8v;
typedef __attribute__((ext_vector_type(4))) float float4v;
typedef unsigned short u16;

__device__ __forceinline__ unsigned pack2(float a, float b) {
  float2 f; f.x = a; f.y = b;
  __hip_bfloat162 h = __float22bfloat162_rn(f);
  return *(unsigned*)&h;
}
__device__ __forceinline__ float bfu2f(u16 u) {
  return __uint_as_float(((unsigned)u) << 16);
}
__device__ __forceinline__ u16 f2bf(float x) {
  __hip_bfloat16 h = __float2bfloat16(x);
  return *(u16*)&h;
}

// ---------------- prep: weight transpose+convert (opt. scale) | ctx cvt | gn stats ----------
struct TDesc { const float* src; u16* dst; int K, N, off, tx; float sc; };
struct TPack { TDesc d[12]; };

__global__ __launch_bounds__(256) void prep_kernel(
    TPack p, int nT,
    const float* __restrict__ ctxsrc, u16* __restrict__ ctxdst,
    const float* __restrict__ x, const float* __restrict__ gs,
    const float* __restrict__ gb, float* __restrict__ chscale, float* __restrict__ chshift) {
  __shared__ float ls[32][33];
  int bt = blockIdx.x, t = threadIdx.x;
  if (bt < nT) {
    int ti = 0;
    #pragma unroll
    for (int i = 1; i < 12; i++) if (bt >= p.d[i].off) ti = i;
    TDesc dd = p.d[ti];
    int local = bt - dd.off;
    int n0 = (local % dd.tx) * 32, k0 = (local / dd.tx) * 32;
    #pragma unroll
    for (int i = 0; i < 4; i++) {
      int idx = t + i*256, r = idx >> 5, c = idx & 31;
      ls[r][c] = dd.src[(size_t)(k0 + r)*dd.N + n0 + c];
    }
    __syncthreads();
    #pragma unroll
    for (int i = 0; i < 2; i++) {
      int p2 = t + i*256, n = p2 >> 4, kp = (p2 & 15)*2;
      *(unsigned*)&dd.dst[(size_t)(n0 + n)*dd.K + k0 + kp] =
        pack2(ls[kp][n]*dd.sc, ls[kp+1][n]*dd.sc);
    }
  } else if (bt < nT + 58) {
    int idx = ((bt - nT)*256 + t)*4;
    if (idx < 59136) {
      float4 v = *(const float4*)&ctxsrc[idx];
      uint2 o; o.x = pack2(v.x, v.y); o.y = pack2(v.z, v.w);
      *(uint2*)&ctxdst[idx] = o;
    }
  } else {
    int g = bt - nT - 58;
    size_t base = (size_t)g * 40960;
    float sum = 0.f, sq = 0.f;
    for (int e = t; e < 40960; e += 256) {
      float v = x[base + e];
      sum += v; sq += v * v;
    }
    float* s1 = &ls[0][0];
    float* s2 = &ls[8][0] + 8;
    s1[t] = sum; s2[t] = sq; __syncthreads();
    for (int st = 128; st > 0; st >>= 1) {
      if (t < st) { s1[t] += s1[t+st]; s2[t] += s2[t+st]; }
      __syncthreads();
    }
    float mu = s1[0] * (1.f/40960.f);
    float var = s2[0] * (1.f/40960.f) - mu*mu;
    float rs = rsqrtf(var + 1e-6f);
    if (t < 10) {
      int c = g*10 + t;
      float sc = rs * gs[c];
      chscale[c] = sc;
      chshift[c] = gb[c] - mu * sc;
    }
  }
}

// ---------------- GN apply + transpose: x[c][s] fp32 -> gnT[s][c] bf16 ----------------
__global__ __launch_bounds__(256) void gn_apply_t_kernel(
    const float* __restrict__ x, const float* __restrict__ chscale,
    const float* __restrict__ chshift, u16* __restrict__ gnT) {
  __shared__ float ts[64][65];
  __shared__ float scl[64], sft[64];
  int s0 = blockIdx.x * 64, c0 = blockIdx.y * 64;
  int t = threadIdx.x;
  if (t < 64) { scl[t] = chscale[c0 + t]; sft[t] = chshift[c0 + t]; }
  int crow = t >> 2, sch = (t & 3) * 16;
  #pragma unroll
  for (int j = 0; j < 4; j++) {
    float4 v = *(const float4*)&x[(size_t)(c0 + crow)*4096 + s0 + sch + 4*j];
    ts[crow][sch + 4*j + 0] = v.x; ts[crow][sch + 4*j + 1] = v.y;
    ts[crow][sch + 4*j + 2] = v.z; ts[crow][sch + 4*j + 3] = v.w;
  }
  __syncthreads();
  int srow = t >> 2, cch = (t & 3) * 16;
  #pragma unroll
  for (int p = 0; p < 8; p++) {
    int cl = cch + 2*p;
    float f0 = ts[cl][srow] * scl[cl] + sft[cl];
    float f1 = ts[cl+1][srow] * scl[cl+1] + sft[cl+1];
    *(unsigned*)&gnT[(size_t)(s0 + srow)*320 + c0 + cl] = pack2(f0, f1);
  }
}

// ---------------- LayerNorm bf16->bf16: one wave per row of 320 ----------------
__global__ __launch_bounds__(64) void layernorm_kernel(
    const u16* __restrict__ X, const float* __restrict__ s,
    const float* __restrict__ b, u16* __restrict__ Y) {
  int row = blockIdx.x, t = threadIdx.x;
  const u16* xr = X + (size_t)row*320;
  float v[5], sum = 0.f, sq = 0.f;
  #pragma unroll
  for (int i = 0; i < 5; i++) { v[i] = bfu2f(xr[t + 64*i]); sum += v[i]; sq += v[i]*v[i]; }
  #pragma unroll
  for (int o = 32; o > 0; o >>= 1) { sum += __shfl_down(sum, o); sq += __shfl_down(sq, o); }
  sum = __shfl(sum, 0); sq = __shfl(sq, 0);
  float mu = sum * (1.f/320.f);
  float var = sq * (1.f/320.f) - mu*mu;
  float rs = rsqrtf(var + 1e-5f);
  u16* yr = Y + (size_t)row*320;
  #pragma unroll
  for (int i = 0; i < 5; i++) {
    int c = t + 64*i;
    yr[c] = f2bf((v[i]-mu)*rs*s[c] + b[c]);
  }
}

// ---------------- One-shot GEMM: C[M,320] = A[M,K] * BT[320,K]^T, K in 320-chunks ---------
template<int MODE>
__global__ __launch_bounds__(256) void oneshot(
    const u16* __restrict__ A, const u16* __restrict__ BT,
    const float* __restrict__ bias, const u16* __restrict__ res,
    const float* __restrict__ xres, void* __restrict__ Cout,
    int K, int chunks) {
  __shared__ __align__(16) u16 As[64*328];
  __shared__ __align__(16) u16 Bs[32*328];
  const int t = threadIdx.x;
  const int lane = t & 63, w = t >> 6, l16 = lane & 15, g = lane >> 4;
  const int bm = blockIdx.x * 64, bn = blockIdx.y * 32;
  const int m0 = (w & 1) * 32, n0 = (w >> 1) * 16;
  float4v acc[2] = {};

  const u16* Ab = A + (size_t)(bm + (t>>2))*K + (t&3)*16;
  u16* Al = As + (t>>2)*328 + (t&3)*16;
  const u16* Bb = BT + (size_t)(bn + (t>>3))*K + (t&7)*16;
  u16* Bl = Bs + (t>>3)*328 + (t&7)*16;
  const bool b3 = (t & 7) < 4;

  for (int ch = 0; ch < chunks; ch++) {
    const int c0 = ch*320;
    __syncthreads();
    #pragma unroll
    for (int j = 0; j < 5; j++) {
      *(short8v*)(Al + 64*j)     = *(const short8v*)(Ab + c0 + 64*j);
      *(short8v*)(Al + 64*j + 8) = *(const short8v*)(Ab + c0 + 64*j + 8);
    }
    *(short8v*)Bl         = *(const short8v*)(Bb + c0);
    *(short8v*)(Bl + 8)   = *(const short8v*)(Bb + c0 + 8);
    *(short8v*)(Bl + 128) = *(const short8v*)(Bb + c0 + 128);
    *(short8v*)(Bl + 136) = *(const short8v*)(Bb + c0 + 136);
    if (b3) {
      *(short8v*)(Bl + 256) = *(const short8v*)(Bb + c0 + 256);
      *(short8v*)(Bl + 264) = *(const short8v*)(Bb + c0 + 264);
    }
    __syncthreads();
    #pragma unroll
    for (int ks = 0; ks < 10; ks++) {
      short8v bfv = *(const short8v*)&Bs[(n0 + l16)*328 + ks*32 + g*8];
      #pragma unroll
      for (int mt = 0; mt < 2; mt++) {
        short8v af = *(const short8v*)&As[(m0 + 16*mt + l16)*328 + ks*32 + g*8];
        acc[mt] = __builtin_amdgcn_mfma_f32_16x16x32_bf16(af, bfv, acc[mt], 0, 0, 0);
      }
    }
  }
  __syncthreads();
  float* Cs = (float*)As;   // [64][36]
  #pragma unroll
  for (int mt = 0; mt < 2; mt++)
    #pragma unroll
    for (int r = 0; r < 4; r++)
      Cs[(m0 + 16*mt + 4*g + r)*36 + n0 + l16] = acc[mt][r];
  __syncthreads();

  if (MODE == 0) {
    u16* C = (u16*)Cout;
    #pragma unroll
    for (int i = 0; i < 4; i++) {
      int p = t + i*256;
      int mm = p >> 4, pp = (p & 15)*2;
      float f0 = Cs[mm*36 + pp], f1 = Cs[mm*36 + pp + 1];
      if (bias) { f0 += bias[bn + pp]; f1 += bias[bn + pp + 1]; }
      if (res) {
        unsigned u = *(const unsigned*)&res[(size_t)(bm + mm)*320 + bn + pp];
        f0 += bfu2f((u16)(u & 0xffffu));
        f1 += bfu2f((u16)(u >> 16));
      }
      *(unsigned*)&C[(size_t)(bm + mm)*320 + bn + pp] = pack2(f0, f1);
    }
  } else {
    float* C = (float*)Cout;
    int nloc = t >> 3, mch = (t & 7) * 8;
    float bb = bias[bn + nloc];
    #pragma unroll
    for (int j = 0; j < 2; j++) {
      int m4 = mch + j*4;
      float4 xv = *(const float4*)&xres[(size_t)(bn + nloc)*4096 + bm + m4];
      float4 ov;
      ov.x = Cs[(m4+0)*36 + nloc] + bb + xv.x;
      ov.y = Cs[(m4+1)*36 + nloc] + bb + xv.y;
      ov.z = Cs[(m4+2)*36 + nloc] + bb + xv.z;
      ov.w = Cs[(m4+3)*36 + nloc] + bb + xv.w;
      *(float4*)&C[(size_t)(bn + nloc)*4096 + bm + m4] = ov;
    }
  }
}

// ---------------- MFMA GEMM (looped BK=64, reg-prefetch): QKV (MODE 3), kc/vc (MODE 1) ----
template<int MODE>
__global__ __launch_bounds__(256) void mgemm(
    const u16* __restrict__ A, const u16* __restrict__ BT,
    const float* __restrict__ bias, const u16* __restrict__ res,
    const float* __restrict__ xres, void* __restrict__ Cout,
    int M, int N, int K, int segStride) {
  __shared__ __align__(16) u16 smem[2*64*72];
  u16* As = smem;
  u16* Bs = smem + 64*72;
  const int t = threadIdx.x;
  const int lane = t & 63, w = t >> 6, l16 = lane & 15, g = lane >> 4;
  const int bm = blockIdx.x * 64, bn = blockIdx.y * 64;
  const int m0 = (w & 1) * 32, n0 = (w >> 1) * 32;
  float4v acc[2][2] = {};
  const int ar = t >> 2, ac = (t & 3) * 16;
  const bool aok = (bm + ar) < M;
  const u16* ga = &A[(size_t)(bm + ar)*K + ac];
  const u16* gb = &BT[(size_t)(bn + ar)*K + ac];

  // prefetch chunk 0 into registers
  short8v pa0 = {}, pa1 = {}, pb0, pb1;
  if (aok) { pa0 = *(const short8v*)ga; pa1 = *(const short8v*)(ga + 8); }
  pb0 = *(const short8v*)gb; pb1 = *(const short8v*)(gb + 8);

  for (int k0 = 0; k0 < K; k0 += 64) {
    __syncthreads();
    *(short8v*)&As[ar*72 + ac] = pa0;
    *(short8v*)&As[ar*72 + ac + 8] = pa1;
    *(short8v*)&Bs[ar*72 + ac] = pb0;
    *(short8v*)&Bs[ar*72 + ac + 8] = pb1;
    __syncthreads();
    if (k0 + 64 < K) {   // prefetch next chunk; latency hidden behind MFMAs below
      const u16* na = ga + k0 + 64;
      const u16* nb = gb + k0 + 64;
      if (aok) { pa0 = *(const short8v*)na; pa1 = *(const short8v*)(na + 8); }
      pb0 = *(const short8v*)nb; pb1 = *(const short8v*)(nb + 8);
    }
    #pragma unroll
    for (int ks = 0; ks < 2; ks++) {
      short8v af[2], bfv[2];
      #pragma unroll
      for (int mt = 0; mt < 2; mt++)
        af[mt] = *(const short8v*)&As[(m0 + 16*mt + l16)*72 + ks*32 + g*8];
      #pragma unroll
      for (int nt = 0; nt < 2; nt++)
        bfv[nt] = *(const short8v*)&Bs[(n0 + 16*nt + l16)*72 + ks*32 + g*8];
      #pragma unroll
      for (int mt = 0; mt < 2; mt++)
        #pragma unroll
        for (int nt = 0; nt < 2; nt++)
          acc[mt][nt] = __builtin_amdgcn_mfma_f32_16x16x32_bf16(af[mt], bfv[nt], acc[mt][nt], 0, 0, 0);
    }
  }
  __syncthreads();
  float* Cs = (float*)smem;  // [64][68]
  #pragma unroll
  for (int mt = 0; mt < 2; mt++)
    #pragma unroll
    for (int nt = 0; nt < 2; nt++)
      #pragma unroll
      for (int r = 0; r < 4; r++)
        Cs[(m0 + 16*mt + 4*g + r)*68 + n0 + 16*nt + l16] = acc[mt][nt][r];
  __syncthreads();

  if (MODE == 1) {
    u16* C = (u16*)Cout + (size_t)(bn / 320) * segStride;
    int nb = bn % 320;
    #pragma unroll
    for (int i = 0; i < 8; i++) {
      int p = t + i*256;
      int mm = p >> 5, nn = (p & 31)*2;
      int gm = bm + mm;
      if (gm >= M) continue;
      *(unsigned*)&C[(size_t)gm*320 + nb + nn] = pack2(Cs[mm*68 + nn], Cs[mm*68 + nn + 1]);
    }
  } else if (MODE == 3) {
    if (bn < 640) {
      u16* C = (u16*)Cout + (size_t)(bn / 320) * segStride;
      int nb = bn % 320;
      #pragma unroll
      for (int i = 0; i < 8; i++) {
        int p = t + i*256;
        int mm = p >> 5, nn = (p & 31)*2;
        *(unsigned*)&C[(size_t)(bm + mm)*320 + nb + nn] = pack2(Cs[mm*68 + nn], Cs[mm*68 + nn + 1]);
      }
    } else {
      u16* vTp = (u16*)(void*)xres;
      int nloc = t >> 2, mch = (t & 3) * 16;
      int vd = bn - 640 + nloc;
      u16* dst = vTp + (size_t)vd*4096 + bm + mch;
      unsigned buf[8];
      #pragma unroll
      for (int jj = 0; jj < 8; jj++)
        buf[jj] = pack2(Cs[(mch + 2*jj)*68 + nloc], Cs[(mch + 2*jj + 1)*68 + nloc]);
      uint4 o0; o0.x = buf[0]; o0.y = buf[1]; o0.z = buf[2]; o0.w = buf[3];
      uint4 o1; o1.x = buf[4]; o1.y = buf[5]; o1.z = buf[6]; o1.w = buf[7];
      *(uint4*)dst = o0;
      *(uint4*)(dst + 8) = o1;
    }
  }
}

// ---------------- GEGLU MFMA (reg-prefetch) ----------------
__global__ __launch_bounds__(256) void geglu_mfma(
    const u16* __restrict__ A, const u16* __restrict__ BT,
    const float* __restrict__ bias, u16* __restrict__ C) {
  __shared__ __align__(16) u16 smem[3*64*72];
  u16* As = smem;
  u16* Ba = smem + 64*72;
  u16* Bg = smem + 2*64*72;
  const int t = threadIdx.x;
  const int lane = t & 63, w = t >> 6, l16 = lane & 15, g = lane >> 4;
  const int bm = blockIdx.x * 64, bn = blockIdx.y * 64;
  const int m0 = (w & 1) * 32, n0 = (w >> 1) * 32;
  float4v aacc[2][2] = {}, gacc[2][2] = {};
  const int ar = t >> 2, ac = (t & 3) * 16;
  const u16* ga  = &A[(size_t)(bm + ar)*320 + ac];
  const u16* gba = &BT[(size_t)(bn + ar)*320 + ac];
  const u16* gbg = &BT[(size_t)(1280 + bn + ar)*320 + ac];

  short8v pa0 = *(const short8v*)ga,  pa1 = *(const short8v*)(ga + 8);
  short8v pb0 = *(const short8v*)gba, pb1 = *(const short8v*)(gba + 8);
  short8v pg0 = *(const short8v*)gbg, pg1 = *(const short8v*)(gbg + 8);

  for (int k0 = 0; k0 < 320; k0 += 64) {
    __syncthreads();
    *(short8v*)&As[ar*72 + ac] = pa0;
    *(short8v*)&As[ar*72 + ac + 8] = pa1;
    *(short8v*)&Ba[ar*72 + ac] = pb0;
    *(short8v*)&Ba[ar*72 + ac + 8] = pb1;
    *(short8v*)&Bg[ar*72 + ac] = pg0;
    *(short8v*)&Bg[ar*72 + ac + 8] = pg1;
    __syncthreads();
    if (k0 + 64 < 320) {
      pa0 = *(const short8v*)(ga + k0 + 64);  pa1 = *(const short8v*)(ga + k0 + 72);
      pb0 = *(const short8v*)(gba + k0 + 64); pb1 = *(const short8v*)(gba + k0 + 72);
      pg0 = *(const short8v*)(gbg + k0 + 64); pg1 = *(const short8v*)(gbg + k0 + 72);
    }
    #pragma unroll
    for (int ks = 0; ks < 2; ks++) {
      short8v af[2], bav[2], bgv[2];
      #pragma unroll
      for (int mt = 0; mt < 2; mt++)
        af[mt] = *(const short8v*)&As[(m0 + 16*mt + l16)*72 + ks*32 + g*8];
      #pragma unroll
      for (int nt = 0; nt < 2; nt++) {
        bav[nt] = *(const short8v*)&Ba[(n0 + 16*nt + l16)*72 + ks*32 + g*8];
        bgv[nt] = *(const short8v*)&Bg[(n0 + 16*nt + l16)*72 + ks*32 + g*8];
      }
      #pragma unroll
      for (int mt = 0; mt < 2; mt++)
        #pragma unroll
        for (int nt = 0; nt < 2; nt++) {
          aacc[mt][nt] = __builtin_amdgcn_mfma_f32_16x16x32_bf16(af[mt], bav[nt], aacc[mt][nt], 0, 0, 0);
          gacc[mt][nt] = __builtin_amdgcn_mfma_f32_16x16x32_bf16(af[mt], bgv[nt], gacc[mt][nt], 0, 0, 0);
        }
    }
  }
  __syncthreads();
  float* Cs = (float*)smem;
  #pragma unroll
  for (int nt = 0; nt < 2; nt++) {
    int col = n0 + 16*nt + l16;
    float ba = bias[bn + col];
    float bg2 = bias[1280 + bn + col];
    #pragma unroll
    for (int mt = 0; mt < 2; mt++)
      #pragma unroll
      for (int r = 0; r < 4; r++) {
        float a = aacc[mt][nt][r] + ba;
        float gv = gacc[mt][nt][r] + bg2;
        float gl = 0.5f * gv * (1.f + erff(gv * 0.70710678118654752f));
        Cs[(m0 + 16*mt + 4*g + r)*68 + col] = a * gl;
      }
  }
  __syncthreads();
  #pragma unroll
  for (int i = 0; i < 8; i++) {
    int p = t + i*256;
    int mm = p >> 5, nn = (p & 31)*2;
    *(unsigned*)&C[(size_t)(bm + mm)*1280 + bn + nn] = pack2(Cs[mm*68 + nn], Cs[mm*68 + nn + 1]);
  }
}

// ---------------- Self-attention partial: reg-prefetch pipeline, max-free softmax ---------
// q pre-scaled by SCALE*log2e. Grid (32 qtiles of 128, 8 heads, 4 splits).
__global__ __launch_bounds__(512) void self_attn_part(
    const u16* __restrict__ Q, const u16* __restrict__ K,
    const u16* __restrict__ vT, u16* __restrict__ Opart,
    float* __restrict__ Lp) {
  const int h = blockIdx.y;
  const int q0 = blockIdx.x * 128;
  const int sp = blockIdx.z;
  const int tid = threadIdx.x;
  const int w = tid >> 6, lane = tid & 63;
  const int l16 = lane & 15, g = lane >> 4;

  __shared__ __align__(16) u16 Kls[64][72];
  __shared__ __align__(16) u16 Vt[48][72];
  __shared__ __align__(16) u16 PsT[8][16][72];

  for (int e = tid; e < 64*12; e += 512) {
    int r = e / 12, c = e % 12;
    *(unsigned*)&Kls[r][40 + 2*c] = 0u;
  }
  if (tid < 256) {
    int r = 40 + (tid >> 5), c = tid & 31;
    *(unsigned*)&Vt[r][2*c] = 0u;
  }

  short8v Qb[2];
  {
    const u16* qrow = Q + (size_t)(q0 + w*16 + l16)*320 + h*40;
    Qb[0] = *(const short8v*)(qrow + g*8);
    short8v z = {};
    Qb[1] = (g == 0) ? *(const short8v*)(qrow + 32) : z;
  }

  const u16* Kbase = K + (size_t)(sp*1024)*320 + h*40;
  const u16* Vbase = vT + (size_t)(h*40)*4096 + sp*1024;

  const int ksl = (tid < 320) ? tid : 0;
  const int keyK = ksl / 5, chK = ksl - keyK*5;
  const u16* gK = Kbase + (size_t)keyK*320 + chK*8;
  u16* lK = &Kls[keyK][chK*8];
  const int vsl = (tid >= 192) ? (tid - 192) : 0;
  const int dV = vsl >> 3, chV = vsl & 7;
  const u16* gV = Vbase + (size_t)dV*4096 + chV*8;
  u16* lV = &Vt[dV][chV*8];

  const bool doK = (tid < 320), doV = (tid >= 192);

  // prefetch tile 0 into registers
  short8v rK = {}, rV = {};
  if (doK) rK = *(const short8v*)gK;
  if (doV) rV = *(const short8v*)gV;
  gK += 64*320; gV += 64;

  float l_i = 0.f;
  float4v Of[3] = {};

  for (int it = 0; it < 16; ++it) {
    __syncthreads();           // prior tile's LDS reads complete
    if (doK) *(short8v*)lK = rK;
    if (doV) *(short8v*)lV = rV;
    __syncthreads();           // staged tiles visible
    if (it < 15) {             // prefetch next tile; latency hidden behind compute below
      if (doK) rK = *(const short8v*)gK;
      if (doV) rV = *(const short8v*)gV;
      gK += 64*320; gV += 64;
    }

    // S^T = K·Q^T (scores in exp2 units; bounded — no running max needed)
    float4v Sf[4];
    #pragma unroll
    for (int mt = 0; mt < 4; mt++) {
      short8v ka0 = *(const short8v*)&Kls[mt*16 + l16][g*8];
      short8v ka1 = *(const short8v*)&Kls[mt*16 + l16][32 + g*8];
      float4v s = {};
      s = __builtin_amdgcn_mfma_f32_16x16x32_bf16(ka0, Qb[0], s, 0, 0, 0);
      s = __builtin_amdgcn_mfma_f32_16x16x32_bf16(ka1, Qb[1], s, 0, 0, 0);
      Sf[mt] = s;
    }

    float rsum = 0.f;
    #pragma unroll
    for (int mt = 0; mt < 4; mt++)
      #pragma unroll
      for (int r = 0; r < 4; r++) {
        float p = exp2f(Sf[mt][r]);
        Sf[mt][r] = p; rsum += p;
      }
    rsum += __shfl_xor(rsum, 16);
    rsum += __shfl_xor(rsum, 32);
    l_i += rsum;

    #pragma unroll
    for (int mt = 0; mt < 4; mt++) {
      uint2 pk;
      pk.x = pack2(Sf[mt][0], Sf[mt][1]);
      pk.y = pack2(Sf[mt][2], Sf[mt][3]);
      *(uint2*)&PsT[w][l16][mt*16 + 4*g] = pk;
    }
    asm volatile("s_waitcnt lgkmcnt(0)" ::: "memory");

    #pragma unroll
    for (int ks = 0; ks < 2; ks++) {
      short8v pb = *(const short8v*)&PsT[w][l16][ks*32 + g*8];
      #pragma unroll
      for (int mt = 0; mt < 3; mt++) {
        short8v va = *(const short8v*)&Vt[mt*16 + l16][ks*32 + g*8];
        Of[mt] = __builtin_amdgcn_mfma_f32_16x16x32_bf16(va, pb, Of[mt], 0, 0, 0);
      }
    }
  }

  // store unnormalized partial O^T (bf16) + l
  const int q = q0 + w*16 + l16;
  u16* orow = Opart + (size_t)sp*4096*320 + (size_t)q*320 + h*40;
  #pragma unroll
  for (int mt = 0; mt < 3; mt++) {
    #pragma unroll
    for (int rp = 0; rp < 2; rp++) {
      int d = mt*16 + 4*g + rp*2;
      if (d < 40)
        *(unsigned*)&orow[d] = pack2(Of[mt][rp*2], Of[mt][rp*2+1]);
    }
  }
  if (g == 0)
    Lp[sp*32768 + q*8 + h] = l_i;
}

// ---------------- merge 4 partials (weights all 1) -> ao bf16 ----------------
__global__ __launch_bounds__(256) void attn_merge(
    const u16* __restrict__ Opart, const float* __restrict__ Lp,
    u16* __restrict__ O) {
  int gid = blockIdx.x*256 + threadIdx.x;   // < 4096*8*20
  int dp = gid % 20;
  int qh = gid / 20;
  int q = qh >> 3, h = qh & 7;
  float ls = Lp[qh] + Lp[32768 + qh] + Lp[2*32768 + qh] + Lp[3*32768 + qh];
  size_t base = (size_t)q*320 + h*40 + dp*2;
  const size_t HBu = 4096u*320u;
  float r0 = 0.f, r1 = 0.f;
  #pragma unroll
  for (int sp = 0; sp < 4; sp++) {
    unsigned u = *(const unsigned*)&Opart[sp*HBu + base];
    r0 += bfu2f((u16)(u & 0xffffu));
    r1 += bfu2f((u16)(u >> 16));
  }
  float inv = 1.f / ls;
  *(unsigned*)&O[base] = pack2(r0*inv, r1*inv);
}

// ---------------- Cross-attention: single-shot MFMA, 77 keys, max-free ----------------
__global__ __launch_bounds__(256) void cross_attn_mfma(
    const u16* __restrict__ Q, const u16* __restrict__ Kc,
    const u16* __restrict__ Vc, u16* __restrict__ O) {
  const int h = blockIdx.y;
  const int q0 = blockIdx.x * 64;
  const int tid = threadIdx.x;
  const int w = tid >> 6, lane = tid & 63;
  const int l16 = lane & 15, g = lane >> 4;

  __shared__ __align__(16) u16 Kls[80][72];
  __shared__ __align__(16) u16 Vt[48][104];
  __shared__ __align__(16) u16 PsT[4][16][104];

  for (int e = tid; e < 80*12; e += 256) {
    int r = e / 12, c = e % 12;
    *(unsigned*)&Kls[r][40 + 2*c] = 0u;
  }
  for (int e = tid; e < 48*52; e += 256) {
    int r = e / 52, c = e % 52;
    *(unsigned*)&Vt[r][2*c] = 0u;
  }
  {
    int r = lane >> 2, c4 = (lane & 3)*4;
    uint2 z; z.x = 0u; z.y = 0u;
    *(uint2*)&PsT[w][r][80 + c4] = z;
  }

  short8v Qb[2];
  {
    const u16* qrow = Q + (size_t)(q0 + w*16 + l16)*320 + h*40;
    Qb[0] = *(const short8v*)(qrow + g*8);
    short8v z = {};
    Qb[1] = (g == 0) ? *(const short8v*)(qrow + 32) : z;
  }

  for (int e = tid; e < 1600; e += 256) {
    int key = e / 20, dp = e % 20;
    unsigned val = 0u;
    if (key < 77) val = *(const unsigned*)&Kc[(size_t)key*320 + h*40 + dp*2];
    *(unsigned*)&Kls[key][dp*2] = val;
  }
  __syncthreads();
  for (int e = tid; e < 1600; e += 256) {
    int kp = e / 40, d = e % 40;
    unsigned u0 = (kp*2     < 77) ? (unsigned)Vc[(size_t)(kp*2    )*320 + h*40 + d] : 0u;
    unsigned u1 = (kp*2 + 1 < 77) ? (unsigned)Vc[(size_t)(kp*2 + 1)*320 + h*40 + d] : 0u;
    *(unsigned*)&Vt[d][kp*2] = u0 | (u1 << 16);
  }
  __syncthreads();

  float4v Sf[5];
  #pragma unroll
  for (int mt = 0; mt < 5; mt++) {
    short8v ka0 = *(const short8v*)&Kls[mt*16 + l16][g*8];
    short8v ka1 = *(const short8v*)&Kls[mt*16 + l16][32 + g*8];
    float4v s = {};
    s = __builtin_amdgcn_mfma_f32_16x16x32_bf16(ka0, Qb[0], s, 0, 0, 0);
    s = __builtin_amdgcn_mfma_f32_16x16x32_bf16(ka1, Qb[1], s, 0, 0, 0);
    Sf[mt] = s;
  }

  float rsum = 0.f;
  #pragma unroll
  for (int mt = 0; mt < 5; mt++)
    #pragma unroll
    for (int r = 0; r < 4; r++) {
      int key = mt*16 + 4*g + r;
      float p = (key < 77) ? exp2f(Sf[mt][r]) : 0.f;
      Sf[mt][r] = p; rsum += p;
    }
  rsum += __shfl_xor(rsum, 16);
  rsum += __shfl_xor(rsum, 32);

  #pragma unroll
  for (int mt = 0; mt < 5; mt++) {
    uint2 pk;
    pk.x = pack2(Sf[mt][0], Sf[mt][1]);
    pk.y = pack2(Sf[mt][2], Sf[mt][3]);
    *(uint2*)&PsT[w][l16][mt*16 + 4*g] = pk;
  }
  __syncthreads();

  float4v Of[3] = {};
  #pragma unroll
  for (int ks = 0; ks < 3; ks++) {
    short8v pb = *(const short8v*)&PsT[w][l16][ks*32 + g*8];
    #pragma unroll
    for (int mt = 0; mt < 3; mt++) {
      short8v va = *(const short8v*)&Vt[mt*16 + l16][ks*32 + g*8];
      Of[mt] = __builtin_amdgcn_mfma_f32_16x16x32_bf16(va, pb, Of[mt], 0, 0, 0);
    }
  }

  float inv = 1.f / rsum;
  u16* orow = O + (size_t)(q0 + w*16 + l16)*320 + h*40;
  #pragma unroll
  for (int mt = 0; mt < 3; mt++) {
    #pragma unroll
    for (int rp = 0; rp < 2; rp++) {
      int d = mt*16 + 4*g + rp*2;
      if (d < 40)
        *(unsigned*)&orow[d] = pack2(Of[mt][rp*2] * inv, Of[mt][rp*2+1] * inv);
    }
  }
}

extern "C" void kernel_launch(void* const* d_in, const int* in_sizes, int n_in,
                              void* d_out, int out_size, void* d_ws, size_t ws_size,
                              hipStream_t stream) {
  const float* x        = (const float*)d_in[0];
  const float* ctx      = (const float*)d_in[1];
  const float* gn_s     = (const float*)d_in[2];
  const float* gn_b     = (const float*)d_in[3];
  const float* w_pin    = (const float*)d_in[4];
  const float* b_pin    = (const float*)d_in[5];
  const float* ln1_s    = (const float*)d_in[6];
  const float* ln1_b    = (const float*)d_in[7];
  const float* wq1      = (const float*)d_in[8];
  const float* wk1      = (const float*)d_in[9];
  const float* wv1      = (const float*)d_in[10];
  const float* wo1      = (const float*)d_in[11];
  const float* bo1      = (const float*)d_in[12];
  const float* ln2_s    = (const float*)d_in[13];
  const float* ln2_b    = (const float*)d_in[14];
  const float* wq2      = (const float*)d_in[15];
  const float* wk2      = (const float*)d_in[16];
  const float* wv2      = (const float*)d_in[17];
  const float* wo2      = (const float*)d_in[18];
  const float* bo2      = (const float*)d_in[19];
  const float* ln3_s    = (const float*)d_in[20];
  const float* ln3_b    = (const float*)d_in[21];
  const float* w_ff1    = (const float*)d_in[22];
  const float* b_ff1    = (const float*)d_in[23];
  const float* w_ff2    = (const float*)d_in[24];
  const float* b_ff2    = (const float*)d_in[25];
  const float* w_pout   = (const float*)d_in[26];
  const float* b_pout   = (const float*)d_in[27];
  float* out = (float*)d_out;

  u16* ws = (u16*)d_ws;
  const size_t HB = 4096u*320u;
  u16* h   = ws;
  u16* hn  = ws + HB;
  u16* q   = ws + 2*HB;    // q,k contiguous (QKV fused epilogue)
  u16* k   = ws + 3*HB;
  u16* vT  = ws + 4*HB;    // V^T [320][4096]
  u16* ao  = ws + 5*HB;
  u16* gnT = k;
  u16* gg  = q;            // GEGLU out overlays q,k,vT,ao
  u16* wb  = ws + 6*HB;
  size_t o = 0;
  u16* ctxb   = wb + o; o += 59136;
  u16* wq1T   = wb + o; o += 102400;   // stacked: wq1T,wk1T,wv1T = [960][320]
  u16* wk1T   = wb + o; o += 102400;
  u16* wv1T   = wb + o; o += 102400;
  u16* wo1T   = wb + o; o += 102400;
  u16* wq2T   = wb + o; o += 102400;
  u16* wk2T   = wb + o; o += 245760;   // stacked: wk2T,wv2T = [640][768]
  u16* wv2T   = wb + o; o += 245760;
  u16* wo2T   = wb + o; o += 102400;
  u16* wff1T  = wb + o; o += 819200;
  u16* wff2T  = wb + o; o += 409600;
  u16* wpoutT = wb + o; o += 102400;
  u16* wpinT  = wb + o; o += 102400;
  u16* kc     = wb + o; o += 24640;    // kc,vc contiguous, segStride 24640
  u16* vc     = wb + o; o += 24640;
  float* chscale = (float*)(wb + o);
  float* chshift = chscale + 320;
  u16* OpartB = (u16*)(chshift + 320);           // 4 x HB bf16 = 10.5 MB
  float* Lpart = (float*)(OpartB + 4*HB);        // 4 x 32768 fp32

  TPack tp;
  const float* srcs[12] = {wq1, wk1, wv1, wo1, wq2, wo2, w_pin, w_pout, wk2, wv2, w_ff1, w_ff2};
  u16* dsts[12]         = {wq1T, wk1T, wv1T, wo1T, wq2T, wo2T, wpinT, wpoutT, wk2T, wv2T, wff1T, wff2T};
  int Ks[12] = {320,320,320,320,320,320,320,320,768,768,320,1280};
  int Ns[12] = {320,320,320,320,320,320,320,320,320,320,2560,320};
  int off = 0;
  for (int i = 0; i < 12; i++) {
    tp.d[i].src = srcs[i]; tp.d[i].dst = dsts[i];
    tp.d[i].K = Ks[i]; tp.d[i].N = Ns[i];
    tp.d[i].off = off; tp.d[i].tx = Ns[i]/32;
    tp.d[i].sc = (i == 0 || i == 4) ? SCALE_L2E : 1.0f;   // wq1, wq2 pre-scaled
    off += (Ks[i]/32)*(Ns[i]/32);
  }

  dim3 blk(256), g64x10(64, 10), g64x5(64, 5);
  const u16* nres = nullptr;
  const float* nb = nullptr;

  hipLaunchKernelGGL(prep_kernel, dim3(off + 58 + 32), blk, 0, stream,
                     tp, off, ctx, ctxb, x, gn_s, gn_b, chscale, chshift);
  hipLaunchKernelGGL(gn_apply_t_kernel, g64x5, blk, 0, stream, x, chscale, chshift, gnT);
  hipLaunchKernelGGL((oneshot<0>), g64x10, blk, 0, stream, gnT, wpinT, b_pin, nres, nb, (void*)h, 320, 1);
  hipLaunchKernelGGL(layernorm_kernel, dim3(4096), dim3(64), 0, stream, h, ln1_s, ln1_b, hn);
  // fused QKV: N=960; segs 0,1 -> q,k; seg 2 -> vT (transposed)
  hipLaunchKernelGGL((mgemm<3>), dim3(64, 15), blk, 0, stream, hn, wq1T, nb, nres, (const float*)vT, (void*)q, 4096, 960, 320, (int)HB);
  hipLaunchKernelGGL(self_attn_part, dim3(32, 8, 4), dim3(512), 0, stream, q, k, vT, OpartB, Lpart);
  hipLaunchKernelGGL(attn_merge, dim3(2560), blk, 0, stream, OpartB, Lpart, ao);
  hipLaunchKernelGGL((oneshot<0>), g64x10, blk, 0, stream, ao, wo1T, bo1, h, nb, (void*)h, 320, 1);
  hipLaunchKernelGGL(layernorm_kernel, dim3(4096), dim3(64), 0, stream, h, ln2_s, ln2_b, hn);
  hipLaunchKernelGGL((oneshot<0>), g64x10, blk, 0, stream, hn, wq2T, nb, nres, nb, (void*)q, 320, 1);
  hipLaunchKernelGGL((mgemm<1>), dim3(2, 10), blk, 0, stream, ctxb, wk2T, nb, nres, nb, (void*)kc, 77, 640, 768, 24640);
  hipLaunchKernelGGL(cross_attn_mfma, dim3(64, 8), blk, 0, stream, q, kc, vc, ao);
  hipLaunchKernelGGL((oneshot<0>), g64x10, blk, 0, stream, ao, wo2T, bo2, h, nb, (void*)h, 320, 1);
  hipLaunchKernelGGL(layernorm_kernel, dim3(4096), dim3(64), 0, stream, h, ln3_s, ln3_b, hn);
  hipLaunchKernelGGL(geglu_mfma, dim3(64, 20), blk, 0, stream, hn, wff1T, b_ff1, gg);
  hipLaunchKernelGGL((oneshot<0>), g64x10, blk, 0, stream, gg, wff2T, b_ff2, h, nb, (void*)h, 1280, 4);
  hipLaunchKernelGGL((oneshot<2>), g64x10, blk, 0, stream, h, wpoutT, b_pout, nres, x, (void*)out, 320, 1);
}

// Round 12
// 292.881 us; speedup vs baseline: 1.6426x; 1.1438x over previous
//
#include <hip/hip_runtime.h>
#include <hip/hip_bf16.h>
#include <math.h>

#define SCALE_L2E  0.22811011265722836f   // (1/sqrt(40)) * log2(e)

typedef __attribute__((ext_vector_type(8))) short short8v;
typedef __attribute__((ext_vector_type(4))) float float4v;
typedef unsigned short u16;

__device__ __forceinline__ unsigned pack2(float a, float b) {
  float2 f; f.x = a; f.y = b;
  __hip_bfloat162 h = __float22bfloat162_rn(f);
  return *(unsigned*)&h;
}
__device__ __forceinline__ float bfu2f(u16 u) {
  return __uint_as_float(((unsigned)u) << 16);
}
__device__ __forceinline__ u16 f2bf(float x) {
  __hip_bfloat16 h = __float2bfloat16(x);
  return *(u16*)&h;
}

// ---------------- prep: weight transpose+convert | ctx cvt | gn PARTIAL stats --------------
struct TDesc { const float* src; u16* dst; int K, N, off, tx; float sc; };
struct TPack { TDesc d[12]; };

__global__ __launch_bounds__(256) void prep_kernel(
    TPack p, int nT,
    const float* __restrict__ ctxsrc, u16* __restrict__ ctxdst,
    const float* __restrict__ x,
    float* __restrict__ psum, float* __restrict__ psq) {
  __shared__ float ls[32][33];
  int bt = blockIdx.x, t = threadIdx.x;
  if (bt < nT) {
    int ti = 0;
    #pragma unroll
    for (int i = 1; i < 12; i++) if (bt >= p.d[i].off) ti = i;
    TDesc dd = p.d[ti];
    int local = bt - dd.off;
    int n0 = (local % dd.tx) * 32, k0 = (local / dd.tx) * 32;
    #pragma unroll
    for (int i = 0; i < 4; i++) {
      int idx = t + i*256, r = idx >> 5, c = idx & 31;
      ls[r][c] = dd.src[(size_t)(k0 + r)*dd.N + n0 + c];
    }
    __syncthreads();
    #pragma unroll
    for (int i = 0; i < 2; i++) {
      int p2 = t + i*256, n = p2 >> 4, kp = (p2 & 15)*2;
      *(unsigned*)&dd.dst[(size_t)(n0 + n)*dd.K + k0 + kp] =
        pack2(ls[kp][n]*dd.sc, ls[kp+1][n]*dd.sc);
    }
  } else if (bt < nT + 58) {
    int idx = ((bt - nT)*256 + t)*4;
    if (idx < 59136) {
      float4 v = *(const float4*)&ctxsrc[idx];
      uint2 o; o.x = pack2(v.x, v.y); o.y = pack2(v.z, v.w);
      *(uint2*)&ctxdst[idx] = o;
    }
  } else {
    // gn partial stats: 256 blocks, 8 per group, 5120 floats each (float4 loads)
    int pp = bt - nT - 58;            // 0..255
    int g = pp >> 3, part = pp & 7;
    size_t base = (size_t)g*40960 + (size_t)part*5120;
    float sum = 0.f, sq = 0.f;
    #pragma unroll
    for (int r = 0; r < 5; r++) {
      float4 v = *(const float4*)&x[base + (size_t)(t + r*256)*4];
      sum += v.x + v.y + v.z + v.w;
      sq  += v.x*v.x + v.y*v.y + v.z*v.z + v.w*v.w;
    }
    float* s1 = &ls[0][0];
    float* s2 = &ls[8][0] + 8;
    s1[t] = sum; s2[t] = sq; __syncthreads();
    for (int st = 128; st > 0; st >>= 1) {
      if (t < st) { s1[t] += s1[t+st]; s2[t] += s2[t+st]; }
      __syncthreads();
    }
    if (t == 0) { psum[pp] = s1[0]; psq[pp] = s2[0]; }
  }
}

// ---------------- GN apply + transpose (folds final stats reduce): x fp32 -> gnT bf16 ------
__global__ __launch_bounds__(256) void gn_apply_t_kernel(
    const float* __restrict__ x, const float* __restrict__ psum,
    const float* __restrict__ psq, const float* __restrict__ gs,
    const float* __restrict__ gb, u16* __restrict__ gnT) {
  __shared__ float ts[64][65];
  __shared__ float scl[64], sft[64];
  int s0 = blockIdx.x * 64, c0 = blockIdx.y * 64;
  int t = threadIdx.x;
  if (t < 64) {
    int c = c0 + t, g = c / 10;
    float s = 0.f, q = 0.f;
    #pragma unroll
    for (int i = 0; i < 8; i++) { s += psum[g*8 + i]; q += psq[g*8 + i]; }
    float mu = s * (1.f/40960.f);
    float var = q * (1.f/40960.f) - mu*mu;
    float rs = rsqrtf(var + 1e-6f);
    float sc = rs * gs[c];
    scl[t] = sc;
    sft[t] = gb[c] - mu * sc;
  }
  int crow = t >> 2, sch = (t & 3) * 16;
  #pragma unroll
  for (int j = 0; j < 4; j++) {
    float4 v = *(const float4*)&x[(size_t)(c0 + crow)*4096 + s0 + sch + 4*j];
    ts[crow][sch + 4*j + 0] = v.x; ts[crow][sch + 4*j + 1] = v.y;
    ts[crow][sch + 4*j + 2] = v.z; ts[crow][sch + 4*j + 3] = v.w;
  }
  __syncthreads();
  int srow = t >> 2, cch = (t & 3) * 16;
  #pragma unroll
  for (int p = 0; p < 8; p++) {
    int cl = cch + 2*p;
    float f0 = ts[cl][srow] * scl[cl] + sft[cl];
    float f1 = ts[cl+1][srow] * scl[cl+1] + sft[cl+1];
    *(unsigned*)&gnT[(size_t)(s0 + srow)*320 + c0 + cl] = pack2(f0, f1);
  }
}

// ---------------- LayerNorm bf16->bf16: one wave per row of 320 ----------------
__global__ __launch_bounds__(64) void layernorm_kernel(
    const u16* __restrict__ X, const float* __restrict__ s,
    const float* __restrict__ b, u16* __restrict__ Y) {
  int row = blockIdx.x, t = threadIdx.x;
  const u16* xr = X + (size_t)row*320;
  float v[5], sum = 0.f, sq = 0.f;
  #pragma unroll
  for (int i = 0; i < 5; i++) { v[i] = bfu2f(xr[t + 64*i]); sum += v[i]; sq += v[i]*v[i]; }
  #pragma unroll
  for (int o = 32; o > 0; o >>= 1) { sum += __shfl_down(sum, o); sq += __shfl_down(sq, o); }
  sum = __shfl(sum, 0); sq = __shfl(sq, 0);
  float mu = sum * (1.f/320.f);
  float var = sq * (1.f/320.f) - mu*mu;
  float rs = rsqrtf(var + 1e-5f);
  u16* yr = Y + (size_t)row*320;
  #pragma unroll
  for (int i = 0; i < 5; i++) {
    int c = t + 64*i;
    yr[c] = f2bf((v[i]-mu)*rs*s[c] + b[c]);
  }
}

// ---------------- One-shot GEMM: C[M,320] = A[M,K] * BT[320,K]^T, K in 320-chunks ---------
template<int MODE>
__global__ __launch_bounds__(256) void oneshot(
    const u16* __restrict__ A, const u16* __restrict__ BT,
    const float* __restrict__ bias, const u16* __restrict__ res,
    const float* __restrict__ xres, void* __restrict__ Cout,
    int K, int chunks) {
  __shared__ __align__(16) u16 As[64*328];
  __shared__ __align__(16) u16 Bs[32*328];
  const int t = threadIdx.x;
  const int lane = t & 63, w = t >> 6, l16 = lane & 15, g = lane >> 4;
  const int bm = blockIdx.x * 64, bn = blockIdx.y * 32;
  const int m0 = (w & 1) * 32, n0 = (w >> 1) * 16;
  float4v acc[2] = {};

  const u16* Ab = A + (size_t)(bm + (t>>2))*K + (t&3)*16;
  u16* Al = As + (t>>2)*328 + (t&3)*16;
  const u16* Bb = BT + (size_t)(bn + (t>>3))*K + (t&7)*16;
  u16* Bl = Bs + (t>>3)*328 + (t&7)*16;
  const bool b3 = (t & 7) < 4;

  for (int ch = 0; ch < chunks; ch++) {
    const int c0 = ch*320;
    __syncthreads();
    #pragma unroll
    for (int j = 0; j < 5; j++) {
      *(short8v*)(Al + 64*j)     = *(const short8v*)(Ab + c0 + 64*j);
      *(short8v*)(Al + 64*j + 8) = *(const short8v*)(Ab + c0 + 64*j + 8);
    }
    *(short8v*)Bl         = *(const short8v*)(Bb + c0);
    *(short8v*)(Bl + 8)   = *(const short8v*)(Bb + c0 + 8);
    *(short8v*)(Bl + 128) = *(const short8v*)(Bb + c0 + 128);
    *(short8v*)(Bl + 136) = *(const short8v*)(Bb + c0 + 136);
    if (b3) {
      *(short8v*)(Bl + 256) = *(const short8v*)(Bb + c0 + 256);
      *(short8v*)(Bl + 264) = *(const short8v*)(Bb + c0 + 264);
    }
    __syncthreads();
    #pragma unroll
    for (int ks = 0; ks < 10; ks++) {
      short8v bfv = *(const short8v*)&Bs[(n0 + l16)*328 + ks*32 + g*8];
      #pragma unroll
      for (int mt = 0; mt < 2; mt++) {
        short8v af = *(const short8v*)&As[(m0 + 16*mt + l16)*328 + ks*32 + g*8];
        acc[mt] = __builtin_amdgcn_mfma_f32_16x16x32_bf16(af, bfv, acc[mt], 0, 0, 0);
      }
    }
  }
  __syncthreads();
  float* Cs = (float*)As;   // [64][36]
  #pragma unroll
  for (int mt = 0; mt < 2; mt++)
    #pragma unroll
    for (int r = 0; r < 4; r++)
      Cs[(m0 + 16*mt + 4*g + r)*36 + n0 + l16] = acc[mt][r];
  __syncthreads();

  if (MODE == 0) {
    u16* C = (u16*)Cout;
    #pragma unroll
    for (int i = 0; i < 4; i++) {
      int p = t + i*256;
      int mm = p >> 4, pp = (p & 15)*2;
      float f0 = Cs[mm*36 + pp], f1 = Cs[mm*36 + pp + 1];
      if (bias) { f0 += bias[bn + pp]; f1 += bias[bn + pp + 1]; }
      if (res) {
        unsigned u = *(const unsigned*)&res[(size_t)(bm + mm)*320 + bn + pp];
        f0 += bfu2f((u16)(u & 0xffffu));
        f1 += bfu2f((u16)(u >> 16));
      }
      *(unsigned*)&C[(size_t)(bm + mm)*320 + bn + pp] = pack2(f0, f1);
    }
  } else {
    float* C = (float*)Cout;
    int nloc = t >> 3, mch = (t & 7) * 8;
    float bb = bias[bn + nloc];
    #pragma unroll
    for (int j = 0; j < 2; j++) {
      int m4 = mch + j*4;
      float4 xv = *(const float4*)&xres[(size_t)(bn + nloc)*4096 + bm + m4];
      float4 ov;
      ov.x = Cs[(m4+0)*36 + nloc] + bb + xv.x;
      ov.y = Cs[(m4+1)*36 + nloc] + bb + xv.y;
      ov.z = Cs[(m4+2)*36 + nloc] + bb + xv.z;
      ov.w = Cs[(m4+3)*36 + nloc] + bb + xv.w;
      *(float4*)&C[(size_t)(bn + nloc)*4096 + bm + m4] = ov;
    }
  }
}

// ---------------- MFMA GEMM (looped BK=64, reg-prefetch): QKV (MODE 3), kc/vc (MODE 1) ----
template<int MODE>
__global__ __launch_bounds__(256) void mgemm(
    const u16* __restrict__ A, const u16* __restrict__ BT,
    const float* __restrict__ bias, const u16* __restrict__ res,
    const float* __restrict__ xres, void* __restrict__ Cout,
    int M, int N, int K, int segStride) {
  __shared__ __align__(16) u16 smem[2*64*72];
  u16* As = smem;
  u16* Bs = smem + 64*72;
  const int t = threadIdx.x;
  const int lane = t & 63, w = t >> 6, l16 = lane & 15, g = lane >> 4;
  const int bm = blockIdx.x * 64, bn = blockIdx.y * 64;
  const int m0 = (w & 1) * 32, n0 = (w >> 1) * 32;
  float4v acc[2][2] = {};
  const int ar = t >> 2, ac = (t & 3) * 16;
  const bool aok = (bm + ar) < M;
  const u16* ga = &A[(size_t)(bm + ar)*K + ac];
  const u16* gb = &BT[(size_t)(bn + ar)*K + ac];

  short8v pa0 = {}, pa1 = {}, pb0, pb1;
  if (aok) { pa0 = *(const short8v*)ga; pa1 = *(const short8v*)(ga + 8); }
  pb0 = *(const short8v*)gb; pb1 = *(const short8v*)(gb + 8);

  for (int k0 = 0; k0 < K; k0 += 64) {
    __syncthreads();
    *(short8v*)&As[ar*72 + ac] = pa0;
    *(short8v*)&As[ar*72 + ac + 8] = pa1;
    *(short8v*)&Bs[ar*72 + ac] = pb0;
    *(short8v*)&Bs[ar*72 + ac + 8] = pb1;
    __syncthreads();
    if (k0 + 64 < K) {
      const u16* na = ga + k0 + 64;
      const u16* nb = gb + k0 + 64;
      if (aok) { pa0 = *(const short8v*)na; pa1 = *(const short8v*)(na + 8); }
      pb0 = *(const short8v*)nb; pb1 = *(const short8v*)(nb + 8);
    }
    #pragma unroll
    for (int ks = 0; ks < 2; ks++) {
      short8v af[2], bfv[2];
      #pragma unroll
      for (int mt = 0; mt < 2; mt++)
        af[mt] = *(const short8v*)&As[(m0 + 16*mt + l16)*72 + ks*32 + g*8];
      #pragma unroll
      for (int nt = 0; nt < 2; nt++)
        bfv[nt] = *(const short8v*)&Bs[(n0 + 16*nt + l16)*72 + ks*32 + g*8];
      #pragma unroll
      for (int mt = 0; mt < 2; mt++)
        #pragma unroll
        for (int nt = 0; nt < 2; nt++)
          acc[mt][nt] = __builtin_amdgcn_mfma_f32_16x16x32_bf16(af[mt], bfv[nt], acc[mt][nt], 0, 0, 0);
    }
  }
  __syncthreads();
  float* Cs = (float*)smem;  // [64][68]
  #pragma unroll
  for (int mt = 0; mt < 2; mt++)
    #pragma unroll
    for (int nt = 0; nt < 2; nt++)
      #pragma unroll
      for (int r = 0; r < 4; r++)
        Cs[(m0 + 16*mt + 4*g + r)*68 + n0 + 16*nt + l16] = acc[mt][nt][r];
  __syncthreads();

  if (MODE == 1) {
    u16* C = (u16*)Cout + (size_t)(bn / 320) * segStride;
    int nb = bn % 320;
    #pragma unroll
    for (int i = 0; i < 8; i++) {
      int p = t + i*256;
      int mm = p >> 5, nn = (p & 31)*2;
      int gm = bm + mm;
      if (gm >= M) continue;
      *(unsigned*)&C[(size_t)gm*320 + nb + nn] = pack2(Cs[mm*68 + nn], Cs[mm*68 + nn + 1]);
    }
  } else if (MODE == 3) {
    if (bn < 640) {
      u16* C = (u16*)Cout + (size_t)(bn / 320) * segStride;
      int nb = bn % 320;
      #pragma unroll
      for (int i = 0; i < 8; i++) {
        int p = t + i*256;
        int mm = p >> 5, nn = (p & 31)*2;
        *(unsigned*)&C[(size_t)(bm + mm)*320 + nb + nn] = pack2(Cs[mm*68 + nn], Cs[mm*68 + nn + 1]);
      }
    } else {
      u16* vTp = (u16*)(void*)xres;
      int nloc = t >> 2, mch = (t & 3) * 16;
      int vd = bn - 640 + nloc;
      u16* dst = vTp + (size_t)vd*4096 + bm + mch;
      unsigned buf[8];
      #pragma unroll
      for (int jj = 0; jj < 8; jj++)
        buf[jj] = pack2(Cs[(mch + 2*jj)*68 + nloc], Cs[(mch + 2*jj + 1)*68 + nloc]);
      uint4 o0; o0.x = buf[0]; o0.y = buf[1]; o0.z = buf[2]; o0.w = buf[3];
      uint4 o1; o1.x = buf[4]; o1.y = buf[5]; o1.z = buf[6]; o1.w = buf[7];
      *(uint4*)dst = o0;
      *(uint4*)(dst + 8) = o1;
    }
  }
}

// ---------------- GEGLU MFMA (reg-prefetch) ----------------
__global__ __launch_bounds__(256) void geglu_mfma(
    const u16* __restrict__ A, const u16* __restrict__ BT,
    const float* __restrict__ bias, u16* __restrict__ C) {
  __shared__ __align__(16) u16 smem[3*64*72];
  u16* As = smem;
  u16* Ba = smem + 64*72;
  u16* Bg = smem + 2*64*72;
  const int t = threadIdx.x;
  const int lane = t & 63, w = t >> 6, l16 = lane & 15, g = lane >> 4;
  const int bm = blockIdx.x * 64, bn = blockIdx.y * 64;
  const int m0 = (w & 1) * 32, n0 = (w >> 1) * 32;
  float4v aacc[2][2] = {}, gacc[2][2] = {};
  const int ar = t >> 2, ac = (t & 3) * 16;
  const u16* ga  = &A[(size_t)(bm + ar)*320 + ac];
  const u16* gba = &BT[(size_t)(bn + ar)*320 + ac];
  const u16* gbg = &BT[(size_t)(1280 + bn + ar)*320 + ac];

  short8v pa0 = *(const short8v*)ga,  pa1 = *(const short8v*)(ga + 8);
  short8v pb0 = *(const short8v*)gba, pb1 = *(const short8v*)(gba + 8);
  short8v pg0 = *(const short8v*)gbg, pg1 = *(const short8v*)(gbg + 8);

  for (int k0 = 0; k0 < 320; k0 += 64) {
    __syncthreads();
    *(short8v*)&As[ar*72 + ac] = pa0;
    *(short8v*)&As[ar*72 + ac + 8] = pa1;
    *(short8v*)&Ba[ar*72 + ac] = pb0;
    *(short8v*)&Ba[ar*72 + ac + 8] = pb1;
    *(short8v*)&Bg[ar*72 + ac] = pg0;
    *(short8v*)&Bg[ar*72 + ac + 8] = pg1;
    __syncthreads();
    if (k0 + 64 < 320) {
      pa0 = *(const short8v*)(ga + k0 + 64);  pa1 = *(const short8v*)(ga + k0 + 72);
      pb0 = *(const short8v*)(gba + k0 + 64); pb1 = *(const short8v*)(gba + k0 + 72);
      pg0 = *(const short8v*)(gbg + k0 + 64); pg1 = *(const short8v*)(gbg + k0 + 72);
    }
    #pragma unroll
    for (int ks = 0; ks < 2; ks++) {
      short8v af[2], bav[2], bgv[2];
      #pragma unroll
      for (int mt = 0; mt < 2; mt++)
        af[mt] = *(const short8v*)&As[(m0 + 16*mt + l16)*72 + ks*32 + g*8];
      #pragma unroll
      for (int nt = 0; nt < 2; nt++) {
        bav[nt] = *(const short8v*)&Ba[(n0 + 16*nt + l16)*72 + ks*32 + g*8];
        bgv[nt] = *(const short8v*)&Bg[(n0 + 16*nt + l16)*72 + ks*32 + g*8];
      }
      #pragma unroll
      for (int mt = 0; mt < 2; mt++)
        #pragma unroll
        for (int nt = 0; nt < 2; nt++) {
          aacc[mt][nt] = __builtin_amdgcn_mfma_f32_16x16x32_bf16(af[mt], bav[nt], aacc[mt][nt], 0, 0, 0);
          gacc[mt][nt] = __builtin_amdgcn_mfma_f32_16x16x32_bf16(af[mt], bgv[nt], gacc[mt][nt], 0, 0, 0);
        }
    }
  }
  __syncthreads();
  float* Cs = (float*)smem;
  #pragma unroll
  for (int nt = 0; nt < 2; nt++) {
    int col = n0 + 16*nt + l16;
    float ba = bias[bn + col];
    float bg2 = bias[1280 + bn + col];
    #pragma unroll
    for (int mt = 0; mt < 2; mt++)
      #pragma unroll
      for (int r = 0; r < 4; r++) {
        float a = aacc[mt][nt][r] + ba;
        float gv = gacc[mt][nt][r] + bg2;
        float gl = 0.5f * gv * (1.f + erff(gv * 0.70710678118654752f));
        Cs[(m0 + 16*mt + 4*g + r)*68 + col] = a * gl;
      }
  }
  __syncthreads();
  #pragma unroll
  for (int i = 0; i < 8; i++) {
    int p = t + i*256;
    int mm = p >> 5, nn = (p & 31)*2;
    *(unsigned*)&C[(size_t)(bm + mm)*1280 + bn + nn] = pack2(Cs[mm*68 + nn], Cs[mm*68 + nn + 1]);
  }
}

// ---------------- Self-attention partial: reg-prefetch pipeline, max-free softmax ---------
__global__ __launch_bounds__(512) void self_attn_part(
    const u16* __restrict__ Q, const u16* __restrict__ K,
    const u16* __restrict__ vT, u16* __restrict__ Opart,
    float* __restrict__ Lp) {
  const int h = blockIdx.y;
  const int q0 = blockIdx.x * 128;
  const int sp = blockIdx.z;
  const int tid = threadIdx.x;
  const int w = tid >> 6, lane = tid & 63;
  const int l16 = lane & 15, g = lane >> 4;

  __shared__ __align__(16) u16 Kls[64][72];
  __shared__ __align__(16) u16 Vt[48][72];
  __shared__ __align__(16) u16 PsT[8][16][72];

  for (int e = tid; e < 64*12; e += 512) {
    int r = e / 12, c = e % 12;
    *(unsigned*)&Kls[r][40 + 2*c] = 0u;
  }
  if (tid < 256) {
    int r = 40 + (tid >> 5), c = tid & 31;
    *(unsigned*)&Vt[r][2*c] = 0u;
  }

  short8v Qb[2];
  {
    const u16* qrow = Q + (size_t)(q0 + w*16 + l16)*320 + h*40;
    Qb[0] = *(const short8v*)(qrow + g*8);
    short8v z = {};
    Qb[1] = (g == 0) ? *(const short8v*)(qrow + 32) : z;
  }

  const u16* Kbase = K + (size_t)(sp*1024)*320 + h*40;
  const u16* Vbase = vT + (size_t)(h*40)*4096 + sp*1024;

  const int ksl = (tid < 320) ? tid : 0;
  const int keyK = ksl / 5, chK = ksl - keyK*5;
  const u16* gK = Kbase + (size_t)keyK*320 + chK*8;
  u16* lK = &Kls[keyK][chK*8];
  const int vsl = (tid >= 192) ? (tid - 192) : 0;
  const int dV = vsl >> 3, chV = vsl & 7;
  const u16* gV = Vbase + (size_t)dV*4096 + chV*8;
  u16* lV = &Vt[dV][chV*8];

  const bool doK = (tid < 320), doV = (tid >= 192);

  short8v rK = {}, rV = {};
  if (doK) rK = *(const short8v*)gK;
  if (doV) rV = *(const short8v*)gV;
  gK += 64*320; gV += 64;

  float l_i = 0.f;
  float4v Of[3] = {};

  for (int it = 0; it < 16; ++it) {
    __syncthreads();
    if (doK) *(short8v*)lK = rK;
    if (doV) *(short8v*)lV = rV;
    __syncthreads();
    if (it < 15) {
      if (doK) rK = *(const short8v*)gK;
      if (doV) rV = *(const short8v*)gV;
      gK += 64*320; gV += 64;
    }

    float4v Sf[4];
    #pragma unroll
    for (int mt = 0; mt < 4; mt++) {
      short8v ka0 = *(const short8v*)&Kls[mt*16 + l16][g*8];
      short8v ka1 = *(const short8v*)&Kls[mt*16 + l16][32 + g*8];
      float4v s = {};
      s = __builtin_amdgcn_mfma_f32_16x16x32_bf16(ka0, Qb[0], s, 0, 0, 0);
      s = __builtin_amdgcn_mfma_f32_16x16x32_bf16(ka1, Qb[1], s, 0, 0, 0);
      Sf[mt] = s;
    }

    float rsum = 0.f;
    #pragma unroll
    for (int mt = 0; mt < 4; mt++)
      #pragma unroll
      for (int r = 0; r < 4; r++) {
        float p = exp2f(Sf[mt][r]);
        Sf[mt][r] = p; rsum += p;
      }
    rsum += __shfl_xor(rsum, 16);
    rsum += __shfl_xor(rsum, 32);
    l_i += rsum;

    #pragma unroll
    for (int mt = 0; mt < 4; mt++) {
      uint2 pk;
      pk.x = pack2(Sf[mt][0], Sf[mt][1]);
      pk.y = pack2(Sf[mt][2], Sf[mt][3]);
      *(uint2*)&PsT[w][l16][mt*16 + 4*g] = pk;
    }
    asm volatile("s_waitcnt lgkmcnt(0)" ::: "memory");

    #pragma unroll
    for (int ks = 0; ks < 2; ks++) {
      short8v pb = *(const short8v*)&PsT[w][l16][ks*32 + g*8];
      #pragma unroll
      for (int mt = 0; mt < 3; mt++) {
        short8v va = *(const short8v*)&Vt[mt*16 + l16][ks*32 + g*8];
        Of[mt] = __builtin_amdgcn_mfma_f32_16x16x32_bf16(va, pb, Of[mt], 0, 0, 0);
      }
    }
  }

  const int q = q0 + w*16 + l16;
  u16* orow = Opart + (size_t)sp*4096*320 + (size_t)q*320 + h*40;
  #pragma unroll
  for (int mt = 0; mt < 3; mt++) {
    #pragma unroll
    for (int rp = 0; rp < 2; rp++) {
      int d = mt*16 + 4*g + rp*2;
      if (d < 40)
        *(unsigned*)&orow[d] = pack2(Of[mt][rp*2], Of[mt][rp*2+1]);
    }
  }
  if (g == 0)
    Lp[sp*32768 + q*8 + h] = l_i;
}

// ---------------- merge 4 partials (weights all 1) -> ao bf16 ----------------
__global__ __launch_bounds__(256) void attn_merge(
    const u16* __restrict__ Opart, const float* __restrict__ Lp,
    u16* __restrict__ O) {
  int gid = blockIdx.x*256 + threadIdx.x;   // < 4096*8*20
  int dp = gid % 20;
  int qh = gid / 20;
  int q = qh >> 3, h = qh & 7;
  float ls = Lp[qh] + Lp[32768 + qh] + Lp[2*32768 + qh] + Lp[3*32768 + qh];
  size_t base = (size_t)q*320 + h*40 + dp*2;
  const size_t HBu = 4096u*320u;
  float r0 = 0.f, r1 = 0.f;
  #pragma unroll
  for (int sp = 0; sp < 4; sp++) {
    unsigned u = *(const unsigned*)&Opart[sp*HBu + base];
    r0 += bfu2f((u16)(u & 0xffffu));
    r1 += bfu2f((u16)(u >> 16));
  }
  float inv = 1.f / ls;
  *(unsigned*)&O[base] = pack2(r0*inv, r1*inv);
}

// ---------------- Cross-attention: single-shot MFMA, 77 keys, max-free ----------------
__global__ __launch_bounds__(256) void cross_attn_mfma(
    const u16* __restrict__ Q, const u16* __restrict__ Kc,
    const u16* __restrict__ Vc, u16* __restrict__ O) {
  const int h = blockIdx.y;
  const int q0 = blockIdx.x * 64;
  const int tid = threadIdx.x;
  const int w = tid >> 6, lane = tid & 63;
  const int l16 = lane & 15, g = lane >> 4;

  __shared__ __align__(16) u16 Kls[80][72];
  __shared__ __align__(16) u16 Vt[48][104];
  __shared__ __align__(16) u16 PsT[4][16][104];

  for (int e = tid; e < 80*12; e += 256) {
    int r = e / 12, c = e % 12;
    *(unsigned*)&Kls[r][40 + 2*c] = 0u;
  }
  for (int e = tid; e < 48*52; e += 256) {
    int r = e / 52, c = e % 52;
    *(unsigned*)&Vt[r][2*c] = 0u;
  }
  {
    int r = lane >> 2, c4 = (lane & 3)*4;
    uint2 z; z.x = 0u; z.y = 0u;
    *(uint2*)&PsT[w][r][80 + c4] = z;
  }

  short8v Qb[2];
  {
    const u16* qrow = Q + (size_t)(q0 + w*16 + l16)*320 + h*40;
    Qb[0] = *(const short8v*)(qrow + g*8);
    short8v z = {};
    Qb[1] = (g == 0) ? *(const short8v*)(qrow + 32) : z;
  }

  for (int e = tid; e < 1600; e += 256) {
    int key = e / 20, dp = e % 20;
    unsigned val = 0u;
    if (key < 77) val = *(const unsigned*)&Kc[(size_t)key*320 + h*40 + dp*2];
    *(unsigned*)&Kls[key][dp*2] = val;
  }
  __syncthreads();
  for (int e = tid; e < 1600; e += 256) {
    int kp = e / 40, d = e % 40;
    unsigned u0 = (kp*2     < 77) ? (unsigned)Vc[(size_t)(kp*2    )*320 + h*40 + d] : 0u;
    unsigned u1 = (kp*2 + 1 < 77) ? (unsigned)Vc[(size_t)(kp*2 + 1)*320 + h*40 + d] : 0u;
    *(unsigned*)&Vt[d][kp*2] = u0 | (u1 << 16);
  }
  __syncthreads();

  float4v Sf[5];
  #pragma unroll
  for (int mt = 0; mt < 5; mt++) {
    short8v ka0 = *(const short8v*)&Kls[mt*16 + l16][g*8];
    short8v ka1 = *(const short8v*)&Kls[mt*16 + l16][32 + g*8];
    float4v s = {};
    s = __builtin_amdgcn_mfma_f32_16x16x32_bf16(ka0, Qb[0], s, 0, 0, 0);
    s = __builtin_amdgcn_mfma_f32_16x16x32_bf16(ka1, Qb[1], s, 0, 0, 0);
    Sf[mt] = s;
  }

  float rsum = 0.f;
  #pragma unroll
  for (int mt = 0; mt < 5; mt++)
    #pragma unroll
    for (int r = 0; r < 4; r++) {
      int key = mt*16 + 4*g + r;
      float p = (key < 77) ? exp2f(Sf[mt][r]) : 0.f;
      Sf[mt][r] = p; rsum += p;
    }
  rsum += __shfl_xor(rsum, 16);
  rsum += __shfl_xor(rsum, 32);

  #pragma unroll
  for (int mt = 0; mt < 5; mt++) {
    uint2 pk;
    pk.x = pack2(Sf[mt][0], Sf[mt][1]);
    pk.y = pack2(Sf[mt][2], Sf[mt][3]);
    *(uint2*)&PsT[w][l16][mt*16 + 4*g] = pk;
  }
  __syncthreads();

  float4v Of[3] = {};
  #pragma unroll
  for (int ks = 0; ks < 3; ks++) {
    short8v pb = *(const short8v*)&PsT[w][l16][ks*32 + g*8];
    #pragma unroll
    for (int mt = 0; mt < 3; mt++) {
      short8v va = *(const short8v*)&Vt[mt*16 + l16][ks*32 + g*8];
      Of[mt] = __builtin_amdgcn_mfma_f32_16x16x32_bf16(va, pb, Of[mt], 0, 0, 0);
    }
  }

  float inv = 1.f / rsum;
  u16* orow = O + (size_t)(q0 + w*16 + l16)*320 + h*40;
  #pragma unroll
  for (int mt = 0; mt < 3; mt++) {
    #pragma unroll
    for (int rp = 0; rp < 2; rp++) {
      int d = mt*16 + 4*g + rp*2;
      if (d < 40)
        *(unsigned*)&orow[d] = pack2(Of[mt][rp*2] * inv, Of[mt][rp*2+1] * inv);
    }
  }
}

extern "C" void kernel_launch(void* const* d_in, const int* in_sizes, int n_in,
                              void* d_out, int out_size, void* d_ws, size_t ws_size,
                              hipStream_t stream) {
  const float* x        = (const float*)d_in[0];
  const float* ctx      = (const float*)d_in[1];
  const float* gn_s     = (const float*)d_in[2];
  const float* gn_b     = (const float*)d_in[3];
  const float* w_pin    = (const float*)d_in[4];
  const float* b_pin    = (const float*)d_in[5];
  const float* ln1_s    = (const float*)d_in[6];
  const float* ln1_b    = (const float*)d_in[7];
  const float* wq1      = (const float*)d_in[8];
  const float* wk1      = (const float*)d_in[9];
  const float* wv1      = (const float*)d_in[10];
  const float* wo1      = (const float*)d_in[11];
  const float* bo1      = (const float*)d_in[12];
  const float* ln2_s    = (const float*)d_in[13];
  const float* ln2_b    = (const float*)d_in[14];
  const float* wq2      = (const float*)d_in[15];
  const float* wk2      = (const float*)d_in[16];
  const float* wv2      = (const float*)d_in[17];
  const float* wo2      = (const float*)d_in[18];
  const float* bo2      = (const float*)d_in[19];
  const float* ln3_s    = (const float*)d_in[20];
  const float* ln3_b    = (const float*)d_in[21];
  const float* w_ff1    = (const float*)d_in[22];
  const float* b_ff1    = (const float*)d_in[23];
  const float* w_ff2    = (const float*)d_in[24];
  const float* b_ff2    = (const float*)d_in[25];
  const float* w_pout   = (const float*)d_in[26];
  const float* b_pout   = (const float*)d_in[27];
  float* out = (float*)d_out;

  u16* ws = (u16*)d_ws;
  const size_t HB = 4096u*320u;
  u16* h   = ws;
  u16* hn  = ws + HB;
  u16* q   = ws + 2*HB;    // q,k contiguous (QKV fused epilogue)
  u16* k   = ws + 3*HB;
  u16* vT  = ws + 4*HB;    // V^T [320][4096]
  u16* ao  = ws + 5*HB;
  u16* gnT = k;
  u16* gg  = q;            // GEGLU out overlays q,k,vT,ao
  u16* wb  = ws + 6*HB;
  size_t o = 0;
  u16* ctxb   = wb + o; o += 59136;
  u16* wq1T   = wb + o; o += 102400;   // stacked: wq1T,wk1T,wv1T = [960][320]
  u16* wk1T   = wb + o; o += 102400;
  u16* wv1T   = wb + o; o += 102400;
  u16* wo1T   = wb + o; o += 102400;
  u16* wq2T   = wb + o; o += 102400;
  u16* wk2T   = wb + o; o += 245760;   // stacked: wk2T,wv2T = [640][768]
  u16* wv2T   = wb + o; o += 245760;
  u16* wo2T   = wb + o; o += 102400;
  u16* wff1T  = wb + o; o += 819200;
  u16* wff2T  = wb + o; o += 409600;
  u16* wpoutT = wb + o; o += 102400;
  u16* wpinT  = wb + o; o += 102400;
  u16* kc     = wb + o; o += 24640;    // kc,vc contiguous, segStride 24640
  u16* vc     = wb + o; o += 24640;
  float* psum = (float*)(wb + o);      // 256 partial sums
  float* psq  = psum + 256;
  u16* OpartB = (u16*)(psq + 256);               // 4 x HB bf16 = 10.5 MB
  float* Lpart = (float*)(OpartB + 4*HB);        // 4 x 32768 fp32

  TPack tp;
  const float* srcs[12] = {wq1, wk1, wv1, wo1, wq2, wo2, w_pin, w_pout, wk2, wv2, w_ff1, w_ff2};
  u16* dsts[12]         = {wq1T, wk1T, wv1T, wo1T, wq2T, wo2T, wpinT, wpoutT, wk2T, wv2T, wff1T, wff2T};
  int Ks[12] = {320,320,320,320,320,320,320,320,768,768,320,1280};
  int Ns[12] = {320,320,320,320,320,320,320,320,320,320,2560,320};
  int off = 0;
  for (int i = 0; i < 12; i++) {
    tp.d[i].src = srcs[i]; tp.d[i].dst = dsts[i];
    tp.d[i].K = Ks[i]; tp.d[i].N = Ns[i];
    tp.d[i].off = off; tp.d[i].tx = Ns[i]/32;
    tp.d[i].sc = (i == 0 || i == 4) ? SCALE_L2E : 1.0f;   // wq1, wq2 pre-scaled
    off += (Ks[i]/32)*(Ns[i]/32);
  }

  dim3 blk(256), g64x10(64, 10), g64x5(64, 5);
  const u16* nres = nullptr;
  const float* nb = nullptr;

  // prep: weight tcvt (off) + ctx cvt (58) + gn partial stats (256)
  hipLaunchKernelGGL(prep_kernel, dim3(off + 58 + 256), blk, 0, stream,
                     tp, off, ctx, ctxb, x, psum, psq);
  hipLaunchKernelGGL(gn_apply_t_kernel, g64x5, blk, 0, stream, x, psum, psq, gn_s, gn_b, gnT);
  hipLaunchKernelGGL((oneshot<0>), g64x10, blk, 0, stream, gnT, wpinT, b_pin, nres, nb, (void*)h, 320, 1);
  hipLaunchKernelGGL(layernorm_kernel, dim3(4096), dim3(64), 0, stream, h, ln1_s, ln1_b, hn);
  // fused QKV: N=960; segs 0,1 -> q,k; seg 2 -> vT (transposed)
  hipLaunchKernelGGL((mgemm<3>), dim3(64, 15), blk, 0, stream, hn, wq1T, nb, nres, (const float*)vT, (void*)q, 4096, 960, 320, (int)HB);
  hipLaunchKernelGGL(self_attn_part, dim3(32, 8, 4), dim3(512), 0, stream, q, k, vT, OpartB, Lpart);
  hipLaunchKernelGGL(attn_merge, dim3(2560), blk, 0, stream, OpartB, Lpart, ao);
  hipLaunchKernelGGL((oneshot<0>), g64x10, blk, 0, stream, ao, wo1T, bo1, h, nb, (void*)h, 320, 1);
  hipLaunchKernelGGL(layernorm_kernel, dim3(4096), dim3(64), 0, stream, h, ln2_s, ln2_b, hn);
  hipLaunchKernelGGL((oneshot<0>), g64x10, blk, 0, stream, hn, wq2T, nb, nres, nb, (void*)q, 320, 1);
  hipLaunchKernelGGL((mgemm<1>), dim3(2, 10), blk, 0, stream, ctxb, wk2T, nb, nres, nb, (void*)kc, 77, 640, 768, 24640);
  hipLaunchKernelGGL(cross_attn_mfma, dim3(64, 8), blk, 0, stream, q, kc, vc, ao);
  hipLaunchKernelGGL((oneshot<0>), g64x10, blk, 0, stream, ao, wo2T, bo2, h, nb, (void*)h, 320, 1);
  hipLaunchKernelGGL(layernorm_kernel, dim3(4096), dim3(64), 0, stream, h, ln3_s, ln3_b, hn);
  hipLaunchKernelGGL(geglu_mfma, dim3(64, 20), blk, 0, stream, hn, wff1T, b_ff1, gg);
  hipLaunchKernelGGL((oneshot<0>), g64x10, blk, 0, stream, gg, wff2T, b_ff2, h, nb, (void*)h, 1280, 4);
  hipLaunchKernelGGL((oneshot<2>), g64x10, blk, 0, stream, h, wpoutT, b_pout, nres, x, (void*)out, 320, 1);
}

// Round 13
// 291.450 us; speedup vs baseline: 1.6507x; 1.0049x over previous
//
#include <hip/hip_runtime.h>
#include <hip/hip_bf16.h>
#include <math.h>

#define SCALE_L2E  0.22811011265722836f   // (1/sqrt(40)) * log2(e)

typedef __attribute__((ext_vector_type(8))) short short8v;
typedef __attribute__((ext_vector_type(4))) float float4v;
typedef unsigned short u16;

__device__ __forceinline__ unsigned pack2(float a, float b) {
  float2 f; f.x = a; f.y = b;
  __hip_bfloat162 h = __float22bfloat162_rn(f);
  return *(unsigned*)&h;
}
__device__ __forceinline__ float bfu2f(u16 u) {
  return __uint_as_float(((unsigned)u) << 16);
}
__device__ __forceinline__ u16 f2bf(float x) {
  __hip_bfloat16 h = __float2bfloat16(x);
  return *(u16*)&h;
}

// ---------------- prep: weight transpose+convert | ctx cvt | gn PARTIAL stats --------------
struct TDesc { const float* src; u16* dst; int K, N, off, tx; float sc; };
struct TPack { TDesc d[12]; };

__global__ __launch_bounds__(256) void prep_kernel(
    TPack p, int nT,
    const float* __restrict__ ctxsrc, u16* __restrict__ ctxdst,
    const float* __restrict__ x,
    float* __restrict__ psum, float* __restrict__ psq) {
  __shared__ float ls[32][33];
  int bt = blockIdx.x, t = threadIdx.x;
  if (bt < nT) {
    int ti = 0;
    #pragma unroll
    for (int i = 1; i < 12; i++) if (bt >= p.d[i].off) ti = i;
    TDesc dd = p.d[ti];
    int local = bt - dd.off;
    int n0 = (local % dd.tx) * 32, k0 = (local / dd.tx) * 32;
    #pragma unroll
    for (int i = 0; i < 4; i++) {
      int idx = t + i*256, r = idx >> 5, c = idx & 31;
      ls[r][c] = dd.src[(size_t)(k0 + r)*dd.N + n0 + c];
    }
    __syncthreads();
    #pragma unroll
    for (int i = 0; i < 2; i++) {
      int p2 = t + i*256, n = p2 >> 4, kp = (p2 & 15)*2;
      *(unsigned*)&dd.dst[(size_t)(n0 + n)*dd.K + k0 + kp] =
        pack2(ls[kp][n]*dd.sc, ls[kp+1][n]*dd.sc);
    }
  } else if (bt < nT + 58) {
    int idx = ((bt - nT)*256 + t)*4;
    if (idx < 59136) {
      float4 v = *(const float4*)&ctxsrc[idx];
      uint2 o; o.x = pack2(v.x, v.y); o.y = pack2(v.z, v.w);
      *(uint2*)&ctxdst[idx] = o;
    }
  } else {
    int pp = bt - nT - 58;            // 0..255
    int g = pp >> 3, part = pp & 7;
    size_t base = (size_t)g*40960 + (size_t)part*5120;
    float sum = 0.f, sq = 0.f;
    #pragma unroll
    for (int r = 0; r < 5; r++) {
      float4 v = *(const float4*)&x[base + (size_t)(t + r*256)*4];
      sum += v.x + v.y + v.z + v.w;
      sq  += v.x*v.x + v.y*v.y + v.z*v.z + v.w*v.w;
    }
    float* s1 = &ls[0][0];
    float* s2 = &ls[8][0] + 8;
    s1[t] = sum; s2[t] = sq; __syncthreads();
    for (int st = 128; st > 0; st >>= 1) {
      if (t < st) { s1[t] += s1[t+st]; s2[t] += s2[t+st]; }
      __syncthreads();
    }
    if (t == 0) { psum[pp] = s1[0]; psq[pp] = s2[0]; }
  }
}

// ---------------- fused: GN apply+transpose (blocks 0..319) | kc/vc GEMM (320..339) --------
__global__ __launch_bounds__(256) void gn_kcvc(
    const float* __restrict__ x, const float* __restrict__ psum,
    const float* __restrict__ psq, const float* __restrict__ gs,
    const float* __restrict__ gb, u16* __restrict__ gnT,
    const u16* __restrict__ ctxb, const u16* __restrict__ wk2T,
    u16* __restrict__ kcvc) {
  __shared__ __align__(16) u16 smem[2*64*72];   // 18.4 KB, aliased by both paths
  __shared__ float scl[64], sft[64];
  const int t = threadIdx.x;
  if (blockIdx.x < 320) {
    // ---- GroupNorm apply + transpose ----
    float* ts = (float*)smem;   // [64][65] = 16640 floats? no: 64*65*4B = 16.6KB <= 18.4KB
    int s0 = (blockIdx.x & 63) * 64, c0 = (blockIdx.x >> 6) * 64;
    if (t < 64) {
      int c = c0 + t, g = c / 10;
      float s = 0.f, q = 0.f;
      #pragma unroll
      for (int i = 0; i < 8; i++) { s += psum[g*8 + i]; q += psq[g*8 + i]; }
      float mu = s * (1.f/40960.f);
      float var = q * (1.f/40960.f) - mu*mu;
      float rs = rsqrtf(var + 1e-6f);
      float sc = rs * gs[c];
      scl[t] = sc;
      sft[t] = gb[c] - mu * sc;
    }
    int crow = t >> 2, sch = (t & 3) * 16;
    #pragma unroll
    for (int j = 0; j < 4; j++) {
      float4 v = *(const float4*)&x[(size_t)(c0 + crow)*4096 + s0 + sch + 4*j];
      ts[crow*65 + sch + 4*j + 0] = v.x; ts[crow*65 + sch + 4*j + 1] = v.y;
      ts[crow*65 + sch + 4*j + 2] = v.z; ts[crow*65 + sch + 4*j + 3] = v.w;
    }
    __syncthreads();
    int srow = t >> 2, cch = (t & 3) * 16;
    #pragma unroll
    for (int p = 0; p < 8; p++) {
      int cl = cch + 2*p;
      float f0 = ts[cl*65 + srow] * scl[cl] + sft[cl];
      float f1 = ts[(cl+1)*65 + srow] * scl[cl+1] + sft[cl+1];
      *(unsigned*)&gnT[(size_t)(s0 + srow)*320 + c0 + cl] = pack2(f0, f1);
    }
  } else {
    // ---- kc/vc GEMM: [77,640] = ctxb[77,768] @ wk2T[640,768]^T, reg-prefetch BK=64 ----
    u16* As = smem;
    u16* Bs = smem + 64*72;
    const int lane = t & 63, w = t >> 6, l16 = lane & 15, g = lane >> 4;
    int local = blockIdx.x - 320;               // 0..19
    const int bm = (local & 1) * 64, bn = (local >> 1) * 64;
    const int m0 = (w & 1) * 32, n0 = (w >> 1) * 32;
    float4v acc[2][2] = {};
    const int ar = t >> 2, ac = (t & 3) * 16;
    const bool aok = (bm + ar) < 77;
    const u16* ga = &ctxb[(size_t)(bm + ar)*768 + ac];
    const u16* gbp = &wk2T[(size_t)(bn + ar)*768 + ac];
    short8v pa0 = {}, pa1 = {}, pb0, pb1;
    if (aok) { pa0 = *(const short8v*)ga; pa1 = *(const short8v*)(ga + 8); }
    pb0 = *(const short8v*)gbp; pb1 = *(const short8v*)(gbp + 8);
    for (int k0 = 0; k0 < 768; k0 += 64) {
      __syncthreads();
      *(short8v*)&As[ar*72 + ac] = pa0;
      *(short8v*)&As[ar*72 + ac + 8] = pa1;
      *(short8v*)&Bs[ar*72 + ac] = pb0;
      *(short8v*)&Bs[ar*72 + ac + 8] = pb1;
      __syncthreads();
      if (k0 + 64 < 768) {
        if (aok) { pa0 = *(const short8v*)(ga + k0 + 64); pa1 = *(const short8v*)(ga + k0 + 72); }
        pb0 = *(const short8v*)(gbp + k0 + 64); pb1 = *(const short8v*)(gbp + k0 + 72);
      }
      #pragma unroll
      for (int ks = 0; ks < 2; ks++) {
        short8v af[2], bfv[2];
        #pragma unroll
        for (int mt = 0; mt < 2; mt++)
          af[mt] = *(const short8v*)&As[(m0 + 16*mt + l16)*72 + ks*32 + g*8];
        #pragma unroll
        for (int nt = 0; nt < 2; nt++)
          bfv[nt] = *(const short8v*)&Bs[(n0 + 16*nt + l16)*72 + ks*32 + g*8];
        #pragma unroll
        for (int mt = 0; mt < 2; mt++)
          #pragma unroll
          for (int nt = 0; nt < 2; nt++)
            acc[mt][nt] = __builtin_amdgcn_mfma_f32_16x16x32_bf16(af[mt], bfv[nt], acc[mt][nt], 0, 0, 0);
      }
    }
    __syncthreads();
    float* Cs = (float*)smem;  // [64][68] = 17.4KB
    #pragma unroll
    for (int mt = 0; mt < 2; mt++)
      #pragma unroll
      for (int nt = 0; nt < 2; nt++)
        #pragma unroll
        for (int r = 0; r < 4; r++)
          Cs[(m0 + 16*mt + 4*g + r)*68 + n0 + 16*nt + l16] = acc[mt][nt][r];
    __syncthreads();
    u16* C = kcvc + (size_t)(bn / 320) * 24640;
    int nb = bn % 320;
    #pragma unroll
    for (int i = 0; i < 8; i++) {
      int p = t + i*256;
      int mm = p >> 5, nn = (p & 31)*2;
      if (bm + mm >= 77) continue;
      *(unsigned*)&C[(size_t)(bm + mm)*320 + nb + nn] = pack2(Cs[mm*68 + nn], Cs[mm*68 + nn + 1]);
    }
  }
}

// ---------------- LayerNorm bf16->bf16: one wave per row of 320 ----------------
__global__ __launch_bounds__(64) void layernorm_kernel(
    const u16* __restrict__ X, const float* __restrict__ s,
    const float* __restrict__ b, u16* __restrict__ Y) {
  int row = blockIdx.x, t = threadIdx.x;
  const u16* xr = X + (size_t)row*320;
  float v[5], sum = 0.f, sq = 0.f;
  #pragma unroll
  for (int i = 0; i < 5; i++) { v[i] = bfu2f(xr[t + 64*i]); sum += v[i]; sq += v[i]*v[i]; }
  #pragma unroll
  for (int o = 32; o > 0; o >>= 1) { sum += __shfl_down(sum, o); sq += __shfl_down(sq, o); }
  sum = __shfl(sum, 0); sq = __shfl(sq, 0);
  float mu = sum * (1.f/320.f);
  float var = sq * (1.f/320.f) - mu*mu;
  float rs = rsqrtf(var + 1e-5f);
  u16* yr = Y + (size_t)row*320;
  #pragma unroll
  for (int i = 0; i < 5; i++) {
    int c = t + 64*i;
    yr[c] = f2bf((v[i]-mu)*rs*s[c] + b[c]);
  }
}

// ---------------- One-shot GEMM: C[M,320] = A[M,K] * BT[320,K]^T, K in 320-chunks ---------
template<int MODE>
__global__ __launch_bounds__(256) void oneshot(
    const u16* __restrict__ A, const u16* __restrict__ BT,
    const float* __restrict__ bias, const u16* __restrict__ res,
    const float* __restrict__ xres, void* __restrict__ Cout,
    int K, int chunks) {
  __shared__ __align__(16) u16 As[64*328];
  __shared__ __align__(16) u16 Bs[32*328];
  const int t = threadIdx.x;
  const int lane = t & 63, w = t >> 6, l16 = lane & 15, g = lane >> 4;
  const int bm = blockIdx.x * 64, bn = blockIdx.y * 32;
  const int m0 = (w & 1) * 32, n0 = (w >> 1) * 16;
  float4v acc[2] = {};

  const u16* Ab = A + (size_t)(bm + (t>>2))*K + (t&3)*16;
  u16* Al = As + (t>>2)*328 + (t&3)*16;
  const u16* Bb = BT + (size_t)(bn + (t>>3))*K + (t&7)*16;
  u16* Bl = Bs + (t>>3)*328 + (t&7)*16;
  const bool b3 = (t & 7) < 4;

  for (int ch = 0; ch < chunks; ch++) {
    const int c0 = ch*320;
    __syncthreads();
    #pragma unroll
    for (int j = 0; j < 5; j++) {
      *(short8v*)(Al + 64*j)     = *(const short8v*)(Ab + c0 + 64*j);
      *(short8v*)(Al + 64*j + 8) = *(const short8v*)(Ab + c0 + 64*j + 8);
    }
    *(short8v*)Bl         = *(const short8v*)(Bb + c0);
    *(short8v*)(Bl + 8)   = *(const short8v*)(Bb + c0 + 8);
    *(short8v*)(Bl + 128) = *(const short8v*)(Bb + c0 + 128);
    *(short8v*)(Bl + 136) = *(const short8v*)(Bb + c0 + 136);
    if (b3) {
      *(short8v*)(Bl + 256) = *(const short8v*)(Bb + c0 + 256);
      *(short8v*)(Bl + 264) = *(const short8v*)(Bb + c0 + 264);
    }
    __syncthreads();
    #pragma unroll
    for (int ks = 0; ks < 10; ks++) {
      short8v bfv = *(const short8v*)&Bs[(n0 + l16)*328 + ks*32 + g*8];
      #pragma unroll
      for (int mt = 0; mt < 2; mt++) {
        short8v af = *(const short8v*)&As[(m0 + 16*mt + l16)*328 + ks*32 + g*8];
        acc[mt] = __builtin_amdgcn_mfma_f32_16x16x32_bf16(af, bfv, acc[mt], 0, 0, 0);
      }
    }
  }
  __syncthreads();
  float* Cs = (float*)As;   // [64][36]
  #pragma unroll
  for (int mt = 0; mt < 2; mt++)
    #pragma unroll
    for (int r = 0; r < 4; r++)
      Cs[(m0 + 16*mt + 4*g + r)*36 + n0 + l16] = acc[mt][r];
  __syncthreads();

  if (MODE == 0) {
    u16* C = (u16*)Cout;
    #pragma unroll
    for (int i = 0; i < 4; i++) {
      int p = t + i*256;
      int mm = p >> 4, pp = (p & 15)*2;
      float f0 = Cs[mm*36 + pp], f1 = Cs[mm*36 + pp + 1];
      if (bias) { f0 += bias[bn + pp]; f1 += bias[bn + pp + 1]; }
      if (res) {
        unsigned u = *(const unsigned*)&res[(size_t)(bm + mm)*320 + bn + pp];
        f0 += bfu2f((u16)(u & 0xffffu));
        f1 += bfu2f((u16)(u >> 16));
      }
      *(unsigned*)&C[(size_t)(bm + mm)*320 + bn + pp] = pack2(f0, f1);
    }
  } else {
    float* C = (float*)Cout;
    int nloc = t >> 3, mch = (t & 7) * 8;
    float bb = bias[bn + nloc];
    #pragma unroll
    for (int j = 0; j < 2; j++) {
      int m4 = mch + j*4;
      float4 xv = *(const float4*)&xres[(size_t)(bn + nloc)*4096 + bm + m4];
      float4 ov;
      ov.x = Cs[(m4+0)*36 + nloc] + bb + xv.x;
      ov.y = Cs[(m4+1)*36 + nloc] + bb + xv.y;
      ov.z = Cs[(m4+2)*36 + nloc] + bb + xv.z;
      ov.w = Cs[(m4+3)*36 + nloc] + bb + xv.w;
      *(float4*)&C[(size_t)(bn + nloc)*4096 + bm + m4] = ov;
    }
  }
}

// ---------------- QKV one-shot: A[4096,320] @ wqkvT[960,320]^T; grid (64,30) ----------
// segs 0,1 -> q,k at [m][n%320]; seg 2 -> vT[(n%320)][m] transposed.
__global__ __launch_bounds__(256) void qkv_oneshot(
    const u16* __restrict__ A, const u16* __restrict__ BT,
    u16* __restrict__ qk, u16* __restrict__ vT, int segStride) {
  __shared__ __align__(16) u16 As[64*328];
  __shared__ __align__(16) u16 Bs[32*328];
  const int t = threadIdx.x;
  const int lane = t & 63, w = t >> 6, l16 = lane & 15, g = lane >> 4;
  const int bm = blockIdx.x * 64, bn = blockIdx.y * 32;
  const int m0 = (w & 1) * 32, n0 = (w >> 1) * 16;
  float4v acc[2] = {};

  const u16* Ab = A + (size_t)(bm + (t>>2))*320 + (t&3)*16;
  u16* Al = As + (t>>2)*328 + (t&3)*16;
  const u16* Bb = BT + (size_t)(bn + (t>>3))*320 + (t&7)*16;
  u16* Bl = Bs + (t>>3)*328 + (t&7)*16;
  const bool b3 = (t & 7) < 4;

  #pragma unroll
  for (int j = 0; j < 5; j++) {
    *(short8v*)(Al + 64*j)     = *(const short8v*)(Ab + 64*j);
    *(short8v*)(Al + 64*j + 8) = *(const short8v*)(Ab + 64*j + 8);
  }
  *(short8v*)Bl         = *(const short8v*)Bb;
  *(short8v*)(Bl + 8)   = *(const short8v*)(Bb + 8);
  *(short8v*)(Bl + 128) = *(const short8v*)(Bb + 128);
  *(short8v*)(Bl + 136) = *(const short8v*)(Bb + 136);
  if (b3) {
    *(short8v*)(Bl + 256) = *(const short8v*)(Bb + 256);
    *(short8v*)(Bl + 264) = *(const short8v*)(Bb + 264);
  }
  __syncthreads();
  #pragma unroll
  for (int ks = 0; ks < 10; ks++) {
    short8v bfv = *(const short8v*)&Bs[(n0 + l16)*328 + ks*32 + g*8];
    #pragma unroll
    for (int mt = 0; mt < 2; mt++) {
      short8v af = *(const short8v*)&As[(m0 + 16*mt + l16)*328 + ks*32 + g*8];
      acc[mt] = __builtin_amdgcn_mfma_f32_16x16x32_bf16(af, bfv, acc[mt], 0, 0, 0);
    }
  }
  __syncthreads();
  float* Cs = (float*)As;   // [64][36]
  #pragma unroll
  for (int mt = 0; mt < 2; mt++)
    #pragma unroll
    for (int r = 0; r < 4; r++)
      Cs[(m0 + 16*mt + 4*g + r)*36 + n0 + l16] = acc[mt][r];
  __syncthreads();

  if (bn < 640) {
    u16* C = qk + (size_t)(bn / 320) * segStride;
    int nb = bn % 320;
    #pragma unroll
    for (int i = 0; i < 4; i++) {
      int p = t + i*256;
      int mm = p >> 4, pp = (p & 15)*2;
      *(unsigned*)&C[(size_t)(bm + mm)*320 + nb + pp] = pack2(Cs[mm*36 + pp], Cs[mm*36 + pp + 1]);
    }
  } else {
    int nloc = t >> 3, mch = (t & 7) * 8;
    int vd = bn - 640 + nloc;
    u16* dst = vT + (size_t)vd*4096 + bm + mch;
    uint4 o0;
    o0.x = pack2(Cs[(mch+0)*36 + nloc], Cs[(mch+1)*36 + nloc]);
    o0.y = pack2(Cs[(mch+2)*36 + nloc], Cs[(mch+3)*36 + nloc]);
    o0.z = pack2(Cs[(mch+4)*36 + nloc], Cs[(mch+5)*36 + nloc]);
    o0.w = pack2(Cs[(mch+6)*36 + nloc], Cs[(mch+7)*36 + nloc]);
    *(uint4*)dst = o0;
  }
}

// ---------------- GEGLU MFMA (reg-prefetch) ----------------
__global__ __launch_bounds__(256) void geglu_mfma(
    const u16* __restrict__ A, const u16* __restrict__ BT,
    const float* __restrict__ bias, u16* __restrict__ C) {
  __shared__ __align__(16) u16 smem[3*64*72];
  u16* As = smem;
  u16* Ba = smem + 64*72;
  u16* Bg = smem + 2*64*72;
  const int t = threadIdx.x;
  const int lane = t & 63, w = t >> 6, l16 = lane & 15, g = lane >> 4;
  const int bm = blockIdx.x * 64, bn = blockIdx.y * 64;
  const int m0 = (w & 1) * 32, n0 = (w >> 1) * 32;
  float4v aacc[2][2] = {}, gacc[2][2] = {};
  const int ar = t >> 2, ac = (t & 3) * 16;
  const u16* ga  = &A[(size_t)(bm + ar)*320 + ac];
  const u16* gba = &BT[(size_t)(bn + ar)*320 + ac];
  const u16* gbg = &BT[(size_t)(1280 + bn + ar)*320 + ac];

  short8v pa0 = *(const short8v*)ga,  pa1 = *(const short8v*)(ga + 8);
  short8v pb0 = *(const short8v*)gba, pb1 = *(const short8v*)(gba + 8);
  short8v pg0 = *(const short8v*)gbg, pg1 = *(const short8v*)(gbg + 8);

  for (int k0 = 0; k0 < 320; k0 += 64) {
    __syncthreads();
    *(short8v*)&As[ar*72 + ac] = pa0;
    *(short8v*)&As[ar*72 + ac + 8] = pa1;
    *(short8v*)&Ba[ar*72 + ac] = pb0;
    *(short8v*)&Ba[ar*72 + ac + 8] = pb1;
    *(short8v*)&Bg[ar*72 + ac] = pg0;
    *(short8v*)&Bg[ar*72 + ac + 8] = pg1;
    __syncthreads();
    if (k0 + 64 < 320) {
      pa0 = *(const short8v*)(ga + k0 + 64);  pa1 = *(const short8v*)(ga + k0 + 72);
      pb0 = *(const short8v*)(gba + k0 + 64); pb1 = *(const short8v*)(gba + k0 + 72);
      pg0 = *(const short8v*)(gbg + k0 + 64); pg1 = *(const short8v*)(gbg + k0 + 72);
    }
    #pragma unroll
    for (int ks = 0; ks < 2; ks++) {
      short8v af[2], bav[2], bgv[2];
      #pragma unroll
      for (int mt = 0; mt < 2; mt++)
        af[mt] = *(const short8v*)&As[(m0 + 16*mt + l16)*72 + ks*32 + g*8];
      #pragma unroll
      for (int nt = 0; nt < 2; nt++) {
        bav[nt] = *(const short8v*)&Ba[(n0 + 16*nt + l16)*72 + ks*32 + g*8];
        bgv[nt] = *(const short8v*)&Bg[(n0 + 16*nt + l16)*72 + ks*32 + g*8];
      }
      #pragma unroll
      for (int mt = 0; mt < 2; mt++)
        #pragma unroll
        for (int nt = 0; nt < 2; nt++) {
          aacc[mt][nt] = __builtin_amdgcn_mfma_f32_16x16x32_bf16(af[mt], bav[nt], aacc[mt][nt], 0, 0, 0);
          gacc[mt][nt] = __builtin_amdgcn_mfma_f32_16x16x32_bf16(af[mt], bgv[nt], gacc[mt][nt], 0, 0, 0);
        }
    }
  }
  __syncthreads();
  float* Cs = (float*)smem;
  #pragma unroll
  for (int nt = 0; nt < 2; nt++) {
    int col = n0 + 16*nt + l16;
    float ba = bias[bn + col];
    float bg2 = bias[1280 + bn + col];
    #pragma unroll
    for (int mt = 0; mt < 2; mt++)
      #pragma unroll
      for (int r = 0; r < 4; r++) {
        float a = aacc[mt][nt][r] + ba;
        float gv = gacc[mt][nt][r] + bg2;
        float gl = 0.5f * gv * (1.f + erff(gv * 0.70710678118654752f));
        Cs[(m0 + 16*mt + 4*g + r)*68 + col] = a * gl;
      }
  }
  __syncthreads();
  #pragma unroll
  for (int i = 0; i < 8; i++) {
    int p = t + i*256;
    int mm = p >> 5, nn = (p & 31)*2;
    *(unsigned*)&C[(size_t)(bm + mm)*1280 + bn + nn] = pack2(Cs[mm*68 + nn], Cs[mm*68 + nn + 1]);
  }
}

// ---------------- Self-attention partial: ones-row l-via-MFMA, reg-prefetch ----------------
__global__ __launch_bounds__(512) void self_attn_part(
    const u16* __restrict__ Q, const u16* __restrict__ K,
    const u16* __restrict__ vT, u16* __restrict__ Opart,
    float* __restrict__ Lp) {
  const int h = blockIdx.y;
  const int q0 = blockIdx.x * 128;
  const int sp = blockIdx.z;
  const int tid = threadIdx.x;
  const int w = tid >> 6, lane = tid & 63;
  const int l16 = lane & 15, g = lane >> 4;

  __shared__ __align__(16) u16 Kls[64][72];
  __shared__ __align__(16) u16 Vt[48][72];
  __shared__ __align__(16) u16 PsT[8][16][72];

  for (int e = tid; e < 64*12; e += 512) {
    int r = e / 12, c = e % 12;
    *(unsigned*)&Kls[r][40 + 2*c] = 0u;
  }
  if (tid < 256) {
    int r = 40 + (tid >> 5), c = tid & 31;
    // row 40 = 1.0 (ones row): PV MFMA then yields l = sum(P) at d=40
    *(unsigned*)&Vt[r][2*c] = (r == 40) ? 0x3F803F80u : 0u;
  }

  short8v Qb[2];
  {
    const u16* qrow = Q + (size_t)(q0 + w*16 + l16)*320 + h*40;
    Qb[0] = *(const short8v*)(qrow + g*8);
    short8v z = {};
    Qb[1] = (g == 0) ? *(const short8v*)(qrow + 32) : z;
  }

  const u16* Kbase = K + (size_t)(sp*1024)*320 + h*40;
  const u16* Vbase = vT + (size_t)(h*40)*4096 + sp*1024;

  const int ksl = (tid < 320) ? tid : 0;
  const int keyK = ksl / 5, chK = ksl - keyK*5;
  const u16* gK = Kbase + (size_t)keyK*320 + chK*8;
  u16* lK = &Kls[keyK][chK*8];
  const int vsl = (tid >= 192) ? (tid - 192) : 0;
  const int dV = vsl >> 3, chV = vsl & 7;
  const u16* gV = Vbase + (size_t)dV*4096 + chV*8;
  u16* lV = &Vt[dV][chV*8];

  const bool doK = (tid < 320), doV = (tid >= 192);

  short8v rK = {}, rV = {};
  if (doK) rK = *(const short8v*)gK;
  if (doV) rV = *(const short8v*)gV;
  gK += 64*320; gV += 64;

  float4v Of[3] = {};

  for (int it = 0; it < 16; ++it) {
    __syncthreads();
    if (doK) *(short8v*)lK = rK;
    if (doV) *(short8v*)lV = rV;
    __syncthreads();
    if (it < 15) {
      if (doK) rK = *(const short8v*)gK;
      if (doV) rV = *(const short8v*)gV;
      gK += 64*320; gV += 64;
    }

    float4v Sf[4];
    #pragma unroll
    for (int mt = 0; mt < 4; mt++) {
      short8v ka0 = *(const short8v*)&Kls[mt*16 + l16][g*8];
      short8v ka1 = *(const short8v*)&Kls[mt*16 + l16][32 + g*8];
      float4v s = {};
      s = __builtin_amdgcn_mfma_f32_16x16x32_bf16(ka0, Qb[0], s, 0, 0, 0);
      s = __builtin_amdgcn_mfma_f32_16x16x32_bf16(ka1, Qb[1], s, 0, 0, 0);
      Sf[mt] = s;
    }

    #pragma unroll
    for (int mt = 0; mt < 4; mt++)
      #pragma unroll
      for (int r = 0; r < 4; r++)
        Sf[mt][r] = exp2f(Sf[mt][r]);

    #pragma unroll
    for (int mt = 0; mt < 4; mt++) {
      uint2 pk;
      pk.x = pack2(Sf[mt][0], Sf[mt][1]);
      pk.y = pack2(Sf[mt][2], Sf[mt][3]);
      *(uint2*)&PsT[w][l16][mt*16 + 4*g] = pk;
    }
    asm volatile("s_waitcnt lgkmcnt(0)" ::: "memory");

    #pragma unroll
    for (int ks = 0; ks < 2; ks++) {
      short8v pb = *(const short8v*)&PsT[w][l16][ks*32 + g*8];
      #pragma unroll
      for (int mt = 0; mt < 3; mt++) {
        short8v va = *(const short8v*)&Vt[mt*16 + l16][ks*32 + g*8];
        Of[mt] = __builtin_amdgcn_mfma_f32_16x16x32_bf16(va, pb, Of[mt], 0, 0, 0);
      }
    }
  }

  const int q = q0 + w*16 + l16;
  u16* orow = Opart + (size_t)sp*4096*320 + (size_t)q*320 + h*40;
  #pragma unroll
  for (int mt = 0; mt < 3; mt++) {
    #pragma unroll
    for (int rp = 0; rp < 2; rp++) {
      int d = mt*16 + 4*g + rp*2;
      if (d < 40)
        *(unsigned*)&orow[d] = pack2(Of[mt][rp*2], Of[mt][rp*2+1]);
    }
  }
  // l = sum of P = Of[2][0] at d=40 (lane g==2)
  if (g == 2)
    Lp[sp*32768 + q*8 + h] = Of[2][0];
}

// ---------------- merge 4 partials (weights all 1) -> ao bf16 ----------------
__global__ __launch_bounds__(256) void attn_merge(
    const u16* __restrict__ Opart, const float* __restrict__ Lp,
    u16* __restrict__ O) {
  int gid = blockIdx.x*256 + threadIdx.x;   // < 4096*8*20
  int dp = gid % 20;
  int qh = gid / 20;
  int q = qh >> 3, h = qh & 7;
  float ls = Lp[qh] + Lp[32768 + qh] + Lp[2*32768 + qh] + Lp[3*32768 + qh];
  size_t base = (size_t)q*320 + h*40 + dp*2;
  const size_t HBu = 4096u*320u;
  float r0 = 0.f, r1 = 0.f;
  #pragma unroll
  for (int sp = 0; sp < 4; sp++) {
    unsigned u = *(const unsigned*)&Opart[sp*HBu + base];
    r0 += bfu2f((u16)(u & 0xffffu));
    r1 += bfu2f((u16)(u >> 16));
  }
  float inv = 1.f / ls;
  *(unsigned*)&O[base] = pack2(r0*inv, r1*inv);
}

// ---------------- Cross-attention: single-shot MFMA, 77 keys, max-free ----------------
__global__ __launch_bounds__(256) void cross_attn_mfma(
    const u16* __restrict__ Q, const u16* __restrict__ Kc,
    const u16* __restrict__ Vc, u16* __restrict__ O) {
  const int h = blockIdx.y;
  const int q0 = blockIdx.x * 64;
  const int tid = threadIdx.x;
  const int w = tid >> 6, lane = tid & 63;
  const int l16 = lane & 15, g = lane >> 4;

  __shared__ __align__(16) u16 Kls[80][72];
  __shared__ __align__(16) u16 Vt[48][104];
  __shared__ __align__(16) u16 PsT[4][16][104];

  for (int e = tid; e < 80*12; e += 256) {
    int r = e / 12, c = e % 12;
    *(unsigned*)&Kls[r][40 + 2*c] = 0u;
  }
  for (int e = tid; e < 48*52; e += 256) {
    int r = e / 52, c = e % 52;
    *(unsigned*)&Vt[r][2*c] = 0u;
  }
  {
    int r = lane >> 2, c4 = (lane & 3)*4;
    uint2 z; z.x = 0u; z.y = 0u;
    *(uint2*)&PsT[w][r][80 + c4] = z;
  }

  short8v Qb[2];
  {
    const u16* qrow = Q + (size_t)(q0 + w*16 + l16)*320 + h*40;
    Qb[0] = *(const short8v*)(qrow + g*8);
    short8v z = {};
    Qb[1] = (g == 0) ? *(const short8v*)(qrow + 32) : z;
  }

  for (int e = tid; e < 1600; e += 256) {
    int key = e / 20, dp = e % 20;
    unsigned val = 0u;
    if (key < 77) val = *(const unsigned*)&Kc[(size_t)key*320 + h*40 + dp*2];
    *(unsigned*)&Kls[key][dp*2] = val;
  }
  __syncthreads();
  for (int e = tid; e < 1600; e += 256) {
    int kp = e / 40, d = e % 40;
    unsigned u0 = (kp*2     < 77) ? (unsigned)Vc[(size_t)(kp*2    )*320 + h*40 + d] : 0u;
    unsigned u1 = (kp*2 + 1 < 77) ? (unsigned)Vc[(size_t)(kp*2 + 1)*320 + h*40 + d] : 0u;
    *(unsigned*)&Vt[d][kp*2] = u0 | (u1 << 16);
  }
  __syncthreads();

  float4v Sf[5];
  #pragma unroll
  for (int mt = 0; mt < 5; mt++) {
    short8v ka0 = *(const short8v*)&Kls[mt*16 + l16][g*8];
    short8v ka1 = *(const short8v*)&Kls[mt*16 + l16][32 + g*8];
    float4v s = {};
    s = __builtin_amdgcn_mfma_f32_16x16x32_bf16(ka0, Qb[0], s, 0, 0, 0);
    s = __builtin_amdgcn_mfma_f32_16x16x32_bf16(ka1, Qb[1], s, 0, 0, 0);
    Sf[mt] = s;
  }

  float rsum = 0.f;
  #pragma unroll
  for (int mt = 0; mt < 5; mt++)
    #pragma unroll
    for (int r = 0; r < 4; r++) {
      int key = mt*16 + 4*g + r;
      float p = (key < 77) ? exp2f(Sf[mt][r]) : 0.f;
      Sf[mt][r] = p; rsum += p;
    }
  rsum += __shfl_xor(rsum, 16);
  rsum += __shfl_xor(rsum, 32);

  #pragma unroll
  for (int mt = 0; mt < 5; mt++) {
    uint2 pk;
    pk.x = pack2(Sf[mt][0], Sf[mt][1]);
    pk.y = pack2(Sf[mt][2], Sf[mt][3]);
    *(uint2*)&PsT[w][l16][mt*16 + 4*g] = pk;
  }
  __syncthreads();

  float4v Of[3] = {};
  #pragma unroll
  for (int ks = 0; ks < 3; ks++) {
    short8v pb = *(const short8v*)&PsT[w][l16][ks*32 + g*8];
    #pragma unroll
    for (int mt = 0; mt < 3; mt++) {
      short8v va = *(const short8v*)&Vt[mt*16 + l16][ks*32 + g*8];
      Of[mt] = __builtin_amdgcn_mfma_f32_16x16x32_bf16(va, pb, Of[mt], 0, 0, 0);
    }
  }

  float inv = 1.f / rsum;
  u16* orow = O + (size_t)(q0 + w*16 + l16)*320 + h*40;
  #pragma unroll
  for (int mt = 0; mt < 3; mt++) {
    #pragma unroll
    for (int rp = 0; rp < 2; rp++) {
      int d = mt*16 + 4*g + rp*2;
      if (d < 40)
        *(unsigned*)&orow[d] = pack2(Of[mt][rp*2] * inv, Of[mt][rp*2+1] * inv);
    }
  }
}

extern "C" void kernel_launch(void* const* d_in, const int* in_sizes, int n_in,
                              void* d_out, int out_size, void* d_ws, size_t ws_size,
                              hipStream_t stream) {
  const float* x        = (const float*)d_in[0];
  const float* ctx      = (const float*)d_in[1];
  const float* gn_s     = (const float*)d_in[2];
  const float* gn_b     = (const float*)d_in[3];
  const float* w_pin    = (const float*)d_in[4];
  const float* b_pin    = (const float*)d_in[5];
  const float* ln1_s    = (const float*)d_in[6];
  const float* ln1_b    = (const float*)d_in[7];
  const float* wq1      = (const float*)d_in[8];
  const float* wk1      = (const float*)d_in[9];
  const float* wv1      = (const float*)d_in[10];
  const float* wo1      = (const float*)d_in[11];
  const float* bo1      = (const float*)d_in[12];
  const float* ln2_s    = (const float*)d_in[13];
  const float* ln2_b    = (const float*)d_in[14];
  const float* wq2      = (const float*)d_in[15];
  const float* wk2      = (const float*)d_in[16];
  const float* wv2      = (const float*)d_in[17];
  const float* wo2      = (const float*)d_in[18];
  const float* bo2      = (const float*)d_in[19];
  const float* ln3_s    = (const float*)d_in[20];
  const float* ln3_b    = (const float*)d_in[21];
  const float* w_ff1    = (const float*)d_in[22];
  const float* b_ff1    = (const float*)d_in[23];
  const float* w_ff2    = (const float*)d_in[24];
  const float* b_ff2    = (const float*)d_in[25];
  const float* w_pout   = (const float*)d_in[26];
  const float* b_pout   = (const float*)d_in[27];
  float* out = (float*)d_out;

  u16* ws = (u16*)d_ws;
  const size_t HB = 4096u*320u;
  u16* h   = ws;
  u16* hn  = ws + HB;
  u16* q   = ws + 2*HB;    // q,k contiguous (QKV fused epilogue)
  u16* k   = ws + 3*HB;
  u16* vT  = ws + 4*HB;    // V^T [320][4096]
  u16* ao  = ws + 5*HB;
  u16* gnT = k;
  u16* gg  = q;            // GEGLU out overlays q,k,vT,ao
  u16* wb  = ws + 6*HB;
  size_t o = 0;
  u16* ctxb   = wb + o; o += 59136;
  u16* wq1T   = wb + o; o += 102400;   // stacked: wq1T,wk1T,wv1T = [960][320]
  u16* wk1T   = wb + o; o += 102400;
  u16* wv1T   = wb + o; o += 102400;
  u16* wo1T   = wb + o; o += 102400;
  u16* wq2T   = wb + o; o += 102400;
  u16* wk2T   = wb + o; o += 245760;   // stacked: wk2T,wv2T = [640][768]
  u16* wv2T   = wb + o; o += 245760;
  u16* wo2T   = wb + o; o += 102400;
  u16* wff1T  = wb + o; o += 819200;
  u16* wff2T  = wb + o; o += 409600;
  u16* wpoutT = wb + o; o += 102400;
  u16* wpinT  = wb + o; o += 102400;
  u16* kc     = wb + o; o += 24640;    // kc,vc contiguous, segStride 24640
  u16* vc     = wb + o; o += 24640;
  float* psum = (float*)(wb + o);      // 256 partial sums
  float* psq  = psum + 256;
  u16* OpartB = (u16*)(psq + 256);               // 4 x HB bf16 = 10.5 MB
  float* Lpart = (float*)(OpartB + 4*HB);        // 4 x 32768 fp32

  TPack tp;
  const float* srcs[12] = {wq1, wk1, wv1, wo1, wq2, wo2, w_pin, w_pout, wk2, wv2, w_ff1, w_ff2};
  u16* dsts[12]         = {wq1T, wk1T, wv1T, wo1T, wq2T, wo2T, wpinT, wpoutT, wk2T, wv2T, wff1T, wff2T};
  int Ks[12] = {320,320,320,320,320,320,320,320,768,768,320,1280};
  int Ns[12] = {320,320,320,320,320,320,320,320,320,320,2560,320};
  int off = 0;
  for (int i = 0; i < 12; i++) {
    tp.d[i].src = srcs[i]; tp.d[i].dst = dsts[i];
    tp.d[i].K = Ks[i]; tp.d[i].N = Ns[i];
    tp.d[i].off = off; tp.d[i].tx = Ns[i]/32;
    tp.d[i].sc = (i == 0 || i == 4) ? SCALE_L2E : 1.0f;   // wq1, wq2 pre-scaled
    off += (Ks[i]/32)*(Ns[i]/32);
  }

  dim3 blk(256), g64x10(64, 10);
  const u16* nres = nullptr;
  const float* nb = nullptr;

  // prep: weight tcvt (off) + ctx cvt (58) + gn partial stats (256)
  hipLaunchKernelGGL(prep_kernel, dim3(off + 58 + 256), blk, 0, stream,
                     tp, off, ctx, ctxb, x, psum, psq);
  // fused: gn apply+transpose (320 blocks) || kc/vc GEMM (20 blocks)
  hipLaunchKernelGGL(gn_kcvc, dim3(340), blk, 0, stream,
                     x, psum, psq, gn_s, gn_b, gnT, ctxb, wk2T, kc);
  hipLaunchKernelGGL((oneshot<0>), g64x10, blk, 0, stream, gnT, wpinT, b_pin, nres, nb, (void*)h, 320, 1);
  hipLaunchKernelGGL(layernorm_kernel, dim3(4096), dim3(64), 0, stream, h, ln1_s, ln1_b, hn);
  // fused QKV one-shot: grid (64,30); segs 0,1 -> q,k; seg 2 -> vT
  hipLaunchKernelGGL(qkv_oneshot, dim3(64, 30), blk, 0, stream, hn, wq1T, q, vT, (int)HB);
  hipLaunchKernelGGL(self_attn_part, dim3(32, 8, 4), dim3(512), 0, stream, q, k, vT, OpartB, Lpart);
  hipLaunchKernelGGL(attn_merge, dim3(2560), blk, 0, stream, OpartB, Lpart, ao);
  hipLaunchKernelGGL((oneshot<0>), g64x10, blk, 0, stream, ao, wo1T, bo1, h, nb, (void*)h, 320, 1);
  hipLaunchKernelGGL(layernorm_kernel, dim3(4096), dim3(64), 0, stream, h, ln2_s, ln2_b, hn);
  hipLaunchKernelGGL((oneshot<0>), g64x10, blk, 0, stream, hn, wq2T, nb, nres, nb, (void*)q, 320, 1);
  hipLaunchKernelGGL(cross_attn_mfma, dim3(64, 8), blk, 0, stream, q, kc, vc, ao);
  hipLaunchKernelGGL((oneshot<0>), g64x10, blk, 0, stream, ao, wo2T, bo2, h, nb, (void*)h, 320, 1);
  hipLaunchKernelGGL(layernorm_kernel, dim3(4096), dim3(64), 0, stream, h, ln3_s, ln3_b, hn);
  hipLaunchKernelGGL(geglu_mfma, dim3(64, 20), blk, 0, stream, hn, wff1T, b_ff1, gg);
  hipLaunchKernelGGL((oneshot<0>), g64x10, blk, 0, stream, gg, wff2T, b_ff2, h, nb, (void*)h, 1280, 4);
  hipLaunchKernelGGL((oneshot<2>), g64x10, blk, 0, stream, h, wpoutT, b_pout, nres, x, (void*)out, 320, 1);
}